// Round 8
// baseline (3608.308 us; speedup 1.0000x reference)
//
#include <hip/hip_runtime.h>
#include <hip/hip_bf16.h>

// ---------------------------------------------------------------------------
// RNNModel (MDN-RNN): embed+concat -> x_pre -> 511-step LSTM -> out GEMM ->
// logsumexp heads.
//   lstm_k (R8): persistent 256 blocks (1/CU, R4 structure: block owns 4
//     h-cols = 16 gate rows, 32KB W_hh LDS). SECTOR-PROGRESSIVE sync:
//     no global barrier. Sector kt = 8 writer blocks (32 h-cols). Wave w's
//     K-step kk polls ONLY flags[8kt..8kt+8) (lane&7), then gathers+MFMAs
//     that sector. Next sector's flag load prefetched behind the gather ->
//     steady-state checks free. Rotation kk0=blk&7 spreads flag-line load.
//     Flags: per-block u32 monotonic step count, agent-scope store after
//     vmcnt(0) drain of the h64 atomic stores (R5-proven). R6 lesson kept:
//     poll tiny flags, never bulk data. R7 lesson: compiler already
//     pipelines gathers; all-wave full-flag polls add traffic.
//   hs2: [256 regions][16384 rows] u64 (R4), out_gemm A-frag = 2x8B.
// ---------------------------------------------------------------------------

typedef float f4 __attribute__((ext_vector_type(4)));
typedef short s8 __attribute__((ext_vector_type(8)));
typedef unsigned short us8v __attribute__((ext_vector_type(8)));
typedef unsigned short us4v __attribute__((ext_vector_type(4)));
typedef unsigned long long u64;
typedef unsigned u32;

#define DEV __device__ __forceinline__

DEV unsigned short f2b(float f) {          // fp32 -> bf16 RNE
  unsigned u = __float_as_uint(f);
  return (unsigned short)((u + 0x7FFFu + ((u >> 16) & 1u)) >> 16);
}
DEV float b2f(unsigned short s) { return __uint_as_float(((unsigned)s) << 16); }

DEV f4 MFMA(s8 a, s8 b, f4 c) {
  return __builtin_amdgcn_mfma_f32_16x16x32_bf16(a, b, c, 0, 0, 0);
}
DEV s8 LD8(const unsigned short* p) { return *reinterpret_cast<const s8*>(p); }

DEV u64 AL(const u64* p) {
  return __hip_atomic_load(p, __ATOMIC_RELAXED, __HIP_MEMORY_SCOPE_AGENT);
}
DEV u32 AL32(const u32* p) {
  return __hip_atomic_load(p, __ATOMIC_RELAXED, __HIP_MEMORY_SCOPE_AGENT);
}

DEV float sigf(float x) {   // 1/(1+e^-x) via v_exp + v_rcp (~1e-6 rel)
  float e = __builtin_amdgcn_exp2f(x * -1.44269504f);
  return __builtin_amdgcn_rcpf(1.f + e);
}
DEV float tanhf_fast(float x) {  // 1 - 2/(e^{2x}+1); saturates correctly
  float e = __builtin_amdgcn_exp2f(x * 2.88539008f);
  return 1.f - 2.f * __builtin_amdgcn_rcpf(e + 1.f);
}

// ---- workspace layout (bytes) ----
// [0,1024)    256 per-block arrival flags (u32, monotonic step count)
// [2048, +131072)   h64: 2 x 32 x 256 u64 (dbl-buffered carry h, bf16 packed)
// [133120, +4MiB)   zt : 512 x 32 x 128 bf16
// [4327424, +3.75MiB) wout16
// [8261632, +32MiB) hs2: 256 regions x 16384 rows x u64
static constexpr size_t WS_HBUF = 2048;
static constexpr size_t WS_ZT   = 133120;
static constexpr size_t WS_WOUT = 4327424;
static constexpr size_t WS_HS2  = 8261632;
static constexpr size_t WS_END  = 41816064;

// ---------------------------------------------------------------------------
__global__ void cvt_wout_k(const float* __restrict__ W, unsigned short* __restrict__ o) {
  int i = blockIdx.x * 256 + threadIdx.x;         // 491776 float4 units exact
  if (i < 491776) {
    const float4 v = reinterpret_cast<const float4*>(W)[i];
    us4v u; u[0] = f2b(v.x); u[1] = f2b(v.y); u[2] = f2b(v.z); u[3] = f2b(v.w);
    reinterpret_cast<us4v*>(o)[i] = u;
  }
}

__global__ void cvt_z_k(const float* __restrict__ z, unsigned short* __restrict__ zt) {
  int u = blockIdx.x * 256 + threadIdx.x;         // 524288 units exact
  if (u < 524288) {
    int d4 = u & 31, bt = u >> 5;
    int b = bt & 31, t = bt >> 5;
    const float4 v = reinterpret_cast<const float4*>(z)[(b * 512 + t) * 32 + d4];
    us4v uu; uu[0] = f2b(v.x); uu[1] = f2b(v.y); uu[2] = f2b(v.z); uu[3] = f2b(v.w);
    reinterpret_cast<us4v*>(zt)[u] = uu;
  }
}

__global__ void zero_hs_tail_k(u64* __restrict__ hs2) {
  // rows 16352..16383 of all 256 regions
  int i = blockIdx.x * 256 + threadIdx.x;
  if (i < 8192) {
    int region = i >> 5, r = 16352 + (i & 31);
    hs2[(size_t)region * 16384 + r] = 0ull;
  }
}

// ---------------------------------------------------------------------------
// Persistent LSTM. grid=256, block=256 (4 waves). Block blk owns h cols
// [4blk,4blk+4) = 16 gate rows {g*1024+4blk+q}. Wave w owns K-slice
// [256w,+256). Sector-progressive flag sync (see header).
__global__ __launch_bounds__(256, 1) void lstm_k(
    const float* __restrict__ Whh, const float* __restrict__ Wih,
    const float* __restrict__ embed, const float* __restrict__ bih,
    const float* __restrict__ bhh, const int* __restrict__ actions,
    const int* __restrict__ dones, const unsigned short* __restrict__ zt,
    u64* __restrict__ h64, u64* __restrict__ hs2,
    u32* __restrict__ flags) {
  const int blk = blockIdx.x;
  const int tid = threadIdx.x;
  const int lane = tid & 63;
  const int w = tid >> 6;
  const int ln = lane & 15, lk = lane >> 4;

  __shared__ alignas(16) unsigned short whh_sw[32 * 64 * 8];   // 32 KB
  __shared__ alignas(16) unsigned short wz_sw[4 * 64 * 8];     // 4 KB
  __shared__ float abias[18][16];
  __shared__ float red[4][32][21];     // padded 21: conflict-free reads
  __shared__ alignas(8) unsigned short st[32][4];   // unmasked h staging
  __shared__ alignas(8) unsigned short stm[32][4];  // masked h staging

  for (int i = tid; i < 32 * 64 * 8; i += 256) {
    int j = i & 7, L = (i >> 3) & 63, kt = i >> 9;
    int n = L & 15;
    int grow = (n >> 2) * 1024 + blk * 4 + (n & 3);
    int k = kt * 32 + ((L >> 4) << 3) + j;
    whh_sw[i] = f2b(Whh[grow * 1024 + k]);
  }
  for (int i = tid; i < 4 * 64 * 8; i += 256) {
    int j = i & 7, L = (i >> 3) & 63, kt = i >> 9;
    int n = L & 15;
    int grow = (n >> 2) * 1024 + blk * 4 + (n & 3);
    int k = kt * 32 + ((L >> 4) << 3) + j;
    wz_sw[i] = f2b(Wih[grow * 144 + k]);
  }
  for (int i = tid; i < 18 * 16; i += 256) {
    int a = i >> 4, n = i & 15;
    int grow = (n >> 2) * 1024 + blk * 4 + (n & 3);
    float s = bih[grow] + bhh[grow];
    for (int j = 0; j < 16; ++j) s += embed[a * 16 + j] * Wih[grow * 144 + 128 + j];
    abias[a][n] = s;
  }
  __syncthreads();

  const int eb = tid & 31, eq = tid >> 5;   // epilogue mapping (tid < 128)
  const int kk0 = blk & 7;                  // sector rotation
  const int fl = lane & 7;                  // flag sub-index within sector
  float c_state = 0.f;

  for (int t = 0; t < 511; ++t) {
    const int p = t & 1;
    const u64* hb = h64 + p * 8192;          // 32 rows x 256 u64

    f4 acc0 = {0.f, 0.f, 0.f, 0.f};
    f4 acc1 = {0.f, 0.f, 0.f, 0.f};

    {  // z contribution: independent of h, issue first
      const unsigned short* zb = zt + (size_t)t * 4096;
      const int kz = w * 32 + (lk << 3);
      s8 a0 = LD8(zb + ln * 128 + kz);
      s8 a1 = LD8(zb + (ln + 16) * 128 + kz);
      s8 bf = LD8(wz_sw + ((w * 64 + lane) << 3));
      acc0 = MFMA(a0, bf, acc0);
      acc1 = MFMA(a1, bf, acc1);
    }
    // per-step scalars: independent of h
    int a_t = 0; float m_t = 0.f;
    if (tid < 128) {
      a_t = actions[eb * 512 + t];
      m_t = 1.f - (float)dones[eb * 512 + t];
    }

    // ---- sector-progressive K-loop: poll 8 flags -> gather -> 2 MFMA ----
    const u32 tgt = (u32)t;
    u32 fcur = 0xFFFFFFFFu;
    if (t) fcur = AL32(flags + (((w << 3) + kk0) << 3) + fl);
#pragma unroll
    for (int i = 0; i < 8; ++i) {
      const int kk = (kk0 + i) & 7;
      const int kt = (w << 3) + kk;
      if (t) {
        unsigned spin = 0;
        while (!__all(fcur >= tgt) && spin < (1u << 20)) {
          __builtin_amdgcn_s_sleep(1);
          fcur = AL32(flags + (kt << 3) + fl);
          ++spin;
        }
      }
      // gather this sector (4 x 8B agent loads)
      const int c2 = (kt << 3) + (lk << 1);
      u64 qa0 = AL(hb + ln * 256 + c2);
      u64 qa1 = AL(hb + ln * 256 + c2 + 1);
      u64 qb0 = AL(hb + (ln + 16) * 256 + c2);
      u64 qb1 = AL(hb + (ln + 16) * 256 + c2 + 1);
      if (t && i < 7) {  // prefetch next sector's flags behind the gather
        const int ktn = (w << 3) + ((kk0 + i + 1) & 7);
        fcur = AL32(flags + (ktn << 3) + fl);
      }
      s8 bf = LD8(whh_sw + ((kt * 64 + lane) << 3));
      union { u64 q[2]; s8 v; } fa, fb;
      fa.q[0] = qa0; fa.q[1] = qa1;
      fb.q[0] = qb0; fb.q[1] = qb1;
      acc0 = MFMA(fa.v, bf, acc0);
      acc1 = MFMA(fb.v, bf, acc1);
    }

    // D layout: row(batch) = 4*(lane>>4)+j, col(gate) = lane&15
#pragma unroll
    for (int j = 0; j < 4; ++j) {
      red[w][(lk << 2) + j][ln] = acc0[j];
      red[w][16 + (lk << 2) + j][ln] = acc1[j];
    }
    __syncthreads();

    if (tid < 128) {  // one thread per (batch eb, local h-index eq)
      float gi = 0.f, gf = 0.f, gg = 0.f, go = 0.f;
#pragma unroll
      for (int ww = 0; ww < 4; ++ww) {
        gi += red[ww][eb][eq];
        gf += red[ww][eb][4 + eq];
        gg += red[ww][eb][8 + eq];
        go += red[ww][eb][12 + eq];
      }
      gi += abias[a_t][eq];       gf += abias[a_t][4 + eq];
      gg += abias[a_t][8 + eq];   go += abias[a_t][12 + eq];
      const float si = sigf(gi), sf = sigf(gf), so = sigf(go);
      const float cn = sf * c_state + si * tanhf_fast(gg);
      const float hn = so * tanhf_fast(cn);
      c_state = cn * m_t;                      // fp32 carry
      st[eb][eq]  = f2b(hn);                   // unmasked -> hs2
      stm[eb][eq] = f2b(hn * m_t);             // masked   -> carry h
    }
    __syncthreads();

    if (tid < 32) {  // carry h: one 8B agent atomic per batch (wave 0)
      const u64 hum = *reinterpret_cast<const u64*>(&stm[tid][0]);
      __hip_atomic_store(h64 + (1 - p) * 8192 + tid * 256 + blk, hum,
                         __ATOMIC_RELAXED, __HIP_MEMORY_SCOPE_AGENT);
    }
    if (tid == 0) {  // drain wave-0 stores to LLC, then publish flag
      asm volatile("s_waitcnt vmcnt(0)" ::: "memory");
      __hip_atomic_store(flags + blk, (u32)(t + 1),
                         __ATOMIC_RELAXED, __HIP_MEMORY_SCOPE_AGENT);
    }
    if (tid < 32) {  // history (off critical path): 8B per batch
      const u64 hu = *reinterpret_cast<const u64*>(&st[tid][0]);
      hs2[(size_t)blk * 16384 + tid * 511 + t] = hu;
    }
  }
}

// ---------------------------------------------------------------------------
// out = hs @ W_out^T (+bias), fused logsumexp on the logmix third.
// grid = (256 Mblk of 64 rows, 24 Nblk of 80 cols). Wave w -> rows [w*16,+16).
__global__ __launch_bounds__(256, 2) void out_gemm_k(
    const u64* __restrict__ hs2, const unsigned short* __restrict__ wout,
    const float* __restrict__ b_out, float* __restrict__ out) {
  const int mblk = blockIdx.x, nblk = blockIdx.y;
  const int tid = threadIdx.x, lane = tid & 63, w = tid >> 6;
  const int ln = lane & 15, lk = lane >> 4;
  __shared__ alignas(16) unsigned char smraw[21760];
  unsigned short* bsm = (unsigned short*)smraw;  // [80][136] bf16 B-chunk
  float* ep = (float*)smraw;                     // [64][84] f32 epilogue tile

  const int r0 = mblk * 64 + w * 16;
  f4 acc[5];
#pragma unroll
  for (int s = 0; s < 5; ++s) acc[s] = (f4){0.f, 0.f, 0.f, 0.f};

  for (int kc = 0; kc < 8; ++kc) {  // K chunks of 128
#pragma unroll
    for (int ii = 0; ii < 5; ++ii) {           // 1280 us8 chunks exact
      int i = tid + ii * 256;
      int n = i >> 4, k16 = i & 15;
      us8v v = *reinterpret_cast<const us8v*>(
          wout + (size_t)(nblk * 80 + n) * 1024 + kc * 128 + (k16 << 3));
      *reinterpret_cast<us8v*>(bsm + n * 136 + (k16 << 3)) = v;
    }
    __syncthreads();
#pragma unroll
    for (int ks = 0; ks < 4; ++ks) {
      const int k0 = kc * 128 + ks * 32 + (lk << 3);
      union { u64 q[2]; s8 v; } ua;            // A-frag: 2 x 8B from hs2
      ua.q[0] = hs2[(size_t)(k0 >> 2) * 16384 + r0 + ln];
      ua.q[1] = hs2[((size_t)(k0 >> 2) + 1) * 16384 + r0 + ln];
#pragma unroll
      for (int s = 0; s < 5; ++s) {
        s8 b = LD8(bsm + (s * 16 + ln) * 136 + ks * 32 + (lk << 3));
        acc[s] = MFMA(ua.v, b, acc[s]);
      }
    }
    __syncthreads();
  }

  const int T = nblk >> 3;  // 0 logmix, 1 mu, 2 logstd
  if (T) {
    float* base = out + (size_t)10465280 * T;
    const int lc0 = (nblk - (T << 3)) * 80;
#pragma unroll
    for (int s = 0; s < 5; ++s) {
      const int lc = lc0 + s * 16 + ln;
      const float bias = b_out[T * 640 + lc];
#pragma unroll
      for (int j = 0; j < 4; ++j) {
        const int row = r0 + (lk << 2) + j;
        if (row < 16352) base[(size_t)row * 640 + lc] = acc[s][j] + bias;
      }
    }
  } else {  // logmix: bounce through LDS, per-(row, z-group) logsumexp over 5
#pragma unroll
    for (int s = 0; s < 5; ++s) {
      const float bias = b_out[nblk * 80 + s * 16 + ln];
#pragma unroll
      for (int j = 0; j < 4; ++j)
        ep[(w * 16 + (lk << 2) + j) * 84 + s * 16 + ln] = acc[s][j] + bias;
    }
    __syncthreads();
    for (int task = tid; task < 1024; task += 256) {
      const int rr = task >> 4, grp = task & 15;
      const int row = mblk * 64 + rr;
      const float* e = ep + rr * 84 + grp * 5;
      float v0 = e[0], v1 = e[1], v2 = e[2], v3 = e[3], v4 = e[4];
      float mx = fmaxf(fmaxf(fmaxf(v0, v1), fmaxf(v2, v3)), v4);
      float ssum = expf(v0 - mx) + expf(v1 - mx) + expf(v2 - mx) +
                   expf(v3 - mx) + expf(v4 - mx);
      float lse = mx + logf(ssum);
      if (row < 16352) {
        float* o = out + (size_t)row * 640 + nblk * 80 + grp * 5;
        o[0] = v0 - lse; o[1] = v1 - lse; o[2] = v2 - lse;
        o[3] = v3 - lse; o[4] = v4 - lse;
      }
    }
  }
}

// ---------------------------------------------------------------------------
__global__ __launch_bounds__(256) void donep_k(
    const u64* __restrict__ hs2, const unsigned short* __restrict__ wout,
    const float* __restrict__ b_out, float* __restrict__ out) {
  const int lane = threadIdx.x & 63;
  const int wv = (blockIdx.x * 256 + threadIdx.x) >> 6;  // 2048 waves
  const unsigned short* wrow = wout + (size_t)1920 * 1024 + lane * 16;
  float wl[16];
#pragma unroll
  for (int i = 0; i < 16; ++i) wl[i] = b2f(wrow[i]);
  const float bias = b_out[1920];
  for (int r = wv; r < 16352; r += 2048) {
    float d = 0.f;
#pragma unroll
    for (int j = 0; j < 4; ++j) {   // k = lane*16 + 4j + (0..3)
      union { u64 q; unsigned short h[4]; } u;
      u.q = hs2[(size_t)(lane * 4 + j) * 16384 + r];
#pragma unroll
      for (int i = 0; i < 4; ++i) d += b2f(u.h[i]) * wl[j * 4 + i];
    }
#pragma unroll
    for (int off = 32; off; off >>= 1) d += __shfl_down(d, off, 64);
    if (lane == 0) out[31395840 + r] = d + bias;
  }
}

// ---------------------------------------------------------------------------
extern "C" void kernel_launch(void* const* d_in, const int* in_sizes, int n_in,
                              void* d_out, int out_size, void* d_ws, size_t ws_size,
                              hipStream_t stream) {
  const float* z       = (const float*)d_in[0];
  const int*   actions = (const int*)d_in[1];
  const int*   dones   = (const int*)d_in[2];
  const float* embed   = (const float*)d_in[3];
  const float* Wih     = (const float*)d_in[4];
  const float* Whh     = (const float*)d_in[5];
  const float* bih     = (const float*)d_in[6];
  const float* bhh     = (const float*)d_in[7];
  const float* Wout    = (const float*)d_in[8];
  const float* bout    = (const float*)d_in[9];
  float* out = (float*)d_out;

  if (ws_size < WS_END) return;  // fail visibly rather than corrupt memory

  char* ws = (char*)d_ws;
  u32* flags             = (u32*)(ws);
  u64* h64               = (u64*)(ws + WS_HBUF);
  unsigned short* zt     = (unsigned short*)(ws + WS_ZT);
  unsigned short* wout16 = (unsigned short*)(ws + WS_WOUT);
  u64* hs2               = (u64*)(ws + WS_HS2);

  // zero flags + initial h (h0 = 0); must happen every launch
  hipMemsetAsync(d_ws, 0, 133120, stream);

  cvt_wout_k<<<1921, 256, 0, stream>>>(Wout, wout16);
  cvt_z_k<<<2048, 256, 0, stream>>>(z, zt);
  zero_hs_tail_k<<<32, 256, 0, stream>>>(hs2);
  lstm_k<<<256, 256, 0, stream>>>(Whh, Wih, embed, bih, bhh, actions, dones,
                                  zt, h64, hs2, flags);
  out_gemm_k<<<dim3(256, 24), 256, 0, stream>>>(hs2, wout16, bout, out);
  donep_k<<<512, 256, 0, stream>>>(hs2, wout16, bout, out);
}

// Round 10
// 2302.120 us; speedup vs baseline: 1.5674x; 1.5674x over previous
//
#include <hip/hip_runtime.h>
#include <hip/hip_bf16.h>

// ---------------------------------------------------------------------------
// RNNModel (MDN-RNN). R9/R10 ALGORITHM: dones (p=0.5) reset h,c -> the
// 511-step recurrence splits into independent segments (avg len 2, max ~15).
//   seg_build_k: scan dones -> segments (b,t0,len); counting-sort desc by len
//     -> slots such that active-at-offset-s = prefix [0, N_s). len-1 segs
//     (half of all) carry nothing. Carriers (len>=2) <= 8160 <= 8192 cap.
//   lstm_seg_k: persistent 256 blocks (R4 tile machinery verbatim: block owns
//     4 h-cols = 16 gate rows, 32KB W_hh LDS, 4-wave K-split, red, epilogue).
//     Loop s=0..maxlen-1: tiles of 32 slots; gates = z + (s? h@Whh : 0);
//     h exchange = dbl-buffered slot buf, 8B agent atomics (proven); c is
//     block-private fp32. ONE group-counter barrier per s (~15 total vs 511).
//   R10 FIX: cvt_z_k bounds were 8x too large (4194304 vs 524288 float4
//     units) -> 56MB OOB read of z + 32MB scribble over zt/wout16/hs2 ->
//     GPU memory fault (R9's Abort). Grid 16384->2048, guard fixed.
//   Big scratch (h_slots 32MB + c 32MB) lives in d_out (dead until out GEMMs);
//   d_ws stays at the proven 41.8MB layout.
// ---------------------------------------------------------------------------

typedef float f4 __attribute__((ext_vector_type(4)));
typedef short s8 __attribute__((ext_vector_type(8)));
typedef unsigned short us8v __attribute__((ext_vector_type(8)));
typedef unsigned short us4v __attribute__((ext_vector_type(4)));
typedef unsigned long long u64;
typedef unsigned u32;

#define DEV __device__ __forceinline__

DEV unsigned short f2b(float f) {          // fp32 -> bf16 RNE
  unsigned u = __float_as_uint(f);
  return (unsigned short)((u + 0x7FFFu + ((u >> 16) & 1u)) >> 16);
}
DEV float b2f(unsigned short s) { return __uint_as_float(((unsigned)s) << 16); }

DEV f4 MFMA(s8 a, s8 b, f4 c) {
  return __builtin_amdgcn_mfma_f32_16x16x32_bf16(a, b, c, 0, 0, 0);
}
DEV s8 LD8(const unsigned short* p) { return *reinterpret_cast<const s8*>(p); }

DEV u64 AL(const u64* p) {
  return __hip_atomic_load(p, __ATOMIC_RELAXED, __HIP_MEMORY_SCOPE_AGENT);
}
DEV u32 AL32(const u32* p) {
  return __hip_atomic_load(p, __ATOMIC_RELAXED, __HIP_MEMORY_SCOPE_AGENT);
}
DEV void AS(u64* p, u64 v) {
  __hip_atomic_store(p, v, __ATOMIC_RELAXED, __HIP_MEMORY_SCOPE_AGENT);
}

DEV float sigf(float x) {   // 1/(1+e^-x) via v_exp + v_rcp (~1e-6 rel)
  float e = __builtin_amdgcn_exp2f(x * -1.44269504f);
  return __builtin_amdgcn_rcpf(1.f + e);
}
DEV float tanhf_fast(float x) {  // 1 - 2/(e^{2x}+1); saturates correctly
  float e = __builtin_amdgcn_exp2f(x * 2.88539008f);
  return 1.f - 2.f * __builtin_amdgcn_rcpf(e + 1.f);
}

// ---- d_ws layout (bytes), total = proven 41.8MB ----
static constexpr size_t WS_GCNT = 0;        // 16 group counters, 128B apart
static constexpr size_t WS_NACT = 2048;     // N_act[512] u32
static constexpr size_t WS_HDR  = 4096;     // hdr[0]=total, hdr[1]=maxlen
static constexpr size_t WS_META = 4352;     // meta[16384] u32
static constexpr size_t WS_TMP  = 131072;   // seg_build scratch (pre-zt)
static constexpr size_t WS_ZT   = 131072;   // zt [16384][128] bf16 (4MB)
static constexpr size_t WS_WOUT = 4325376;  // wout16 (3.75MB)
static constexpr size_t WS_HS2  = 8261632;  // hs2 [256][16384] u64 (32MB)
static constexpr size_t WS_END  = 41816064;
// ---- d_out scratch (dead until out GEMMs overwrite) ----
// h_slots: [2 phase][8192 slot][256 u64] = 32MB at d_out+0
// c_all  : [256 blk][8192 slot][4 f32]   = 32MB at d_out+32MB

// ---------------------------------------------------------------------------
__global__ void cvt_wout_k(const float* __restrict__ W, unsigned short* __restrict__ o) {
  int i = blockIdx.x * 256 + threadIdx.x;         // 491776 float4 units exact
  if (i < 491776) {
    const float4 v = reinterpret_cast<const float4*>(W)[i];
    us4v u; u[0] = f2b(v.x); u[1] = f2b(v.y); u[2] = f2b(v.z); u[3] = f2b(v.w);
    reinterpret_cast<us4v*>(o)[i] = u;
  }
}

__global__ void cvt_z_k(const float* __restrict__ z, unsigned short* __restrict__ zt) {
  // z = 32*512*128 f32 = 524288 float4 units exact (linear, layout preserved)
  int i = blockIdx.x * 256 + threadIdx.x;
  if (i < 524288) {
    const float4 v = reinterpret_cast<const float4*>(z)[i];
    us4v u; u[0] = f2b(v.x); u[1] = f2b(v.y); u[2] = f2b(v.z); u[3] = f2b(v.w);
    reinterpret_cast<us4v*>(zt)[i] = u;
  }
}

__global__ void zero_hs_tail_k(u64* __restrict__ hs2) {
  // rows 16352..16383 of all 256 regions
  int i = blockIdx.x * 256 + threadIdx.x;
  if (i < 8192) {
    int region = i >> 5, r = 16352 + (i & 31);
    hs2[(size_t)region * 16384 + r] = 0ull;
  }
}

// ---------------------------------------------------------------------------
// Segment scan + counting sort (desc by len). 1 block.
__global__ __launch_bounds__(256) void seg_build_k(
    const int* __restrict__ dones, u32* __restrict__ tmp,
    u32* __restrict__ meta, u32* __restrict__ nact, u32* __restrict__ hdr) {
  __shared__ u32 hist[512];
  __shared__ u32 cur[512];
  __shared__ u32 scnt[32];
  const int tid = threadIdx.x;
  for (int i = tid; i < 512; i += 256) hist[i] = 0;
  __syncthreads();
  if (tid < 32) {   // per-batch scan: step t fresh iff t==0 or done[t-1]
    int b = tid, cnt = 0, t0 = 0;
    for (int t = 1; t <= 511; ++t) {
      bool brk = (t == 511) || (dones[b * 512 + t - 1] != 0);
      if (brk) {
        int len = t - t0;
        tmp[b * 511 + cnt] = ((u32)t0 << 16) | (u32)len;
        atomicAdd(&hist[len], 1u);
        ++cnt; t0 = t;
      }
    }
    scnt[b] = (u32)cnt;
  }
  __syncthreads();
  if (tid == 0) {   // suffix sums: nact[s] = #len>s; bucket bases (desc)
    u32 acc = 0; int ml = 0;
    for (int L = 511; L >= 0; --L) {
      cur[L] = acc; nact[L] = acc;
      if (hist[L] && !ml) ml = L;
      acc += hist[L];
    }
    hdr[0] = acc; hdr[1] = (u32)ml;
  }
  __syncthreads();
  if (tid < 32) {   // scatter (within-bucket order arbitrary: prefix prop ok)
    int b = tid; u32 c = scnt[b];
    for (u32 i = 0; i < c; ++i) {
      u32 e = tmp[b * 511 + i];
      u32 len = e & 0xFFFFu, t0 = e >> 16;
      u32 slot = atomicAdd(&cur[len], 1u);
      meta[slot] = ((u32)b << 20) | (t0 << 10) | len;
    }
  }
}

// ---------------------------------------------------------------------------
// Segment-batched LSTM. grid=256, block=256 (4 waves). Block blk owns h cols
// [4blk,4blk+4) = 16 gate rows {g*1024+4blk+q}. Wave w owns K-slice [256w,+256).
__global__ __launch_bounds__(256, 1) void lstm_seg_k(
    const float* __restrict__ Whh, const float* __restrict__ Wih,
    const float* __restrict__ embed, const float* __restrict__ bih,
    const float* __restrict__ bhh, const int* __restrict__ actions,
    const unsigned short* __restrict__ zt, const u32* __restrict__ meta,
    const u32* __restrict__ nact, const u32* __restrict__ hdr,
    u64* __restrict__ hsl, float* __restrict__ c_all,
    u64* __restrict__ hs2, u32* __restrict__ gcnt) {
  const int blk = blockIdx.x;
  const int tid = threadIdx.x;
  const int lane = tid & 63;
  const int w = tid >> 6;
  const int ln = lane & 15, lk = lane >> 4;

  __shared__ alignas(16) unsigned short whh_sw[32 * 64 * 8];   // 32 KB
  __shared__ alignas(16) unsigned short wz_sw[4 * 64 * 8];     // 4 KB
  __shared__ float abias[18][16];
  __shared__ float red[4][32][21];
  __shared__ alignas(8) unsigned short st[32][4];   // unmasked h -> hs2
  __shared__ alignas(8) unsigned short stm[32][4];  // carried h -> h_slots
  __shared__ u32 zrow_l[32], len_l[32], act_l[32], orow_l[32];

  for (int i = tid; i < 32 * 64 * 8; i += 256) {
    int j = i & 7, L = (i >> 3) & 63, kt = i >> 9;
    int n = L & 15;
    int grow = (n >> 2) * 1024 + blk * 4 + (n & 3);
    int k = kt * 32 + ((L >> 4) << 3) + j;
    whh_sw[i] = f2b(Whh[grow * 1024 + k]);
  }
  for (int i = tid; i < 4 * 64 * 8; i += 256) {
    int j = i & 7, L = (i >> 3) & 63, kt = i >> 9;
    int n = L & 15;
    int grow = (n >> 2) * 1024 + blk * 4 + (n & 3);
    int k = kt * 32 + ((L >> 4) << 3) + j;
    wz_sw[i] = f2b(Wih[grow * 144 + k]);
  }
  for (int i = tid; i < 18 * 16; i += 256) {
    int a = i >> 4, n = i & 15;
    int grow = (n >> 2) * 1024 + blk * 4 + (n & 3);
    float s = bih[grow] + bhh[grow];
    for (int j = 0; j < 16; ++j) s += embed[a * 16 + j] * Wih[grow * 144 + 128 + j];
    abias[a][n] = s;
  }
  __syncthreads();

  const int eb = tid & 31, eq = tid >> 5;   // epilogue mapping (tid < 128)
  const int maxlen = (int)hdr[1];

  for (int s = 0; s < maxlen; ++s) {
    const u32 N = nact[s];                   // active slots (prefix)
    const int ntiles = (int)((N + 31) >> 5);
    const u64* hread = hsl + (size_t)((s & 1) ^ 1) * 2097152;  // prev offset
    u64* hwrite = hsl + (size_t)(s & 1) * 2097152;

    for (int tile = 0; tile < ntiles; ++tile) {
      const u32 sb = (u32)tile << 5;
      if (tid < 32) {  // tile meta
        u32 slot = sb + (u32)tid;
        u32 m = (slot < N) ? meta[slot] : 0u;
        u32 b = m >> 20, t0 = (m >> 10) & 1023u, L = m & 1023u;
        u32 zr = b * 512u + t0 + (u32)s;
        zrow_l[tid] = zr; len_l[tid] = L;
        orow_l[tid] = b * 511u + t0 + (u32)s;
        act_l[tid] = (slot < N) ? (u32)actions[zr] : 0u;
      }
      __syncthreads();

      f4 acc0 = {0.f, 0.f, 0.f, 0.f};
      f4 acc1 = {0.f, 0.f, 0.f, 0.f};
      {  // z contribution (K=128)
        const int kz = w * 32 + (lk << 3);
        s8 a0 = LD8(zt + (size_t)zrow_l[ln] * 128 + kz);
        s8 a1 = LD8(zt + (size_t)zrow_l[ln + 16] * 128 + kz);
        s8 bf = LD8(wz_sw + ((w * 64 + lane) << 3));
        acc0 = MFMA(a0, bf, acc0);
        acc1 = MFMA(a1, bf, acc1);
      }
      if (s) {  // h contribution (K=1024); s==0 -> h=0, skip entirely
#pragma unroll
        for (int kk = 0; kk < 8; ++kk) {
          const int kt = (w << 3) + kk;
          const int c2 = (kt << 3) + (lk << 1);
          const u64* pa = hread + (size_t)(sb + ln) * 256 + c2;
          const u64* pb = hread + (size_t)(sb + ln + 16) * 256 + c2;
          u64 qa0 = AL(pa), qa1 = AL(pa + 1);
          u64 qb0 = AL(pb), qb1 = AL(pb + 1);
          s8 bf = LD8(whh_sw + ((kt * 64 + lane) << 3));
          union { u64 q[2]; s8 v; } fa, fb;
          fa.q[0] = qa0; fa.q[1] = qa1;
          fb.q[0] = qb0; fb.q[1] = qb1;
          acc0 = MFMA(fa.v, bf, acc0);
          acc1 = MFMA(fb.v, bf, acc1);
        }
      }

      // D layout: row(slot-in-tile) = 16*mt + 4*lk + j, col(gate) = lane&15
#pragma unroll
      for (int j = 0; j < 4; ++j) {
        red[w][(lk << 2) + j][ln] = acc0[j];
        red[w][16 + (lk << 2) + j][ln] = acc1[j];
      }
      __syncthreads();

      if (tid < 128) {  // epilogue: (slot eb, col eq)
        const u32 slot = sb + (u32)eb;
        float gi = 0.f, gf = 0.f, gg = 0.f, go = 0.f;
#pragma unroll
        for (int ww = 0; ww < 4; ++ww) {
          gi += red[ww][eb][eq];
          gf += red[ww][eb][4 + eq];
          gg += red[ww][eb][8 + eq];
          go += red[ww][eb][12 + eq];
        }
        const u32 a = act_l[eb];
        gi += abias[a][eq];       gf += abias[a][4 + eq];
        gg += abias[a][8 + eq];   go += abias[a][12 + eq];
        float* cp = c_all + (((size_t)blk << 13) + slot) * 4 + eq;
        const float cprev = (s && slot < N) ? *cp : 0.f;
        const float si = sigf(gi), sf = sigf(gf), so = sigf(go);
        const float cn = sf * cprev + si * tanhf_fast(gg);
        const float hn = so * tanhf_fast(cn);
        if (slot < N) {
          st[eb][eq] = f2b(hn);                      // output (unmasked)
          if (len_l[eb] > (u32)(s + 1)) {            // segment continues
            *cp = cn;                                // fp32 c carry (private)
            stm[eb][eq] = f2b(hn);                   // mid-segment done==0
          }
        }
      }
      __syncthreads();

      if (tid < 32) {  // publish
        const u32 slot = sb + (u32)tid;
        if (slot < N) {
          hs2[((size_t)blk << 14) + orow_l[tid]] =
              *reinterpret_cast<const u64*>(&st[tid][0]);
          if (len_l[tid] > (u32)(s + 1))
            AS(hwrite + (size_t)slot * 256 + blk,
               *reinterpret_cast<const u64*>(&stm[tid][0]));
        }
      }
      __syncthreads();
    }

    if (s + 1 < maxlen) {  // one global barrier per offset (~15 total)
      if (tid == 0) {
        asm volatile("s_waitcnt vmcnt(0)" ::: "memory");
        __hip_atomic_fetch_add(gcnt + (blk >> 4) * 32, 1u,
                               __ATOMIC_RELAXED, __HIP_MEMORY_SCOPE_AGENT);
        const u32 tgt = (u32)(s + 1) * 16u;
        for (u32 spin = 0; spin < (1u << 20); ++spin) {
          u32 mn = 0xFFFFFFFFu;
#pragma unroll
          for (int g = 0; g < 16; ++g) {
            u32 v = AL32(gcnt + g * 32);
            mn = (v < mn) ? v : mn;
          }
          if (mn >= tgt) break;
          __builtin_amdgcn_s_sleep(1);
        }
      }
      __syncthreads();
    }
  }
}

// ---------------------------------------------------------------------------
// out = hs @ W_out^T (+bias), fused logsumexp on the logmix third.
__global__ __launch_bounds__(256, 2) void out_gemm_k(
    const u64* __restrict__ hs2, const unsigned short* __restrict__ wout,
    const float* __restrict__ b_out, float* __restrict__ out) {
  const int mblk = blockIdx.x, nblk = blockIdx.y;
  const int tid = threadIdx.x, lane = tid & 63, w = tid >> 6;
  const int ln = lane & 15, lk = lane >> 4;
  __shared__ alignas(16) unsigned char smraw[21760];
  unsigned short* bsm = (unsigned short*)smraw;  // [80][136] bf16 B-chunk
  float* ep = (float*)smraw;                     // [64][84] f32 epilogue tile

  const int r0 = mblk * 64 + w * 16;
  f4 acc[5];
#pragma unroll
  for (int s = 0; s < 5; ++s) acc[s] = (f4){0.f, 0.f, 0.f, 0.f};

  for (int kc = 0; kc < 8; ++kc) {  // K chunks of 128
#pragma unroll
    for (int ii = 0; ii < 5; ++ii) {           // 1280 us8 chunks exact
      int i = tid + ii * 256;
      int n = i >> 4, k16 = i & 15;
      us8v v = *reinterpret_cast<const us8v*>(
          wout + (size_t)(nblk * 80 + n) * 1024 + kc * 128 + (k16 << 3));
      *reinterpret_cast<us8v*>(bsm + n * 136 + (k16 << 3)) = v;
    }
    __syncthreads();
#pragma unroll
    for (int ks = 0; ks < 4; ++ks) {
      const int k0 = kc * 128 + ks * 32 + (lk << 3);
      union { u64 q[2]; s8 v; } ua;            // A-frag: 2 x 8B from hs2
      ua.q[0] = hs2[(size_t)(k0 >> 2) * 16384 + r0 + ln];
      ua.q[1] = hs2[((size_t)(k0 >> 2) + 1) * 16384 + r0 + ln];
#pragma unroll
      for (int s = 0; s < 5; ++s) {
        s8 b = LD8(bsm + (s * 16 + ln) * 136 + ks * 32 + (lk << 3));
        acc[s] = MFMA(ua.v, b, acc[s]);
      }
    }
    __syncthreads();
  }

  const int T = nblk >> 3;  // 0 logmix, 1 mu, 2 logstd
  if (T) {
    float* base = out + (size_t)10465280 * T;
    const int lc0 = (nblk - (T << 3)) * 80;
#pragma unroll
    for (int s = 0; s < 5; ++s) {
      const int lc = lc0 + s * 16 + ln;
      const float bias = b_out[T * 640 + lc];
#pragma unroll
      for (int j = 0; j < 4; ++j) {
        const int row = r0 + (lk << 2) + j;
        if (row < 16352) base[(size_t)row * 640 + lc] = acc[s][j] + bias;
      }
    }
  } else {  // logmix: bounce through LDS, per-(row, z-group) logsumexp over 5
#pragma unroll
    for (int s = 0; s < 5; ++s) {
      const float bias = b_out[nblk * 80 + s * 16 + ln];
#pragma unroll
      for (int j = 0; j < 4; ++j)
        ep[(w * 16 + (lk << 2) + j) * 84 + s * 16 + ln] = acc[s][j] + bias;
    }
    __syncthreads();
    for (int task = tid; task < 1024; task += 256) {
      const int rr = task >> 4, grp = task & 15;
      const int row = mblk * 64 + rr;
      const float* e = ep + rr * 84 + grp * 5;
      float v0 = e[0], v1 = e[1], v2 = e[2], v3 = e[3], v4 = e[4];
      float mx = fmaxf(fmaxf(fmaxf(v0, v1), fmaxf(v2, v3)), v4);
      float ssum = expf(v0 - mx) + expf(v1 - mx) + expf(v2 - mx) +
                   expf(v3 - mx) + expf(v4 - mx);
      float lse = mx + logf(ssum);
      if (row < 16352) {
        float* o = out + (size_t)row * 640 + nblk * 80 + grp * 5;
        o[0] = v0 - lse; o[1] = v1 - lse; o[2] = v2 - lse;
        o[3] = v3 - lse; o[4] = v4 - lse;
      }
    }
  }
}

// ---------------------------------------------------------------------------
__global__ __launch_bounds__(256) void donep_k(
    const u64* __restrict__ hs2, const unsigned short* __restrict__ wout,
    const float* __restrict__ b_out, float* __restrict__ out) {
  const int lane = threadIdx.x & 63;
  const int wv = (blockIdx.x * 256 + threadIdx.x) >> 6;  // 2048 waves
  const unsigned short* wrow = wout + (size_t)1920 * 1024 + lane * 16;
  float wl[16];
#pragma unroll
  for (int i = 0; i < 16; ++i) wl[i] = b2f(wrow[i]);
  const float bias = b_out[1920];
  for (int r = wv; r < 16352; r += 2048) {
    float d = 0.f;
#pragma unroll
    for (int j = 0; j < 4; ++j) {   // k = lane*16 + 4j + (0..3)
      union { u64 q; unsigned short h[4]; } u;
      u.q = hs2[(size_t)(lane * 4 + j) * 16384 + r];
#pragma unroll
      for (int i = 0; i < 4; ++i) d += b2f(u.h[i]) * wl[j * 4 + i];
    }
#pragma unroll
    for (int off = 32; off; off >>= 1) d += __shfl_down(d, off, 64);
    if (lane == 0) out[31395840 + r] = d + bias;
  }
}

// ---------------------------------------------------------------------------
extern "C" void kernel_launch(void* const* d_in, const int* in_sizes, int n_in,
                              void* d_out, int out_size, void* d_ws, size_t ws_size,
                              hipStream_t stream) {
  const float* z       = (const float*)d_in[0];
  const int*   actions = (const int*)d_in[1];
  const int*   dones   = (const int*)d_in[2];
  const float* embed   = (const float*)d_in[3];
  const float* Wih     = (const float*)d_in[4];
  const float* Whh     = (const float*)d_in[5];
  const float* bih     = (const float*)d_in[6];
  const float* bhh     = (const float*)d_in[7];
  const float* Wout    = (const float*)d_in[8];
  const float* bout    = (const float*)d_in[9];
  float* out = (float*)d_out;

  if (ws_size < WS_END) return;  // fail visibly rather than corrupt memory

  char* ws = (char*)d_ws;
  u32* gcnt              = (u32*)(ws + WS_GCNT);
  u32* nact              = (u32*)(ws + WS_NACT);
  u32* hdr               = (u32*)(ws + WS_HDR);
  u32* metaA             = (u32*)(ws + WS_META);
  u32* tmp               = (u32*)(ws + WS_TMP);
  unsigned short* zt     = (unsigned short*)(ws + WS_ZT);
  unsigned short* wout16 = (unsigned short*)(ws + WS_WOUT);
  u64* hs2               = (u64*)(ws + WS_HS2);
  // d_out doubles as scratch during the recurrence (overwritten afterwards)
  u64* hsl    = (u64*)d_out;                          // 32MB: 2x8192x2KB
  float* call = (float*)((char*)d_out + 33554432);    // 32MB: 256x8192x16B

  hipMemsetAsync(d_ws, 0, 2048, stream);  // barrier counters only

  seg_build_k<<<1, 256, 0, stream>>>(dones, tmp, metaA, nact, hdr);
  cvt_z_k<<<2048, 256, 0, stream>>>(z, zt);    // overwrites tmp after build
  zero_hs_tail_k<<<32, 256, 0, stream>>>(hs2);
  lstm_seg_k<<<256, 256, 0, stream>>>(Whh, Wih, embed, bih, bhh, actions,
                                      zt, metaA, nact, hdr, hsl, call,
                                      hs2, gcnt);
  cvt_wout_k<<<1921, 256, 0, stream>>>(Wout, wout16);
  out_gemm_k<<<dim3(256, 24), 256, 0, stream>>>(hs2, wout16, bout, out);
  donep_k<<<512, 256, 0, stream>>>(hs2, wout16, bout, out);
}

// Round 11
// 1527.437 us; speedup vs baseline: 2.3623x; 1.5072x over previous
//
#include <hip/hip_runtime.h>
#include <hip/hip_bf16.h>

// ---------------------------------------------------------------------------
// RNNModel (MDN-RNN). Segment algorithm (R9/R10): dones (p=0.5) reset h,c ->
// 511-step recurrence splits into segments (avg len 2, max ~15); counting-
// sorted desc by len so active-at-offset-s = prefix [0,N_s).
// R11: lstm_seg_k made WAVE-AUTONOMOUS -- 512 thr/block = 8 waves, each wave
//   owns whole tiles (full K=1152), zero __syncthreads in the tile loop:
//   - gate transpose = wave-private LDS bounce (same-wave DS order)
//   - meta via __shfl, h-pack via __shfl_xor(32)
//   - 8 concurrent tile pipelines/CU hide the ~1us LLC gather latency
//   (R10 paid 3 block barriers/tile x 512 tiles = 4us/tile, 12% occupancy).
//   Per-wave s_waitcnt vmcnt(0) before the per-s barrier (all waves store).
// Proven pieces kept verbatim: seg_build, group-counter barrier per s,
// hs2 layout, out_gemm/donep, d_out-as-scratch (hsl 32MB + c_all 32MB).
// ---------------------------------------------------------------------------

typedef float f4 __attribute__((ext_vector_type(4)));
typedef short s8 __attribute__((ext_vector_type(8)));
typedef unsigned short us8v __attribute__((ext_vector_type(8)));
typedef unsigned short us4v __attribute__((ext_vector_type(4)));
typedef unsigned long long u64;
typedef unsigned u32;

#define DEV __device__ __forceinline__

DEV unsigned short f2b(float f) {          // fp32 -> bf16 RNE
  unsigned u = __float_as_uint(f);
  return (unsigned short)((u + 0x7FFFu + ((u >> 16) & 1u)) >> 16);
}
DEV float b2f(unsigned short s) { return __uint_as_float(((unsigned)s) << 16); }

DEV f4 MFMA(s8 a, s8 b, f4 c) {
  return __builtin_amdgcn_mfma_f32_16x16x32_bf16(a, b, c, 0, 0, 0);
}
DEV s8 LD8(const unsigned short* p) { return *reinterpret_cast<const s8*>(p); }

DEV u64 AL(const u64* p) {
  return __hip_atomic_load(p, __ATOMIC_RELAXED, __HIP_MEMORY_SCOPE_AGENT);
}
DEV u32 AL32(const u32* p) {
  return __hip_atomic_load(p, __ATOMIC_RELAXED, __HIP_MEMORY_SCOPE_AGENT);
}
DEV void AS(u64* p, u64 v) {
  __hip_atomic_store(p, v, __ATOMIC_RELAXED, __HIP_MEMORY_SCOPE_AGENT);
}

DEV float sigf(float x) {   // 1/(1+e^-x) via v_exp + v_rcp (~1e-6 rel)
  float e = __builtin_amdgcn_exp2f(x * -1.44269504f);
  return __builtin_amdgcn_rcpf(1.f + e);
}
DEV float tanhf_fast(float x) {  // 1 - 2/(e^{2x}+1); saturates correctly
  float e = __builtin_amdgcn_exp2f(x * 2.88539008f);
  return 1.f - 2.f * __builtin_amdgcn_rcpf(e + 1.f);
}

// ---- d_ws layout (bytes), total = proven 41.8MB ----
static constexpr size_t WS_GCNT = 0;        // 16 group counters, 128B apart
static constexpr size_t WS_NACT = 2048;     // N_act[512] u32
static constexpr size_t WS_HDR  = 4096;     // hdr[0]=total, hdr[1]=maxlen
static constexpr size_t WS_META = 4352;     // meta[16384] u32
static constexpr size_t WS_TMP  = 131072;   // seg_build scratch (pre-zt)
static constexpr size_t WS_ZT   = 131072;   // zt [16384][128] bf16 (4MB)
static constexpr size_t WS_WOUT = 4325376;  // wout16 (3.75MB)
static constexpr size_t WS_HS2  = 8261632;  // hs2 [256][16384] u64 (32MB)
static constexpr size_t WS_END  = 41816064;
// ---- d_out scratch (dead until out GEMMs overwrite) ----
// h_slots: [2 phase][8192 slot][256 u64] = 32MB at d_out+0
// c_all  : [256 blk][8192 slot][4 f32]   = 32MB at d_out+32MB

// ---------------------------------------------------------------------------
__global__ void cvt_wout_k(const float* __restrict__ W, unsigned short* __restrict__ o) {
  int i = blockIdx.x * 256 + threadIdx.x;         // 491776 float4 units exact
  if (i < 491776) {
    const float4 v = reinterpret_cast<const float4*>(W)[i];
    us4v u; u[0] = f2b(v.x); u[1] = f2b(v.y); u[2] = f2b(v.z); u[3] = f2b(v.w);
    reinterpret_cast<us4v*>(o)[i] = u;
  }
}

__global__ void cvt_z_k(const float* __restrict__ z, unsigned short* __restrict__ zt) {
  // z = 32*512*128 f32 = 524288 float4 units exact (linear, layout preserved)
  int i = blockIdx.x * 256 + threadIdx.x;
  if (i < 524288) {
    const float4 v = reinterpret_cast<const float4*>(z)[i];
    us4v u; u[0] = f2b(v.x); u[1] = f2b(v.y); u[2] = f2b(v.z); u[3] = f2b(v.w);
    reinterpret_cast<us4v*>(zt)[i] = u;
  }
}

__global__ void zero_hs_tail_k(u64* __restrict__ hs2) {
  // rows 16352..16383 of all 256 regions
  int i = blockIdx.x * 256 + threadIdx.x;
  if (i < 8192) {
    int region = i >> 5, r = 16352 + (i & 31);
    hs2[(size_t)region * 16384 + r] = 0ull;
  }
}

// ---------------------------------------------------------------------------
// Segment scan + counting sort (desc by len). 1 block.
__global__ __launch_bounds__(256) void seg_build_k(
    const int* __restrict__ dones, u32* __restrict__ tmp,
    u32* __restrict__ meta, u32* __restrict__ nact, u32* __restrict__ hdr) {
  __shared__ u32 hist[512];
  __shared__ u32 cur[512];
  __shared__ u32 scnt[32];
  const int tid = threadIdx.x;
  for (int i = tid; i < 512; i += 256) hist[i] = 0;
  __syncthreads();
  if (tid < 32) {   // per-batch scan: step t fresh iff t==0 or done[t-1]
    int b = tid, cnt = 0, t0 = 0;
    for (int t = 1; t <= 511; ++t) {
      bool brk = (t == 511) || (dones[b * 512 + t - 1] != 0);
      if (brk) {
        int len = t - t0;
        tmp[b * 511 + cnt] = ((u32)t0 << 16) | (u32)len;
        atomicAdd(&hist[len], 1u);
        ++cnt; t0 = t;
      }
    }
    scnt[b] = (u32)cnt;
  }
  __syncthreads();
  if (tid == 0) {   // suffix sums: nact[s] = #len>s; bucket bases (desc)
    u32 acc = 0; int ml = 0;
    for (int L = 511; L >= 0; --L) {
      cur[L] = acc; nact[L] = acc;
      if (hist[L] && !ml) ml = L;
      acc += hist[L];
    }
    hdr[0] = acc; hdr[1] = (u32)ml;
  }
  __syncthreads();
  if (tid < 32) {   // scatter (within-bucket order arbitrary: prefix prop ok)
    int b = tid; u32 c = scnt[b];
    for (u32 i = 0; i < c; ++i) {
      u32 e = tmp[b * 511 + i];
      u32 len = e & 0xFFFFu, t0 = e >> 16;
      u32 slot = atomicAdd(&cur[len], 1u);
      meta[slot] = ((u32)b << 20) | (t0 << 10) | len;
    }
  }
}

// ---------------------------------------------------------------------------
// Segment-batched LSTM, wave-autonomous tiles. grid=256, block=512 (8 waves).
// Block blk owns h cols [4blk,4blk+4) = 16 gate rows. Wave w -> tiles
// w, w+8, ... of 32 slots each, full K=1152 per wave, no intra-tile barriers.
__global__ __launch_bounds__(512, 1) void lstm_seg_k(
    const float* __restrict__ Whh, const float* __restrict__ Wih,
    const float* __restrict__ embed, const float* __restrict__ bih,
    const float* __restrict__ bhh, const int* __restrict__ actions,
    const unsigned short* __restrict__ zt, const u32* __restrict__ meta,
    const u32* __restrict__ nact, const u32* __restrict__ hdr,
    u64* __restrict__ hsl, float* __restrict__ c_all,
    u64* __restrict__ hs2, u32* __restrict__ gcnt) {
  const int blk = blockIdx.x;
  const int tid = threadIdx.x;
  const int lane = tid & 63;
  const int w = tid >> 6;                 // wave 0..7
  const int ln = lane & 15, lk = lane >> 4;
  const int slane = lane & 31;            // slot sub-index in tile
  const int ehalf = lane >> 5;            // 0: cols 0-1, 1: cols 2-3

  __shared__ alignas(16) unsigned short whh_sw[32 * 64 * 8];   // 32 KB
  __shared__ alignas(16) unsigned short wz_sw[4 * 64 * 8];     // 4 KB
  __shared__ float abias[18][16];
  __shared__ float red[8][32][17];        // wave-private gate transpose

  for (int i = tid; i < 32 * 64 * 8; i += 512) {
    int j = i & 7, L = (i >> 3) & 63, kt = i >> 9;
    int n = L & 15;
    int grow = (n >> 2) * 1024 + blk * 4 + (n & 3);
    int k = kt * 32 + ((L >> 4) << 3) + j;
    whh_sw[i] = f2b(Whh[grow * 1024 + k]);
  }
  for (int i = tid; i < 4 * 64 * 8; i += 512) {
    int j = i & 7, L = (i >> 3) & 63, kt = i >> 9;
    int n = L & 15;
    int grow = (n >> 2) * 1024 + blk * 4 + (n & 3);
    int k = kt * 32 + ((L >> 4) << 3) + j;
    wz_sw[i] = f2b(Wih[grow * 144 + k]);
  }
  for (int i = tid; i < 18 * 16; i += 512) {
    int a = i >> 4, n = i & 15;
    int grow = (n >> 2) * 1024 + blk * 4 + (n & 3);
    float s = bih[grow] + bhh[grow];
    for (int j = 0; j < 16; ++j) s += embed[a * 16 + j] * Wih[grow * 144 + 128 + j];
    abias[a][n] = s;
  }
  __syncthreads();

  const int maxlen = (int)hdr[1];

  for (int s = 0; s < maxlen; ++s) {
    const u32 N = nact[s];                   // active slots (prefix)
    const int ntiles = (int)((N + 31) >> 5);
    const u64* hread = hsl + (size_t)((s & 1) ^ 1) * 2097152;
    u64* hwrite = hsl + (size_t)(s & 1) * 2097152;

    for (int tile = w; tile < ntiles; tile += 8) {
      const u32 sb = (u32)tile << 5;
      const u32 slot = sb + (u32)slane;
      const bool valid = slot < N;
      // meta: each lane for its slot (lanes 32-63 duplicate 0-31)
      const u32 m = valid ? meta[slot] : 0u;
      const u32 b = m >> 20, t0 = (m >> 10) & 1023u, L = m & 1023u;
      const int zrow = (int)(b * 512u + t0 + (u32)s);
      const int orow = (int)(b * 511u + t0 + (u32)s);
      const u32 act = valid ? (u32)actions[zrow] : 0u;
      // broadcast z rows for the two A-subtiles
      const int zr0 = __shfl(zrow, ln, 64);
      const int zr1 = __shfl(zrow, ln + 16, 64);

      f4 acc0 = {0.f, 0.f, 0.f, 0.f};
      f4 acc1 = {0.f, 0.f, 0.f, 0.f};
#pragma unroll
      for (int kz = 0; kz < 4; ++kz) {     // z contribution (K=128)
        s8 a0 = LD8(zt + (size_t)zr0 * 128 + kz * 32 + (lk << 3));
        s8 a1 = LD8(zt + (size_t)zr1 * 128 + kz * 32 + (lk << 3));
        s8 bf = LD8(wz_sw + ((kz * 64 + lane) << 3));
        acc0 = MFMA(a0, bf, acc0);
        acc1 = MFMA(a1, bf, acc1);
      }
      if (s) {  // h contribution (K=1024), full K in this wave
#pragma unroll 4
        for (int kt = 0; kt < 32; ++kt) {
          const int c2 = (kt << 3) + (lk << 1);
          const u64* pa = hread + (size_t)(sb + ln) * 256 + c2;
          const u64* pb = hread + (size_t)(sb + ln + 16) * 256 + c2;
          u64 qa0 = AL(pa), qa1 = AL(pa + 1);
          u64 qb0 = AL(pb), qb1 = AL(pb + 1);
          s8 bf = LD8(whh_sw + ((kt * 64 + lane) << 3));
          union { u64 q[2]; s8 v; } fa, fb;
          fa.q[0] = qa0; fa.q[1] = qa1;
          fb.q[0] = qb0; fb.q[1] = qb1;
          acc0 = MFMA(fa.v, bf, acc0);
          acc1 = MFMA(fb.v, bf, acc1);
        }
      }

      // wave-private transpose: D row(slot)=4*lk+j (+16 for acc1), col=ln
#pragma unroll
      for (int j = 0; j < 4; ++j) {
        red[w][(lk << 2) + j][ln] = acc0[j];
        red[w][16 + (lk << 2) + j][ln] = acc1[j];
      }
      // same-wave DS ordering: reads below wait on lgkmcnt for the writes
      const bool carry = valid && (L > (u32)(s + 1));
      u32 hbits = 0;
#pragma unroll
      for (int e = 0; e < 2; ++e) {   // this lane: slot=slane, cols 2*ehalf+e
        const int eq = (ehalf << 1) + e;
        float gi = red[w][slane][eq]      + abias[act][eq];
        float gf = red[w][slane][4 + eq]  + abias[act][4 + eq];
        float gg = red[w][slane][8 + eq]  + abias[act][8 + eq];
        float go = red[w][slane][12 + eq] + abias[act][12 + eq];
        float* cp = c_all + (((size_t)blk << 13) + slot) * 4 + eq;
        const float cprev = (s && valid) ? *cp : 0.f;
        const float si = sigf(gi), sf = sigf(gf), so = sigf(go);
        const float cn = sf * cprev + si * tanhf_fast(gg);
        const float hn = so * tanhf_fast(cn);
        if (carry) *cp = cn;
        hbits |= ((u32)f2b(hn)) << (16 * e);
      }
      // pack 4 cols: lane<32 has cols 0-1 (low), lane+32 has 2-3 (high)
      const u32 other = (u32)__shfl_xor((int)hbits, 32, 64);
      if (lane < 32 && valid) {
        const u64 hu = ((u64)other << 32) | (u64)hbits;
        hs2[((size_t)blk << 14) + orow] = hu;          // history (plain)
        if (carry) AS(hwrite + (size_t)slot * 256 + blk, hu);  // carry h
      }
    }

    // per-wave drain of carry stores, then block sync, then global barrier
    asm volatile("s_waitcnt vmcnt(0)" ::: "memory");
    __syncthreads();
    if (s + 1 < maxlen) {
      if (tid == 0) {
        __hip_atomic_fetch_add(gcnt + (blk >> 4) * 32, 1u,
                               __ATOMIC_RELAXED, __HIP_MEMORY_SCOPE_AGENT);
        const u32 tgt = (u32)(s + 1) * 16u;
        for (u32 spin = 0; spin < (1u << 20); ++spin) {
          u32 mn = 0xFFFFFFFFu;
#pragma unroll
          for (int g = 0; g < 16; ++g) {
            u32 v = AL32(gcnt + g * 32);
            mn = (v < mn) ? v : mn;
          }
          if (mn >= tgt) break;
          __builtin_amdgcn_s_sleep(1);
        }
      }
      __syncthreads();
    }
  }
}

// ---------------------------------------------------------------------------
// out = hs @ W_out^T (+bias), fused logsumexp on the logmix third.
__global__ __launch_bounds__(256, 2) void out_gemm_k(
    const u64* __restrict__ hs2, const unsigned short* __restrict__ wout,
    const float* __restrict__ b_out, float* __restrict__ out) {
  const int mblk = blockIdx.x, nblk = blockIdx.y;
  const int tid = threadIdx.x, lane = tid & 63, w = tid >> 6;
  const int ln = lane & 15, lk = lane >> 4;
  __shared__ alignas(16) unsigned char smraw[21760];
  unsigned short* bsm = (unsigned short*)smraw;  // [80][136] bf16 B-chunk
  float* ep = (float*)smraw;                     // [64][84] f32 epilogue tile

  const int r0 = mblk * 64 + w * 16;
  f4 acc[5];
#pragma unroll
  for (int s = 0; s < 5; ++s) acc[s] = (f4){0.f, 0.f, 0.f, 0.f};

  for (int kc = 0; kc < 8; ++kc) {  // K chunks of 128
#pragma unroll
    for (int ii = 0; ii < 5; ++ii) {           // 1280 us8 chunks exact
      int i = tid + ii * 256;
      int n = i >> 4, k16 = i & 15;
      us8v v = *reinterpret_cast<const us8v*>(
          wout + (size_t)(nblk * 80 + n) * 1024 + kc * 128 + (k16 << 3));
      *reinterpret_cast<us8v*>(bsm + n * 136 + (k16 << 3)) = v;
    }
    __syncthreads();
#pragma unroll
    for (int ks = 0; ks < 4; ++ks) {
      const int k0 = kc * 128 + ks * 32 + (lk << 3);
      union { u64 q[2]; s8 v; } ua;            // A-frag: 2 x 8B from hs2
      ua.q[0] = hs2[(size_t)(k0 >> 2) * 16384 + r0 + ln];
      ua.q[1] = hs2[((size_t)(k0 >> 2) + 1) * 16384 + r0 + ln];
#pragma unroll
      for (int s = 0; s < 5; ++s) {
        s8 b = LD8(bsm + (s * 16 + ln) * 136 + ks * 32 + (lk << 3));
        acc[s] = MFMA(ua.v, b, acc[s]);
      }
    }
    __syncthreads();
  }

  const int T = nblk >> 3;  // 0 logmix, 1 mu, 2 logstd
  if (T) {
    float* base = out + (size_t)10465280 * T;
    const int lc0 = (nblk - (T << 3)) * 80;
#pragma unroll
    for (int s = 0; s < 5; ++s) {
      const int lc = lc0 + s * 16 + ln;
      const float bias = b_out[T * 640 + lc];
#pragma unroll
      for (int j = 0; j < 4; ++j) {
        const int row = r0 + (lk << 2) + j;
        if (row < 16352) base[(size_t)row * 640 + lc] = acc[s][j] + bias;
      }
    }
  } else {  // logmix: bounce through LDS, per-(row, z-group) logsumexp over 5
#pragma unroll
    for (int s = 0; s < 5; ++s) {
      const float bias = b_out[nblk * 80 + s * 16 + ln];
#pragma unroll
      for (int j = 0; j < 4; ++j)
        ep[(w * 16 + (lk << 2) + j) * 84 + s * 16 + ln] = acc[s][j] + bias;
    }
    __syncthreads();
    for (int task = tid; task < 1024; task += 256) {
      const int rr = task >> 4, grp = task & 15;
      const int row = mblk * 64 + rr;
      const float* e = ep + rr * 84 + grp * 5;
      float v0 = e[0], v1 = e[1], v2 = e[2], v3 = e[3], v4 = e[4];
      float mx = fmaxf(fmaxf(fmaxf(v0, v1), fmaxf(v2, v3)), v4);
      float ssum = expf(v0 - mx) + expf(v1 - mx) + expf(v2 - mx) +
                   expf(v3 - mx) + expf(v4 - mx);
      float lse = mx + logf(ssum);
      if (row < 16352) {
        float* o = out + (size_t)row * 640 + nblk * 80 + grp * 5;
        o[0] = v0 - lse; o[1] = v1 - lse; o[2] = v2 - lse;
        o[3] = v3 - lse; o[4] = v4 - lse;
      }
    }
  }
}

// ---------------------------------------------------------------------------
__global__ __launch_bounds__(256) void donep_k(
    const u64* __restrict__ hs2, const unsigned short* __restrict__ wout,
    const float* __restrict__ b_out, float* __restrict__ out) {
  const int lane = threadIdx.x & 63;
  const int wv = (blockIdx.x * 256 + threadIdx.x) >> 6;  // 2048 waves
  const unsigned short* wrow = wout + (size_t)1920 * 1024 + lane * 16;
  float wl[16];
#pragma unroll
  for (int i = 0; i < 16; ++i) wl[i] = b2f(wrow[i]);
  const float bias = b_out[1920];
  for (int r = wv; r < 16352; r += 2048) {
    float d = 0.f;
#pragma unroll
    for (int j = 0; j < 4; ++j) {   // k = lane*16 + 4j + (0..3)
      union { u64 q; unsigned short h[4]; } u;
      u.q = hs2[(size_t)(lane * 4 + j) * 16384 + r];
#pragma unroll
      for (int i = 0; i < 4; ++i) d += b2f(u.h[i]) * wl[j * 4 + i];
    }
#pragma unroll
    for (int off = 32; off; off >>= 1) d += __shfl_down(d, off, 64);
    if (lane == 0) out[31395840 + r] = d + bias;
  }
}

// ---------------------------------------------------------------------------
extern "C" void kernel_launch(void* const* d_in, const int* in_sizes, int n_in,
                              void* d_out, int out_size, void* d_ws, size_t ws_size,
                              hipStream_t stream) {
  const float* z       = (const float*)d_in[0];
  const int*   actions = (const int*)d_in[1];
  const int*   dones   = (const int*)d_in[2];
  const float* embed   = (const float*)d_in[3];
  const float* Wih     = (const float*)d_in[4];
  const float* Whh     = (const float*)d_in[5];
  const float* bih     = (const float*)d_in[6];
  const float* bhh     = (const float*)d_in[7];
  const float* Wout    = (const float*)d_in[8];
  const float* bout    = (const float*)d_in[9];
  float* out = (float*)d_out;

  if (ws_size < WS_END) return;  // fail visibly rather than corrupt memory

  char* ws = (char*)d_ws;
  u32* gcnt              = (u32*)(ws + WS_GCNT);
  u32* nact              = (u32*)(ws + WS_NACT);
  u32* hdr               = (u32*)(ws + WS_HDR);
  u32* metaA             = (u32*)(ws + WS_META);
  u32* tmp               = (u32*)(ws + WS_TMP);
  unsigned short* zt     = (unsigned short*)(ws + WS_ZT);
  unsigned short* wout16 = (unsigned short*)(ws + WS_WOUT);
  u64* hs2               = (u64*)(ws + WS_HS2);
  // d_out doubles as scratch during the recurrence (overwritten afterwards)
  u64* hsl    = (u64*)d_out;                          // 32MB: 2x8192x2KB
  float* call = (float*)((char*)d_out + 33554432);    // 32MB: 256x8192x16B

  hipMemsetAsync(d_ws, 0, 2048, stream);  // barrier counters only

  seg_build_k<<<1, 256, 0, stream>>>(dones, tmp, metaA, nact, hdr);
  cvt_z_k<<<2048, 256, 0, stream>>>(z, zt);    // overwrites tmp after build
  zero_hs_tail_k<<<32, 256, 0, stream>>>(hs2);
  lstm_seg_k<<<256, 512, 0, stream>>>(Whh, Wih, embed, bih, bhh, actions,
                                      zt, metaA, nact, hdr, hsl, call,
                                      hs2, gcnt);
  cvt_wout_k<<<1921, 256, 0, stream>>>(Wout, wout16);
  out_gemm_k<<<dim3(256, 24), 256, 0, stream>>>(hs2, wout16, bout, out);
  donep_k<<<512, 256, 0, stream>>>(hs2, wout16, bout, out);
}

// Round 15
// 1112.324 us; speedup vs baseline: 3.2439x; 1.3732x over previous
//
#include <hip/hip_runtime.h>
#include <hip/hip_bf16.h>

// ---------------------------------------------------------------------------
// RNNModel (MDN-RNN). Segment algorithm (R9-R14): dones (p=0.5) reset h,c ->
// recurrence splits into segments (max ~15 offsets); sorted desc by len so
// active-at-offset-s = prefix [0,N_s). Ladder h-exchange: region_s at loff[s],
// each (slot,s) address written once (8B agent atomic) and read once.
// R15 FIX: R12-R14's gather used (kt<<6) on a USHORT pointer = kt*64 bf16
//   stride -- double the correct kt*32 (8 u64 = 32 bf16). Wrong h-elements
//   for every kt>=1, next-slot reads for kt>=16 -> deterministic 5.5e-2
//   across all three rounds regardless of coherence treatment. Fix: (kt<<5).
//   (Lesson: identical absmax across different "fixes" = bug outside their
//   domain. The prefetch-staleness theory was never the cause.)
// Kept from R14 (cheap insurance): per-step acquire fence (L1/L2 inv) after
//   the barrier; nothing dirty in L2 (hs2 + c-state via 8B agent atomics,
//   c packed 2xf32/u64, atomic load issued early to hide LLC latency).
// lstm_seg_k: wave-autonomous tiles (R11): 512 thr = 8 waves, wave owns whole
//   tiles (full K=1152), no intra-tile barriers; gate transpose wave-private.
// Proven pieces verbatim: seg_build scan/sort, group-counter barrier per s,
// hs2 layout, out_gemm/donep.
// ---------------------------------------------------------------------------

typedef float f4 __attribute__((ext_vector_type(4)));
typedef short s8 __attribute__((ext_vector_type(8)));
typedef unsigned short us8v __attribute__((ext_vector_type(8)));
typedef unsigned short us4v __attribute__((ext_vector_type(4)));
typedef unsigned long long u64;
typedef unsigned u32;

#define DEV __device__ __forceinline__

DEV unsigned short f2b(float f) {          // fp32 -> bf16 RNE
  unsigned u = __float_as_uint(f);
  return (unsigned short)((u + 0x7FFFu + ((u >> 16) & 1u)) >> 16);
}
DEV float b2f(unsigned short s) { return __uint_as_float(((unsigned)s) << 16); }

DEV f4 MFMA(s8 a, s8 b, f4 c) {
  return __builtin_amdgcn_mfma_f32_16x16x32_bf16(a, b, c, 0, 0, 0);
}
DEV s8 LD8(const unsigned short* p) { return *reinterpret_cast<const s8*>(p); }

DEV u64 AL(const u64* p) {
  return __hip_atomic_load(p, __ATOMIC_RELAXED, __HIP_MEMORY_SCOPE_AGENT);
}
DEV u32 AL32(const u32* p) {
  return __hip_atomic_load(p, __ATOMIC_RELAXED, __HIP_MEMORY_SCOPE_AGENT);
}
DEV void AS(u64* p, u64 v) {
  __hip_atomic_store(p, v, __ATOMIC_RELAXED, __HIP_MEMORY_SCOPE_AGENT);
}

DEV float sigf(float x) {   // 1/(1+e^-x) via v_exp + v_rcp (~1e-6 rel)
  float e = __builtin_amdgcn_exp2f(x * -1.44269504f);
  return __builtin_amdgcn_rcpf(1.f + e);
}
DEV float tanhf_fast(float x) {  // 1 - 2/(e^{2x}+1); saturates correctly
  float e = __builtin_amdgcn_exp2f(x * 2.88539008f);
  return 1.f - 2.f * __builtin_amdgcn_rcpf(e + 1.f);
}

// ---- d_ws layout (bytes), total = proven 41.8MB ----
static constexpr size_t WS_GCNT = 0;        // 16 group counters, 128B apart
static constexpr size_t WS_NACT = 2048;     // N_act[512] u32
static constexpr size_t WS_HDR  = 4096;     // hdr[0]=total, hdr[1]=maxlen
static constexpr size_t WS_META = 4352;     // meta[16384] u32 (ends 69888)
static constexpr size_t WS_LOFF = 69888;    // loff[512] u32 (ends 71936)
static constexpr size_t WS_TMP  = 131072;   // seg_build scratch (pre-zt)
static constexpr size_t WS_ZT   = 131072;   // zt [16384][128] bf16 (4MB)
static constexpr size_t WS_WOUT = 4325376;  // wout16 (3.75MB)
static constexpr size_t WS_HS2  = 8261632;  // hs2 [256][16384] u64 (32MB)
static constexpr size_t WS_END  = 41816064;
// ---- d_out scratch (dead until out GEMMs overwrite) ----
// hsl ladder: <= 16320 slots x 2KB = 33.4MB at d_out+0
// c_all: [256 blk][8192 slot][2 u64(=4 f32)] = 32MB at d_out+34MiB
static constexpr size_t DO_CALL = 35651584;

// ---------------------------------------------------------------------------
__global__ void cvt_wout_k(const float* __restrict__ W, unsigned short* __restrict__ o) {
  int i = blockIdx.x * 256 + threadIdx.x;         // 491776 float4 units exact
  if (i < 491776) {
    const float4 v = reinterpret_cast<const float4*>(W)[i];
    us4v u; u[0] = f2b(v.x); u[1] = f2b(v.y); u[2] = f2b(v.z); u[3] = f2b(v.w);
    reinterpret_cast<us4v*>(o)[i] = u;
  }
}

__global__ void cvt_z_k(const float* __restrict__ z, unsigned short* __restrict__ zt) {
  // z = 32*512*128 f32 = 524288 float4 units exact (linear, layout preserved)
  int i = blockIdx.x * 256 + threadIdx.x;
  if (i < 524288) {
    const float4 v = reinterpret_cast<const float4*>(z)[i];
    us4v u; u[0] = f2b(v.x); u[1] = f2b(v.y); u[2] = f2b(v.z); u[3] = f2b(v.w);
    reinterpret_cast<us4v*>(zt)[i] = u;
  }
}

__global__ void zero_hs_tail_k(u64* __restrict__ hs2) {
  // rows 16352..16383 of all 256 regions
  int i = blockIdx.x * 256 + threadIdx.x;
  if (i < 8192) {
    int region = i >> 5, r = 16352 + (i & 31);
    hs2[(size_t)region * 16384 + r] = 0ull;
  }
}

// ---------------------------------------------------------------------------
// Segment scan + counting sort (desc by len) + ladder offsets. 1 block.
__global__ __launch_bounds__(256) void seg_build_k(
    const int* __restrict__ dones, u32* __restrict__ tmp,
    u32* __restrict__ meta, u32* __restrict__ nact, u32* __restrict__ hdr,
    u32* __restrict__ loff) {
  __shared__ u32 hist[512];
  __shared__ u32 cur[512];
  __shared__ u32 scnt[32];
  const int tid = threadIdx.x;
  for (int i = tid; i < 512; i += 256) hist[i] = 0;
  __syncthreads();
  if (tid < 32) {   // per-batch scan: step t fresh iff t==0 or done[t-1]
    int b = tid, cnt = 0, t0 = 0;
    for (int t = 1; t <= 511; ++t) {
      bool brk = (t == 511) || (dones[b * 512 + t - 1] != 0);
      if (brk) {
        int len = t - t0;
        tmp[b * 511 + cnt] = ((u32)t0 << 16) | (u32)len;
        atomicAdd(&hist[len], 1u);
        ++cnt; t0 = t;
      }
    }
    scnt[b] = (u32)cnt;
  }
  __syncthreads();
  if (tid == 0) {   // suffix sums: nact[s] = #len>s; bucket bases (desc)
    u32 acc = 0; int ml = 0;
    for (int L = 511; L >= 0; --L) {
      cur[L] = acc; nact[L] = acc;
      if (hist[L] && !ml) ml = L;
      acc += hist[L];
    }
    hdr[0] = acc; hdr[1] = (u32)ml;
    u32 off = 0; loff[0] = 0;          // ladder: region s at loff[s] slots
    for (int s2 = 1; s2 <= ml; ++s2) { loff[s2] = off; off += nact[s2]; }
  }
  __syncthreads();
  if (tid < 32) {   // scatter (within-bucket order arbitrary: prefix prop ok)
    int b = tid; u32 c = scnt[b];
    for (u32 i = 0; i < c; ++i) {
      u32 e = tmp[b * 511 + i];
      u32 len = e & 0xFFFFu, t0 = e >> 16;
      u32 slot = atomicAdd(&cur[len], 1u);
      meta[slot] = ((u32)b << 20) | (t0 << 10) | len;
    }
  }
}

// ---------------------------------------------------------------------------
// Segment-batched LSTM, wave-autonomous tiles + ladder exchange + per-step
// acquire fence. grid=256, block=512 (8 waves). Block blk owns h cols
// [4blk,4blk+4).
__global__ __launch_bounds__(512, 1) void lstm_seg_k(
    const float* __restrict__ Whh, const float* __restrict__ Wih,
    const float* __restrict__ embed, const float* __restrict__ bih,
    const float* __restrict__ bhh, const int* __restrict__ actions,
    const unsigned short* __restrict__ zt, const u32* __restrict__ meta,
    const u32* __restrict__ nact, const u32* __restrict__ hdr,
    const u32* __restrict__ loff, u64* __restrict__ hsl,
    u64* __restrict__ c_all, u64* __restrict__ hs2,
    u32* __restrict__ gcnt) {
  const int blk = blockIdx.x;
  const int tid = threadIdx.x;
  const int lane = tid & 63;
  const int w = tid >> 6;                 // wave 0..7
  const int ln = lane & 15, lk = lane >> 4;
  const int slane = lane & 31;            // slot sub-index in tile
  const int ehalf = lane >> 5;            // 0: cols 0-1, 1: cols 2-3

  __shared__ alignas(16) unsigned short whh_sw[32 * 64 * 8];   // 32 KB
  __shared__ alignas(16) unsigned short wz_sw[4 * 64 * 8];     // 4 KB
  __shared__ float abias[18][16];
  __shared__ float red[8][32][17];        // wave-private gate transpose

  for (int i = tid; i < 32 * 64 * 8; i += 512) {
    int j = i & 7, L = (i >> 3) & 63, kt = i >> 9;
    int n = L & 15;
    int grow = (n >> 2) * 1024 + blk * 4 + (n & 3);
    int k = kt * 32 + ((L >> 4) << 3) + j;
    whh_sw[i] = f2b(Whh[grow * 1024 + k]);
  }
  for (int i = tid; i < 4 * 64 * 8; i += 512) {
    int j = i & 7, L = (i >> 3) & 63, kt = i >> 9;
    int n = L & 15;
    int grow = (n >> 2) * 1024 + blk * 4 + (n & 3);
    int k = kt * 32 + ((L >> 4) << 3) + j;
    wz_sw[i] = f2b(Wih[grow * 144 + k]);
  }
  for (int i = tid; i < 18 * 16; i += 512) {
    int a = i >> 4, n = i & 15;
    int grow = (n >> 2) * 1024 + blk * 4 + (n & 3);
    float s = bih[grow] + bhh[grow];
    for (int j = 0; j < 16; ++j) s += embed[a * 16 + j] * Wih[grow * 144 + 128 + j];
    abias[a][n] = s;
  }
  __syncthreads();

  const int maxlen = (int)hdr[1];

  for (int s = 0; s < maxlen; ++s) {
    const u32 N = nact[s];                   // active slots (prefix)
    const int ntiles = (int)((N + 31) >> 5);
    const u64* hread = hsl + (size_t)loff[s] * 256;       // region s (s>=1)
    u64* hwrite = hsl + (size_t)loff[s + 1] * 256;        // region s+1

    for (int tile = w; tile < ntiles; tile += 8) {
      const u32 sb = (u32)tile << 5;
      const u32 slot = sb + (u32)slane;
      const bool valid = slot < N;
      // meta: each lane for its slot (lanes 32-63 duplicate 0-31)
      const u32 m = valid ? meta[slot] : 0u;
      const u32 b = m >> 20, t0 = (m >> 10) & 1023u, L = m & 1023u;
      const int zrow = (int)(b * 512u + t0 + (u32)s);
      const int orow = (int)(b * 511u + t0 + (u32)s);
      const u32 act = valid ? (u32)actions[zrow] : 0u;
      // c-state: 2 f32 packed per u64 per lane; atomic load issued EARLY so
      // LLC latency hides under the MFMA work below. cq==0 -> cprev=0.0f.
      u64 cq = 0;
      if (s && valid)
        cq = AL(c_all + ((size_t)blk << 14) + ((size_t)slot << 1) + ehalf);
      // broadcast z rows for the two A-subtiles
      const int zr0 = __shfl(zrow, ln, 64);
      const int zr1 = __shfl(zrow, ln + 16, 64);

      f4 acc0 = {0.f, 0.f, 0.f, 0.f};
      f4 acc1 = {0.f, 0.f, 0.f, 0.f};
#pragma unroll
      for (int kz = 0; kz < 4; ++kz) {     // z contribution (K=128)
        s8 a0 = LD8(zt + (size_t)zr0 * 128 + kz * 32 + (lk << 3));
        s8 a1 = LD8(zt + (size_t)zr1 * 128 + kz * 32 + (lk << 3));
        s8 bf = LD8(wz_sw + ((kz * 64 + lane) << 3));
        acc0 = MFMA(a0, bf, acc0);
        acc1 = MFMA(a1, bf, acc1);
      }
      if (s) {  // h gather: PLAIN coalesced 16B loads (ladder + acquire inv)
        const u32 rA = sb + (u32)ln;
        const u32 rB = rA + 16u;
        const u32 rAc = (rA < N) ? rA : (N - 1u);   // stay inside region s
        const u32 rBc = (rB < N) ? rB : (N - 1u);
        // ushort-unit base: row*1024 + lk*8; per-kt stride = 32 bf16 (kt<<5).
        // R15 FIX: was (kt<<6) = kt*64 bf16 (double stride) in R12-R14.
        const unsigned short* hrow0 =
            (const unsigned short*)(hread + (size_t)rAc * 256 + (lk << 1));
        const unsigned short* hrow1 =
            (const unsigned short*)(hread + (size_t)rBc * 256 + (lk << 1));
#pragma unroll 4
        for (int kt = 0; kt < 32; ++kt) {
          s8 fa = LD8(hrow0 + (kt << 5));   // +kt*8 u64 = +kt*32 bf16
          s8 fb = LD8(hrow1 + (kt << 5));
          s8 bf = LD8(whh_sw + ((kt * 64 + lane) << 3));
          acc0 = MFMA(fa, bf, acc0);
          acc1 = MFMA(fb, bf, acc1);
        }
      }

      // wave-private transpose: D row(slot)=4*lk+j (+16 for acc1), col=ln
#pragma unroll
      for (int j = 0; j < 4; ++j) {
        red[w][(lk << 2) + j][ln] = acc0[j];
        red[w][16 + (lk << 2) + j][ln] = acc1[j];
      }
      // same-wave DS ordering: reads below wait on lgkmcnt for the writes
      const bool carry = valid && (L > (u32)(s + 1));
      u32 hbits = 0;
      u32 cbits0 = 0, cbits1 = 0;
#pragma unroll
      for (int e = 0; e < 2; ++e) {   // this lane: slot=slane, cols 2*ehalf+e
        const int eq = (ehalf << 1) + e;
        float gi = red[w][slane][eq]      + abias[act][eq];
        float gf = red[w][slane][4 + eq]  + abias[act][4 + eq];
        float gg = red[w][slane][8 + eq]  + abias[act][8 + eq];
        float go = red[w][slane][12 + eq] + abias[act][12 + eq];
        const float cprev = (e == 0) ? __uint_as_float((u32)cq)
                                     : __uint_as_float((u32)(cq >> 32));
        const float si = sigf(gi), sf = sigf(gf), so = sigf(go);
        const float cn = sf * cprev + si * tanhf_fast(gg);
        const float hn = so * tanhf_fast(cn);
        if (e == 0) cbits0 = __float_as_uint(cn); else cbits1 = __float_as_uint(cn);
        hbits |= ((u32)f2b(hn)) << (16 * e);
      }
      if (carry)   // fp32 c carry, agent atomic (write-through, never dirty)
        AS(c_all + ((size_t)blk << 14) + ((size_t)slot << 1) + ehalf,
           ((u64)cbits1 << 32) | (u64)cbits0);
      // pack 4 cols: lane<32 has cols 0-1 (low), lane+32 has 2-3 (high)
      const u32 other = (u32)__shfl_xor((int)hbits, 32, 64);
      if (lane < 32 && valid) {
        const u64 hu = ((u64)other << 32) | (u64)hbits;
        AS(&hs2[((size_t)blk << 14) + orow], hu);      // history (atomic)
        if (carry) AS(hwrite + (size_t)slot * 256 + blk, hu);  // carry h
      }
    }

    // per-wave drain of stores, block sync, global barrier, acquire inv
    asm volatile("s_waitcnt vmcnt(0)" ::: "memory");
    __syncthreads();
    if (s + 1 < maxlen) {
      if (tid == 0) {
        __hip_atomic_fetch_add(gcnt + (blk >> 4) * 32, 1u,
                               __ATOMIC_RELAXED, __HIP_MEMORY_SCOPE_AGENT);
        const u32 tgt = (u32)(s + 1) * 16u;
        for (u32 spin = 0; spin < (1u << 20); ++spin) {
          u32 mn = 0xFFFFFFFFu;
#pragma unroll
          for (int g = 0; g < 16; ++g) {
            u32 v = AL32(gcnt + g * 32);
            mn = (v < mn) ? v : mn;
          }
          if (mn >= tgt) break;
          __builtin_amdgcn_s_sleep(1);
        }
        // architected acquire: invalidate this CU's L1 + XCD's L2 (clean
        // lines only matter -- nothing dirty lives in L2 during this kernel).
        __builtin_amdgcn_fence(__ATOMIC_ACQUIRE, "agent");
      }
      __syncthreads();
    }
  }
}

// ---------------------------------------------------------------------------
// out = hs @ W_out^T (+bias), fused logsumexp on the logmix third.
__global__ __launch_bounds__(256, 2) void out_gemm_k(
    const u64* __restrict__ hs2, const unsigned short* __restrict__ wout,
    const float* __restrict__ b_out, float* __restrict__ out) {
  const int mblk = blockIdx.x, nblk = blockIdx.y;
  const int tid = threadIdx.x, lane = tid & 63, w = tid >> 6;
  const int ln = lane & 15, lk = lane >> 4;
  __shared__ alignas(16) unsigned char smraw[21760];
  unsigned short* bsm = (unsigned short*)smraw;  // [80][136] bf16 B-chunk
  float* ep = (float*)smraw;                     // [64][84] f32 epilogue tile

  const int r0 = mblk * 64 + w * 16;
  f4 acc[5];
#pragma unroll
  for (int s = 0; s < 5; ++s) acc[s] = (f4){0.f, 0.f, 0.f, 0.f};

  for (int kc = 0; kc < 8; ++kc) {  // K chunks of 128
#pragma unroll
    for (int ii = 0; ii < 5; ++ii) {           // 1280 us8 chunks exact
      int i = tid + ii * 256;
      int n = i >> 4, k16 = i & 15;
      us8v v = *reinterpret_cast<const us8v*>(
          wout + (size_t)(nblk * 80 + n) * 1024 + kc * 128 + (k16 << 3));
      *reinterpret_cast<us8v*>(bsm + n * 136 + (k16 << 3)) = v;
    }
    __syncthreads();
#pragma unroll
    for (int ks = 0; ks < 4; ++ks) {
      const int k0 = kc * 128 + ks * 32 + (lk << 3);
      union { u64 q[2]; s8 v; } ua;            // A-frag: 2 x 8B from hs2
      ua.q[0] = hs2[(size_t)(k0 >> 2) * 16384 + r0 + ln];
      ua.q[1] = hs2[((size_t)(k0 >> 2) + 1) * 16384 + r0 + ln];
#pragma unroll
      for (int s = 0; s < 5; ++s) {
        s8 b = LD8(bsm + (s * 16 + ln) * 136 + ks * 32 + (lk << 3));
        acc[s] = MFMA(ua.v, b, acc[s]);
      }
    }
    __syncthreads();
  }

  const int T = nblk >> 3;  // 0 logmix, 1 mu, 2 logstd
  if (T) {
    float* base = out + (size_t)10465280 * T;
    const int lc0 = (nblk - (T << 3)) * 80;
#pragma unroll
    for (int s = 0; s < 5; ++s) {
      const int lc = lc0 + s * 16 + ln;
      const float bias = b_out[T * 640 + lc];
#pragma unroll
      for (int j = 0; j < 4; ++j) {
        const int row = r0 + (lk << 2) + j;
        if (row < 16352) base[(size_t)row * 640 + lc] = acc[s][j] + bias;
      }
    }
  } else {  // logmix: bounce through LDS, per-(row, z-group) logsumexp over 5
#pragma unroll
    for (int s = 0; s < 5; ++s) {
      const float bias = b_out[nblk * 80 + s * 16 + ln];
#pragma unroll
      for (int j = 0; j < 4; ++j)
        ep[(w * 16 + (lk << 2) + j) * 84 + s * 16 + ln] = acc[s][j] + bias;
    }
    __syncthreads();
    for (int task = tid; task < 1024; task += 256) {
      const int rr = task >> 4, grp = task & 15;
      const int row = mblk * 64 + rr;
      const float* e = ep + rr * 84 + grp * 5;
      float v0 = e[0], v1 = e[1], v2 = e[2], v3 = e[3], v4 = e[4];
      float mx = fmaxf(fmaxf(fmaxf(v0, v1), fmaxf(v2, v3)), v4);
      float ssum = expf(v0 - mx) + expf(v1 - mx) + expf(v2 - mx) +
                   expf(v3 - mx) + expf(v4 - mx);
      float lse = mx + logf(ssum);
      if (row < 16352) {
        float* o = out + (size_t)row * 640 + nblk * 80 + grp * 5;
        o[0] = v0 - lse; o[1] = v1 - lse; o[2] = v2 - lse;
        o[3] = v3 - lse; o[4] = v4 - lse;
      }
    }
  }
}

// ---------------------------------------------------------------------------
__global__ __launch_bounds__(256) void donep_k(
    const u64* __restrict__ hs2, const unsigned short* __restrict__ wout,
    const float* __restrict__ b_out, float* __restrict__ out) {
  const int lane = threadIdx.x & 63;
  const int wv = (blockIdx.x * 256 + threadIdx.x) >> 6;  // 2048 waves
  const unsigned short* wrow = wout + (size_t)1920 * 1024 + lane * 16;
  float wl[16];
#pragma unroll
  for (int i = 0; i < 16; ++i) wl[i] = b2f(wrow[i]);
  const float bias = b_out[1920];
  for (int r = wv; r < 16352; r += 2048) {
    float d = 0.f;
#pragma unroll
    for (int j = 0; j < 4; ++j) {   // k = lane*16 + 4j + (0..3)
      union { u64 q; unsigned short h[4]; } u;
      u.q = hs2[(size_t)(lane * 4 + j) * 16384 + r];
#pragma unroll
      for (int i = 0; i < 4; ++i) d += b2f(u.h[i]) * wl[j * 4 + i];
    }
#pragma unroll
    for (int off = 32; off; off >>= 1) d += __shfl_down(d, off, 64);
    if (lane == 0) out[31395840 + r] = d + bias;
  }
}

// ---------------------------------------------------------------------------
extern "C" void kernel_launch(void* const* d_in, const int* in_sizes, int n_in,
                              void* d_out, int out_size, void* d_ws, size_t ws_size,
                              hipStream_t stream) {
  const float* z       = (const float*)d_in[0];
  const int*   actions = (const int*)d_in[1];
  const int*   dones   = (const int*)d_in[2];
  const float* embed   = (const float*)d_in[3];
  const float* Wih     = (const float*)d_in[4];
  const float* Whh     = (const float*)d_in[5];
  const float* bih     = (const float*)d_in[6];
  const float* bhh     = (const float*)d_in[7];
  const float* Wout    = (const float*)d_in[8];
  const float* bout    = (const float*)d_in[9];
  float* out = (float*)d_out;

  if (ws_size < WS_END) return;  // fail visibly rather than corrupt memory

  char* ws = (char*)d_ws;
  u32* gcnt              = (u32*)(ws + WS_GCNT);
  u32* nact              = (u32*)(ws + WS_NACT);
  u32* hdr               = (u32*)(ws + WS_HDR);
  u32* metaA             = (u32*)(ws + WS_META);
  u32* loff              = (u32*)(ws + WS_LOFF);
  u32* tmp               = (u32*)(ws + WS_TMP);
  unsigned short* zt     = (unsigned short*)(ws + WS_ZT);
  unsigned short* wout16 = (unsigned short*)(ws + WS_WOUT);
  u64* hs2               = (u64*)(ws + WS_HS2);
  // d_out doubles as scratch during the recurrence (overwritten afterwards)
  u64* hsl   = (u64*)d_out;                          // ladder <= 33.4MB
  u64* call  = (u64*)((char*)d_out + DO_CALL);       // 32MB c-state (packed)

  hipMemsetAsync(d_ws, 0, 2048, stream);  // barrier counters only

  seg_build_k<<<1, 256, 0, stream>>>(dones, tmp, metaA, nact, hdr, loff);
  cvt_z_k<<<2048, 256, 0, stream>>>(z, zt);    // overwrites tmp after build
  zero_hs_tail_k<<<32, 256, 0, stream>>>(hs2);
  lstm_seg_k<<<256, 512, 0, stream>>>(Whh, Wih, embed, bih, bhh, actions,
                                      zt, metaA, nact, hdr, loff, hsl, call,
                                      hs2, gcnt);
  cvt_wout_k<<<1921, 256, 0, stream>>>(Wout, wout16);
  out_gemm_k<<<dim3(256, 24), 256, 0, stream>>>(hs2, wout16, bout, out);
  donep_k<<<512, 256, 0, stream>>>(hs2, wout16, bout, out);
}

// Round 16
// 1082.246 us; speedup vs baseline: 3.3341x; 1.0278x over previous
//
#include <hip/hip_runtime.h>
#include <hip/hip_bf16.h>

// ---------------------------------------------------------------------------
// RNNModel (MDN-RNN). Segment algorithm (R9-R15): dones (p=0.5) reset h,c ->
// recurrence splits into segments (max ~15 offsets); sorted desc by len so
// active-at-offset-s = prefix [0,N_s). Ladder h-exchange: region_s at loff[s],
// each (slot,s) address written once (8B agent atomic -> LLC), read once at
// the next step with PLAIN coalesced 16B loads (clamped inside region; R15).
// R16 (TLP/ILP only -- no protocol or arithmetic change from passing R15):
//   - block 512 -> 1024 threads (16 waves): tiles/wave 64->32, waves/SIMD
//     2->4. R15 counters (MfmaUtil 4.3%, occ 24.5%) showed unhidden LLC
//     latency with nothing to switch to; this doubles hiding capacity.
//   - gather loop unroll 4 -> 8: 16 loads in flight per chunk.
// Kept (proven): per-step acquire fence (L1/L2 inv) after the barrier;
//   nothing dirty in L2 (hs2 + c via 8B agent atomics, c packed 2xf32/u64);
//   wave-autonomous tiles (full K=1152/wave, no intra-tile barriers);
//   seg_build scan/sort, group-counter barrier per s, hs2, out_gemm/donep.
// ---------------------------------------------------------------------------

typedef float f4 __attribute__((ext_vector_type(4)));
typedef short s8 __attribute__((ext_vector_type(8)));
typedef unsigned short us8v __attribute__((ext_vector_type(8)));
typedef unsigned short us4v __attribute__((ext_vector_type(4)));
typedef unsigned long long u64;
typedef unsigned u32;

#define DEV __device__ __forceinline__

DEV unsigned short f2b(float f) {          // fp32 -> bf16 RNE
  unsigned u = __float_as_uint(f);
  return (unsigned short)((u + 0x7FFFu + ((u >> 16) & 1u)) >> 16);
}
DEV float b2f(unsigned short s) { return __uint_as_float(((unsigned)s) << 16); }

DEV f4 MFMA(s8 a, s8 b, f4 c) {
  return __builtin_amdgcn_mfma_f32_16x16x32_bf16(a, b, c, 0, 0, 0);
}
DEV s8 LD8(const unsigned short* p) { return *reinterpret_cast<const s8*>(p); }

DEV u64 AL(const u64* p) {
  return __hip_atomic_load(p, __ATOMIC_RELAXED, __HIP_MEMORY_SCOPE_AGENT);
}
DEV u32 AL32(const u32* p) {
  return __hip_atomic_load(p, __ATOMIC_RELAXED, __HIP_MEMORY_SCOPE_AGENT);
}
DEV void AS(u64* p, u64 v) {
  __hip_atomic_store(p, v, __ATOMIC_RELAXED, __HIP_MEMORY_SCOPE_AGENT);
}

DEV float sigf(float x) {   // 1/(1+e^-x) via v_exp + v_rcp (~1e-6 rel)
  float e = __builtin_amdgcn_exp2f(x * -1.44269504f);
  return __builtin_amdgcn_rcpf(1.f + e);
}
DEV float tanhf_fast(float x) {  // 1 - 2/(e^{2x}+1); saturates correctly
  float e = __builtin_amdgcn_exp2f(x * 2.88539008f);
  return 1.f - 2.f * __builtin_amdgcn_rcpf(e + 1.f);
}

// ---- d_ws layout (bytes), total = proven 41.8MB ----
static constexpr size_t WS_GCNT = 0;        // 16 group counters, 128B apart
static constexpr size_t WS_NACT = 2048;     // N_act[512] u32
static constexpr size_t WS_HDR  = 4096;     // hdr[0]=total, hdr[1]=maxlen
static constexpr size_t WS_META = 4352;     // meta[16384] u32 (ends 69888)
static constexpr size_t WS_LOFF = 69888;    // loff[512] u32 (ends 71936)
static constexpr size_t WS_TMP  = 131072;   // seg_build scratch (pre-zt)
static constexpr size_t WS_ZT   = 131072;   // zt [16384][128] bf16 (4MB)
static constexpr size_t WS_WOUT = 4325376;  // wout16 (3.75MB)
static constexpr size_t WS_HS2  = 8261632;  // hs2 [256][16384] u64 (32MB)
static constexpr size_t WS_END  = 41816064;
// ---- d_out scratch (dead until out GEMMs overwrite) ----
// hsl ladder: <= 16320 slots x 2KB = 33.4MB at d_out+0
// c_all: [256 blk][8192 slot][2 u64(=4 f32)] = 32MB at d_out+34MiB
static constexpr size_t DO_CALL = 35651584;

// ---------------------------------------------------------------------------
__global__ void cvt_wout_k(const float* __restrict__ W, unsigned short* __restrict__ o) {
  int i = blockIdx.x * 256 + threadIdx.x;         // 491776 float4 units exact
  if (i < 491776) {
    const float4 v = reinterpret_cast<const float4*>(W)[i];
    us4v u; u[0] = f2b(v.x); u[1] = f2b(v.y); u[2] = f2b(v.z); u[3] = f2b(v.w);
    reinterpret_cast<us4v*>(o)[i] = u;
  }
}

__global__ void cvt_z_k(const float* __restrict__ z, unsigned short* __restrict__ zt) {
  // z = 32*512*128 f32 = 524288 float4 units exact (linear, layout preserved)
  int i = blockIdx.x * 256 + threadIdx.x;
  if (i < 524288) {
    const float4 v = reinterpret_cast<const float4*>(z)[i];
    us4v u; u[0] = f2b(v.x); u[1] = f2b(v.y); u[2] = f2b(v.z); u[3] = f2b(v.w);
    reinterpret_cast<us4v*>(zt)[i] = u;
  }
}

__global__ void zero_hs_tail_k(u64* __restrict__ hs2) {
  // rows 16352..16383 of all 256 regions
  int i = blockIdx.x * 256 + threadIdx.x;
  if (i < 8192) {
    int region = i >> 5, r = 16352 + (i & 31);
    hs2[(size_t)region * 16384 + r] = 0ull;
  }
}

// ---------------------------------------------------------------------------
// Segment scan + counting sort (desc by len) + ladder offsets. 1 block.
__global__ __launch_bounds__(256) void seg_build_k(
    const int* __restrict__ dones, u32* __restrict__ tmp,
    u32* __restrict__ meta, u32* __restrict__ nact, u32* __restrict__ hdr,
    u32* __restrict__ loff) {
  __shared__ u32 hist[512];
  __shared__ u32 cur[512];
  __shared__ u32 scnt[32];
  const int tid = threadIdx.x;
  for (int i = tid; i < 512; i += 256) hist[i] = 0;
  __syncthreads();
  if (tid < 32) {   // per-batch scan: step t fresh iff t==0 or done[t-1]
    int b = tid, cnt = 0, t0 = 0;
    for (int t = 1; t <= 511; ++t) {
      bool brk = (t == 511) || (dones[b * 512 + t - 1] != 0);
      if (brk) {
        int len = t - t0;
        tmp[b * 511 + cnt] = ((u32)t0 << 16) | (u32)len;
        atomicAdd(&hist[len], 1u);
        ++cnt; t0 = t;
      }
    }
    scnt[b] = (u32)cnt;
  }
  __syncthreads();
  if (tid == 0) {   // suffix sums: nact[s] = #len>s; bucket bases (desc)
    u32 acc = 0; int ml = 0;
    for (int L = 511; L >= 0; --L) {
      cur[L] = acc; nact[L] = acc;
      if (hist[L] && !ml) ml = L;
      acc += hist[L];
    }
    hdr[0] = acc; hdr[1] = (u32)ml;
    u32 off = 0; loff[0] = 0;          // ladder: region s at loff[s] slots
    for (int s2 = 1; s2 <= ml; ++s2) { loff[s2] = off; off += nact[s2]; }
  }
  __syncthreads();
  if (tid < 32) {   // scatter (within-bucket order arbitrary: prefix prop ok)
    int b = tid; u32 c = scnt[b];
    for (u32 i = 0; i < c; ++i) {
      u32 e = tmp[b * 511 + i];
      u32 len = e & 0xFFFFu, t0 = e >> 16;
      u32 slot = atomicAdd(&cur[len], 1u);
      meta[slot] = ((u32)b << 20) | (t0 << 10) | len;
    }
  }
}

// ---------------------------------------------------------------------------
// Segment-batched LSTM, wave-autonomous tiles + ladder exchange + per-step
// acquire fence. grid=256, block=1024 (16 waves). Block blk owns h cols
// [4blk,4blk+4). Wave w -> tiles w, w+16, ...
__global__ __launch_bounds__(1024, 1) void lstm_seg_k(
    const float* __restrict__ Whh, const float* __restrict__ Wih,
    const float* __restrict__ embed, const float* __restrict__ bih,
    const float* __restrict__ bhh, const int* __restrict__ actions,
    const unsigned short* __restrict__ zt, const u32* __restrict__ meta,
    const u32* __restrict__ nact, const u32* __restrict__ hdr,
    const u32* __restrict__ loff, u64* __restrict__ hsl,
    u64* __restrict__ c_all, u64* __restrict__ hs2,
    u32* __restrict__ gcnt) {
  const int blk = blockIdx.x;
  const int tid = threadIdx.x;
  const int lane = tid & 63;
  const int w = tid >> 6;                 // wave 0..15
  const int ln = lane & 15, lk = lane >> 4;
  const int slane = lane & 31;            // slot sub-index in tile
  const int ehalf = lane >> 5;            // 0: cols 0-1, 1: cols 2-3

  __shared__ alignas(16) unsigned short whh_sw[32 * 64 * 8];   // 32 KB
  __shared__ alignas(16) unsigned short wz_sw[4 * 64 * 8];     // 4 KB
  __shared__ float abias[18][16];
  __shared__ float red[16][32][17];       // wave-private gate transpose ~35KB

  for (int i = tid; i < 32 * 64 * 8; i += 1024) {
    int j = i & 7, L = (i >> 3) & 63, kt = i >> 9;
    int n = L & 15;
    int grow = (n >> 2) * 1024 + blk * 4 + (n & 3);
    int k = kt * 32 + ((L >> 4) << 3) + j;
    whh_sw[i] = f2b(Whh[grow * 1024 + k]);
  }
  for (int i = tid; i < 4 * 64 * 8; i += 1024) {
    int j = i & 7, L = (i >> 3) & 63, kt = i >> 9;
    int n = L & 15;
    int grow = (n >> 2) * 1024 + blk * 4 + (n & 3);
    int k = kt * 32 + ((L >> 4) << 3) + j;
    wz_sw[i] = f2b(Wih[grow * 144 + k]);
  }
  for (int i = tid; i < 18 * 16; i += 1024) {
    int a = i >> 4, n = i & 15;
    int grow = (n >> 2) * 1024 + blk * 4 + (n & 3);
    float s = bih[grow] + bhh[grow];
    for (int j = 0; j < 16; ++j) s += embed[a * 16 + j] * Wih[grow * 144 + 128 + j];
    abias[a][n] = s;
  }
  __syncthreads();

  const int maxlen = (int)hdr[1];

  for (int s = 0; s < maxlen; ++s) {
    const u32 N = nact[s];                   // active slots (prefix)
    const int ntiles = (int)((N + 31) >> 5);
    const u64* hread = hsl + (size_t)loff[s] * 256;       // region s (s>=1)
    u64* hwrite = hsl + (size_t)loff[s + 1] * 256;        // region s+1

    for (int tile = w; tile < ntiles; tile += 16) {
      const u32 sb = (u32)tile << 5;
      const u32 slot = sb + (u32)slane;
      const bool valid = slot < N;
      // meta: each lane for its slot (lanes 32-63 duplicate 0-31)
      const u32 m = valid ? meta[slot] : 0u;
      const u32 b = m >> 20, t0 = (m >> 10) & 1023u, L = m & 1023u;
      const int zrow = (int)(b * 512u + t0 + (u32)s);
      const int orow = (int)(b * 511u + t0 + (u32)s);
      const u32 act = valid ? (u32)actions[zrow] : 0u;
      // c-state: 2 f32 packed per u64 per lane; atomic load issued EARLY so
      // LLC latency hides under the MFMA work below. cq==0 -> cprev=0.0f.
      u64 cq = 0;
      if (s && valid)
        cq = AL(c_all + ((size_t)blk << 14) + ((size_t)slot << 1) + ehalf);
      // broadcast z rows for the two A-subtiles
      const int zr0 = __shfl(zrow, ln, 64);
      const int zr1 = __shfl(zrow, ln + 16, 64);

      f4 acc0 = {0.f, 0.f, 0.f, 0.f};
      f4 acc1 = {0.f, 0.f, 0.f, 0.f};
#pragma unroll
      for (int kz = 0; kz < 4; ++kz) {     // z contribution (K=128)
        s8 a0 = LD8(zt + (size_t)zr0 * 128 + kz * 32 + (lk << 3));
        s8 a1 = LD8(zt + (size_t)zr1 * 128 + kz * 32 + (lk << 3));
        s8 bf = LD8(wz_sw + ((kz * 64 + lane) << 3));
        acc0 = MFMA(a0, bf, acc0);
        acc1 = MFMA(a1, bf, acc1);
      }
      if (s) {  // h gather: PLAIN coalesced 16B loads (ladder; clamped)
        const u32 rA = sb + (u32)ln;
        const u32 rB = rA + 16u;
        const u32 rAc = (rA < N) ? rA : (N - 1u);   // stay inside region s
        const u32 rBc = (rB < N) ? rB : (N - 1u);
        const unsigned short* hrow0 =
            (const unsigned short*)(hread + (size_t)rAc * 256 + (lk << 1));
        const unsigned short* hrow1 =
            (const unsigned short*)(hread + (size_t)rBc * 256 + (lk << 1));
#pragma unroll 8
        for (int kt = 0; kt < 32; ++kt) {
          s8 fa = LD8(hrow0 + (kt << 5));   // +kt*8 u64 = +kt*32 bf16
          s8 fb = LD8(hrow1 + (kt << 5));
          s8 bf = LD8(whh_sw + ((kt * 64 + lane) << 3));
          acc0 = MFMA(fa, bf, acc0);
          acc1 = MFMA(fb, bf, acc1);
        }
      }

      // wave-private transpose: D row(slot)=4*lk+j (+16 for acc1), col=ln
#pragma unroll
      for (int j = 0; j < 4; ++j) {
        red[w][(lk << 2) + j][ln] = acc0[j];
        red[w][16 + (lk << 2) + j][ln] = acc1[j];
      }
      // same-wave DS ordering: reads below wait on lgkmcnt for the writes
      const bool carry = valid && (L > (u32)(s + 1));
      u32 hbits = 0;
      u32 cbits0 = 0, cbits1 = 0;
#pragma unroll
      for (int e = 0; e < 2; ++e) {   // this lane: slot=slane, cols 2*ehalf+e
        const int eq = (ehalf << 1) + e;
        float gi = red[w][slane][eq]      + abias[act][eq];
        float gf = red[w][slane][4 + eq]  + abias[act][4 + eq];
        float gg = red[w][slane][8 + eq]  + abias[act][8 + eq];
        float go = red[w][slane][12 + eq] + abias[act][12 + eq];
        const float cprev = (e == 0) ? __uint_as_float((u32)cq)
                                     : __uint_as_float((u32)(cq >> 32));
        const float si = sigf(gi), sf = sigf(gf), so = sigf(go);
        const float cn = sf * cprev + si * tanhf_fast(gg);
        const float hn = so * tanhf_fast(cn);
        if (e == 0) cbits0 = __float_as_uint(cn); else cbits1 = __float_as_uint(cn);
        hbits |= ((u32)f2b(hn)) << (16 * e);
      }
      if (carry)   // fp32 c carry, agent atomic (write-through, never dirty)
        AS(c_all + ((size_t)blk << 14) + ((size_t)slot << 1) + ehalf,
           ((u64)cbits1 << 32) | (u64)cbits0);
      // pack 4 cols: lane<32 has cols 0-1 (low), lane+32 has 2-3 (high)
      const u32 other = (u32)__shfl_xor((int)hbits, 32, 64);
      if (lane < 32 && valid) {
        const u64 hu = ((u64)other << 32) | (u64)hbits;
        AS(&hs2[((size_t)blk << 14) + orow], hu);      // history (atomic)
        if (carry) AS(hwrite + (size_t)slot * 256 + blk, hu);  // carry h
      }
    }

    // per-wave drain of stores, block sync, global barrier, acquire inv
    asm volatile("s_waitcnt vmcnt(0)" ::: "memory");
    __syncthreads();
    if (s + 1 < maxlen) {
      if (tid == 0) {
        __hip_atomic_fetch_add(gcnt + (blk >> 4) * 32, 1u,
                               __ATOMIC_RELAXED, __HIP_MEMORY_SCOPE_AGENT);
        const u32 tgt = (u32)(s + 1) * 16u;
        for (u32 spin = 0; spin < (1u << 20); ++spin) {
          u32 mn = 0xFFFFFFFFu;
#pragma unroll
          for (int g = 0; g < 16; ++g) {
            u32 v = AL32(gcnt + g * 32);
            mn = (v < mn) ? v : mn;
          }
          if (mn >= tgt) break;
          __builtin_amdgcn_s_sleep(1);
        }
        // architected acquire: invalidate this CU's L1 + XCD's L2 (clean
        // lines only matter -- nothing dirty lives in L2 during this kernel).
        __builtin_amdgcn_fence(__ATOMIC_ACQUIRE, "agent");
      }
      __syncthreads();
    }
  }
}

// ---------------------------------------------------------------------------
// out = hs @ W_out^T (+bias), fused logsumexp on the logmix third.
__global__ __launch_bounds__(256, 2) void out_gemm_k(
    const u64* __restrict__ hs2, const unsigned short* __restrict__ wout,
    const float* __restrict__ b_out, float* __restrict__ out) {
  const int mblk = blockIdx.x, nblk = blockIdx.y;
  const int tid = threadIdx.x, lane = tid & 63, w = tid >> 6;
  const int ln = lane & 15, lk = lane >> 4;
  __shared__ alignas(16) unsigned char smraw[21760];
  unsigned short* bsm = (unsigned short*)smraw;  // [80][136] bf16 B-chunk
  float* ep = (float*)smraw;                     // [64][84] f32 epilogue tile

  const int r0 = mblk * 64 + w * 16;
  f4 acc[5];
#pragma unroll
  for (int s = 0; s < 5; ++s) acc[s] = (f4){0.f, 0.f, 0.f, 0.f};

  for (int kc = 0; kc < 8; ++kc) {  // K chunks of 128
#pragma unroll
    for (int ii = 0; ii < 5; ++ii) {           // 1280 us8 chunks exact
      int i = tid + ii * 256;
      int n = i >> 4, k16 = i & 15;
      us8v v = *reinterpret_cast<const us8v*>(
          wout + (size_t)(nblk * 80 + n) * 1024 + kc * 128 + (k16 << 3));
      *reinterpret_cast<us8v*>(bsm + n * 136 + (k16 << 3)) = v;
    }
    __syncthreads();
#pragma unroll
    for (int ks = 0; ks < 4; ++ks) {
      const int k0 = kc * 128 + ks * 32 + (lk << 3);
      union { u64 q[2]; s8 v; } ua;            // A-frag: 2 x 8B from hs2
      ua.q[0] = hs2[(size_t)(k0 >> 2) * 16384 + r0 + ln];
      ua.q[1] = hs2[((size_t)(k0 >> 2) + 1) * 16384 + r0 + ln];
#pragma unroll
      for (int s = 0; s < 5; ++s) {
        s8 b = LD8(bsm + (s * 16 + ln) * 136 + ks * 32 + (lk << 3));
        acc[s] = MFMA(ua.v, b, acc[s]);
      }
    }
    __syncthreads();
  }

  const int T = nblk >> 3;  // 0 logmix, 1 mu, 2 logstd
  if (T) {
    float* base = out + (size_t)10465280 * T;
    const int lc0 = (nblk - (T << 3)) * 80;
#pragma unroll
    for (int s = 0; s < 5; ++s) {
      const int lc = lc0 + s * 16 + ln;
      const float bias = b_out[T * 640 + lc];
#pragma unroll
      for (int j = 0; j < 4; ++j) {
        const int row = r0 + (lk << 2) + j;
        if (row < 16352) base[(size_t)row * 640 + lc] = acc[s][j] + bias;
      }
    }
  } else {  // logmix: bounce through LDS, per-(row, z-group) logsumexp over 5
#pragma unroll
    for (int s = 0; s < 5; ++s) {
      const float bias = b_out[nblk * 80 + s * 16 + ln];
#pragma unroll
      for (int j = 0; j < 4; ++j)
        ep[(w * 16 + (lk << 2) + j) * 84 + s * 16 + ln] = acc[s][j] + bias;
    }
    __syncthreads();
    for (int task = tid; task < 1024; task += 256) {
      const int rr = task >> 4, grp = task & 15;
      const int row = mblk * 64 + rr;
      const float* e = ep + rr * 84 + grp * 5;
      float v0 = e[0], v1 = e[1], v2 = e[2], v3 = e[3], v4 = e[4];
      float mx = fmaxf(fmaxf(fmaxf(v0, v1), fmaxf(v2, v3)), v4);
      float ssum = expf(v0 - mx) + expf(v1 - mx) + expf(v2 - mx) +
                   expf(v3 - mx) + expf(v4 - mx);
      float lse = mx + logf(ssum);
      if (row < 16352) {
        float* o = out + (size_t)row * 640 + nblk * 80 + grp * 5;
        o[0] = v0 - lse; o[1] = v1 - lse; o[2] = v2 - lse;
        o[3] = v3 - lse; o[4] = v4 - lse;
      }
    }
  }
}

// ---------------------------------------------------------------------------
__global__ __launch_bounds__(256) void donep_k(
    const u64* __restrict__ hs2, const unsigned short* __restrict__ wout,
    const float* __restrict__ b_out, float* __restrict__ out) {
  const int lane = threadIdx.x & 63;
  const int wv = (blockIdx.x * 256 + threadIdx.x) >> 6;  // 2048 waves
  const unsigned short* wrow = wout + (size_t)1920 * 1024 + lane * 16;
  float wl[16];
#pragma unroll
  for (int i = 0; i < 16; ++i) wl[i] = b2f(wrow[i]);
  const float bias = b_out[1920];
  for (int r = wv; r < 16352; r += 2048) {
    float d = 0.f;
#pragma unroll
    for (int j = 0; j < 4; ++j) {   // k = lane*16 + 4j + (0..3)
      union { u64 q; unsigned short h[4]; } u;
      u.q = hs2[(size_t)(lane * 4 + j) * 16384 + r];
#pragma unroll
      for (int i = 0; i < 4; ++i) d += b2f(u.h[i]) * wl[j * 4 + i];
    }
#pragma unroll
    for (int off = 32; off; off >>= 1) d += __shfl_down(d, off, 64);
    if (lane == 0) out[31395840 + r] = d + bias;
  }
}

// ---------------------------------------------------------------------------
extern "C" void kernel_launch(void* const* d_in, const int* in_sizes, int n_in,
                              void* d_out, int out_size, void* d_ws, size_t ws_size,
                              hipStream_t stream) {
  const float* z       = (const float*)d_in[0];
  const int*   actions = (const int*)d_in[1];
  const int*   dones   = (const int*)d_in[2];
  const float* embed   = (const float*)d_in[3];
  const float* Wih     = (const float*)d_in[4];
  const float* Whh     = (const float*)d_in[5];
  const float* bih     = (const float*)d_in[6];
  const float* bhh     = (const float*)d_in[7];
  const float* Wout    = (const float*)d_in[8];
  const float* bout    = (const float*)d_in[9];
  float* out = (float*)d_out;

  if (ws_size < WS_END) return;  // fail visibly rather than corrupt memory

  char* ws = (char*)d_ws;
  u32* gcnt              = (u32*)(ws + WS_GCNT);
  u32* nact              = (u32*)(ws + WS_NACT);
  u32* hdr               = (u32*)(ws + WS_HDR);
  u32* metaA             = (u32*)(ws + WS_META);
  u32* loff              = (u32*)(ws + WS_LOFF);
  u32* tmp               = (u32*)(ws + WS_TMP);
  unsigned short* zt     = (unsigned short*)(ws + WS_ZT);
  unsigned short* wout16 = (unsigned short*)(ws + WS_WOUT);
  u64* hs2               = (u64*)(ws + WS_HS2);
  // d_out doubles as scratch during the recurrence (overwritten afterwards)
  u64* hsl   = (u64*)d_out;                          // ladder <= 33.4MB
  u64* call  = (u64*)((char*)d_out + DO_CALL);       // 32MB c-state (packed)

  hipMemsetAsync(d_ws, 0, 2048, stream);  // barrier counters only

  seg_build_k<<<1, 256, 0, stream>>>(dones, tmp, metaA, nact, hdr, loff);
  cvt_z_k<<<2048, 256, 0, stream>>>(z, zt);    // overwrites tmp after build
  zero_hs_tail_k<<<32, 256, 0, stream>>>(hs2);
  lstm_seg_k<<<256, 1024, 0, stream>>>(Whh, Wih, embed, bih, bhh, actions,
                                       zt, metaA, nact, hdr, loff, hsl, call,
                                       hs2, gcnt);
  cvt_wout_k<<<1921, 256, 0, stream>>>(Wout, wout16);
  out_gemm_k<<<dim3(256, 24), 256, 0, stream>>>(hs2, wout16, bout, out);
  donep_k<<<512, 256, 0, stream>>>(hs2, wout16, bout, out);
}

// Round 17
// 1055.535 us; speedup vs baseline: 3.4185x; 1.0253x over previous
//
#include <hip/hip_runtime.h>
#include <hip/hip_bf16.h>

// ---------------------------------------------------------------------------
// RNNModel (MDN-RNN). Segment algorithm (R9-R16): dones (p=0.5) reset h,c ->
// recurrence splits into segments (max ~15 offsets); sorted desc by len so
// active-at-offset-s = prefix [0,N_s). Ladder h-exchange: region_s at loff[s],
// each (slot,s) address written once (8B agent atomic -> LLC), read once at
// the next step with PLAIN coalesced 16B loads clamped inside region s.
// R17 (single variable vs passing R16): REMOVE the per-step acquire fence.
//   R16 evidence: doubling waves/SIMD changed nothing (849->814us) -> limiter
//   is a block-level per-step fixed cost. The ~3840 async L1+L2 invalidates
//   continuously destroyed the XCD-shared ladder lines (32 blocks/XCD read
//   the same slot rows) -> gathers degraded to LLC latency. The fence's
//   original justification (R13 "prefetch staleness") was a misdiagnosis:
//   R13's error came from the kt-stride bug (reads stayed inside the 2KB
//   row), and dispatch-boundary acquire/release handles memset residue.
//   Clamp (no demand read touches unwritten addresses) is the real guard.
//   If absmax ~5e-2 returns, fence IS load-bearing -> revert + pivot.
// Kept: 16 waves/block, gather unroll 8, wave-autonomous tiles (full K=1152),
//   agent-atomic h/c/hs2 publishes + vmcnt drain + group barrier per s,
//   seg_build scan/sort, hs2 layout, out_gemm/donep.
// ---------------------------------------------------------------------------

typedef float f4 __attribute__((ext_vector_type(4)));
typedef short s8 __attribute__((ext_vector_type(8)));
typedef unsigned short us8v __attribute__((ext_vector_type(8)));
typedef unsigned short us4v __attribute__((ext_vector_type(4)));
typedef unsigned long long u64;
typedef unsigned u32;

#define DEV __device__ __forceinline__

DEV unsigned short f2b(float f) {          // fp32 -> bf16 RNE
  unsigned u = __float_as_uint(f);
  return (unsigned short)((u + 0x7FFFu + ((u >> 16) & 1u)) >> 16);
}
DEV float b2f(unsigned short s) { return __uint_as_float(((unsigned)s) << 16); }

DEV f4 MFMA(s8 a, s8 b, f4 c) {
  return __builtin_amdgcn_mfma_f32_16x16x32_bf16(a, b, c, 0, 0, 0);
}
DEV s8 LD8(const unsigned short* p) { return *reinterpret_cast<const s8*>(p); }

DEV u64 AL(const u64* p) {
  return __hip_atomic_load(p, __ATOMIC_RELAXED, __HIP_MEMORY_SCOPE_AGENT);
}
DEV u32 AL32(const u32* p) {
  return __hip_atomic_load(p, __ATOMIC_RELAXED, __HIP_MEMORY_SCOPE_AGENT);
}
DEV void AS(u64* p, u64 v) {
  __hip_atomic_store(p, v, __ATOMIC_RELAXED, __HIP_MEMORY_SCOPE_AGENT);
}

DEV float sigf(float x) {   // 1/(1+e^-x) via v_exp + v_rcp (~1e-6 rel)
  float e = __builtin_amdgcn_exp2f(x * -1.44269504f);
  return __builtin_amdgcn_rcpf(1.f + e);
}
DEV float tanhf_fast(float x) {  // 1 - 2/(e^{2x}+1); saturates correctly
  float e = __builtin_amdgcn_exp2f(x * 2.88539008f);
  return 1.f - 2.f * __builtin_amdgcn_rcpf(e + 1.f);
}

// ---- d_ws layout (bytes), total = proven 41.8MB ----
static constexpr size_t WS_GCNT = 0;        // 16 group counters, 128B apart
static constexpr size_t WS_NACT = 2048;     // N_act[512] u32
static constexpr size_t WS_HDR  = 4096;     // hdr[0]=total, hdr[1]=maxlen
static constexpr size_t WS_META = 4352;     // meta[16384] u32 (ends 69888)
static constexpr size_t WS_LOFF = 69888;    // loff[512] u32 (ends 71936)
static constexpr size_t WS_TMP  = 131072;   // seg_build scratch (pre-zt)
static constexpr size_t WS_ZT   = 131072;   // zt [16384][128] bf16 (4MB)
static constexpr size_t WS_WOUT = 4325376;  // wout16 (3.75MB)
static constexpr size_t WS_HS2  = 8261632;  // hs2 [256][16384] u64 (32MB)
static constexpr size_t WS_END  = 41816064;
// ---- d_out scratch (dead until out GEMMs overwrite) ----
// hsl ladder: <= 16320 slots x 2KB = 33.4MB at d_out+0
// c_all: [256 blk][8192 slot][2 u64(=4 f32)] = 32MB at d_out+34MiB
static constexpr size_t DO_CALL = 35651584;

// ---------------------------------------------------------------------------
__global__ void cvt_wout_k(const float* __restrict__ W, unsigned short* __restrict__ o) {
  int i = blockIdx.x * 256 + threadIdx.x;         // 491776 float4 units exact
  if (i < 491776) {
    const float4 v = reinterpret_cast<const float4*>(W)[i];
    us4v u; u[0] = f2b(v.x); u[1] = f2b(v.y); u[2] = f2b(v.z); u[3] = f2b(v.w);
    reinterpret_cast<us4v*>(o)[i] = u;
  }
}

__global__ void cvt_z_k(const float* __restrict__ z, unsigned short* __restrict__ zt) {
  // z = 32*512*128 f32 = 524288 float4 units exact (linear, layout preserved)
  int i = blockIdx.x * 256 + threadIdx.x;
  if (i < 524288) {
    const float4 v = reinterpret_cast<const float4*>(z)[i];
    us4v u; u[0] = f2b(v.x); u[1] = f2b(v.y); u[2] = f2b(v.z); u[3] = f2b(v.w);
    reinterpret_cast<us4v*>(zt)[i] = u;
  }
}

__global__ void zero_hs_tail_k(u64* __restrict__ hs2) {
  // rows 16352..16383 of all 256 regions
  int i = blockIdx.x * 256 + threadIdx.x;
  if (i < 8192) {
    int region = i >> 5, r = 16352 + (i & 31);
    hs2[(size_t)region * 16384 + r] = 0ull;
  }
}

// ---------------------------------------------------------------------------
// Segment scan + counting sort (desc by len) + ladder offsets. 1 block.
__global__ __launch_bounds__(256) void seg_build_k(
    const int* __restrict__ dones, u32* __restrict__ tmp,
    u32* __restrict__ meta, u32* __restrict__ nact, u32* __restrict__ hdr,
    u32* __restrict__ loff) {
  __shared__ u32 hist[512];
  __shared__ u32 cur[512];
  __shared__ u32 scnt[32];
  const int tid = threadIdx.x;
  for (int i = tid; i < 512; i += 256) hist[i] = 0;
  __syncthreads();
  if (tid < 32) {   // per-batch scan: step t fresh iff t==0 or done[t-1]
    int b = tid, cnt = 0, t0 = 0;
    for (int t = 1; t <= 511; ++t) {
      bool brk = (t == 511) || (dones[b * 512 + t - 1] != 0);
      if (brk) {
        int len = t - t0;
        tmp[b * 511 + cnt] = ((u32)t0 << 16) | (u32)len;
        atomicAdd(&hist[len], 1u);
        ++cnt; t0 = t;
      }
    }
    scnt[b] = (u32)cnt;
  }
  __syncthreads();
  if (tid == 0) {   // suffix sums: nact[s] = #len>s; bucket bases (desc)
    u32 acc = 0; int ml = 0;
    for (int L = 511; L >= 0; --L) {
      cur[L] = acc; nact[L] = acc;
      if (hist[L] && !ml) ml = L;
      acc += hist[L];
    }
    hdr[0] = acc; hdr[1] = (u32)ml;
    u32 off = 0; loff[0] = 0;          // ladder: region s at loff[s] slots
    for (int s2 = 1; s2 <= ml; ++s2) { loff[s2] = off; off += nact[s2]; }
  }
  __syncthreads();
  if (tid < 32) {   // scatter (within-bucket order arbitrary: prefix prop ok)
    int b = tid; u32 c = scnt[b];
    for (u32 i = 0; i < c; ++i) {
      u32 e = tmp[b * 511 + i];
      u32 len = e & 0xFFFFu, t0 = e >> 16;
      u32 slot = atomicAdd(&cur[len], 1u);
      meta[slot] = ((u32)b << 20) | (t0 << 10) | len;
    }
  }
}

// ---------------------------------------------------------------------------
// Segment-batched LSTM, wave-autonomous tiles + ladder exchange.
// grid=256, block=1024 (16 waves). Block blk owns h cols [4blk,4blk+4).
__global__ __launch_bounds__(1024, 1) void lstm_seg_k(
    const float* __restrict__ Whh, const float* __restrict__ Wih,
    const float* __restrict__ embed, const float* __restrict__ bih,
    const float* __restrict__ bhh, const int* __restrict__ actions,
    const unsigned short* __restrict__ zt, const u32* __restrict__ meta,
    const u32* __restrict__ nact, const u32* __restrict__ hdr,
    const u32* __restrict__ loff, u64* __restrict__ hsl,
    u64* __restrict__ c_all, u64* __restrict__ hs2,
    u32* __restrict__ gcnt) {
  const int blk = blockIdx.x;
  const int tid = threadIdx.x;
  const int lane = tid & 63;
  const int w = tid >> 6;                 // wave 0..15
  const int ln = lane & 15, lk = lane >> 4;
  const int slane = lane & 31;            // slot sub-index in tile
  const int ehalf = lane >> 5;            // 0: cols 0-1, 1: cols 2-3

  __shared__ alignas(16) unsigned short whh_sw[32 * 64 * 8];   // 32 KB
  __shared__ alignas(16) unsigned short wz_sw[4 * 64 * 8];     // 4 KB
  __shared__ float abias[18][16];
  __shared__ float red[16][32][17];       // wave-private gate transpose ~35KB

  for (int i = tid; i < 32 * 64 * 8; i += 1024) {
    int j = i & 7, L = (i >> 3) & 63, kt = i >> 9;
    int n = L & 15;
    int grow = (n >> 2) * 1024 + blk * 4 + (n & 3);
    int k = kt * 32 + ((L >> 4) << 3) + j;
    whh_sw[i] = f2b(Whh[grow * 1024 + k]);
  }
  for (int i = tid; i < 4 * 64 * 8; i += 1024) {
    int j = i & 7, L = (i >> 3) & 63, kt = i >> 9;
    int n = L & 15;
    int grow = (n >> 2) * 1024 + blk * 4 + (n & 3);
    int k = kt * 32 + ((L >> 4) << 3) + j;
    wz_sw[i] = f2b(Wih[grow * 144 + k]);
  }
  for (int i = tid; i < 18 * 16; i += 1024) {
    int a = i >> 4, n = i & 15;
    int grow = (n >> 2) * 1024 + blk * 4 + (n & 3);
    float s = bih[grow] + bhh[grow];
    for (int j = 0; j < 16; ++j) s += embed[a * 16 + j] * Wih[grow * 144 + 128 + j];
    abias[a][n] = s;
  }
  __syncthreads();

  const int maxlen = (int)hdr[1];

  for (int s = 0; s < maxlen; ++s) {
    const u32 N = nact[s];                   // active slots (prefix)
    const int ntiles = (int)((N + 31) >> 5);
    const u64* hread = hsl + (size_t)loff[s] * 256;       // region s (s>=1)
    u64* hwrite = hsl + (size_t)loff[s + 1] * 256;        // region s+1

    for (int tile = w; tile < ntiles; tile += 16) {
      const u32 sb = (u32)tile << 5;
      const u32 slot = sb + (u32)slane;
      const bool valid = slot < N;
      // meta: each lane for its slot (lanes 32-63 duplicate 0-31)
      const u32 m = valid ? meta[slot] : 0u;
      const u32 b = m >> 20, t0 = (m >> 10) & 1023u, L = m & 1023u;
      const int zrow = (int)(b * 512u + t0 + (u32)s);
      const int orow = (int)(b * 511u + t0 + (u32)s);
      const u32 act = valid ? (u32)actions[zrow] : 0u;
      // c-state: 2 f32 packed per u64 per lane; atomic load issued EARLY so
      // LLC latency hides under the MFMA work below. cq==0 -> cprev=0.0f.
      u64 cq = 0;
      if (s && valid)
        cq = AL(c_all + ((size_t)blk << 14) + ((size_t)slot << 1) + ehalf);
      // broadcast z rows for the two A-subtiles
      const int zr0 = __shfl(zrow, ln, 64);
      const int zr1 = __shfl(zrow, ln + 16, 64);

      f4 acc0 = {0.f, 0.f, 0.f, 0.f};
      f4 acc1 = {0.f, 0.f, 0.f, 0.f};
#pragma unroll
      for (int kz = 0; kz < 4; ++kz) {     // z contribution (K=128)
        s8 a0 = LD8(zt + (size_t)zr0 * 128 + kz * 32 + (lk << 3));
        s8 a1 = LD8(zt + (size_t)zr1 * 128 + kz * 32 + (lk << 3));
        s8 bf = LD8(wz_sw + ((kz * 64 + lane) << 3));
        acc0 = MFMA(a0, bf, acc0);
        acc1 = MFMA(a1, bf, acc1);
      }
      if (s) {  // h gather: PLAIN coalesced 16B loads (ladder; clamped)
        const u32 rA = sb + (u32)ln;
        const u32 rB = rA + 16u;
        const u32 rAc = (rA < N) ? rA : (N - 1u);   // stay inside region s
        const u32 rBc = (rB < N) ? rB : (N - 1u);
        const unsigned short* hrow0 =
            (const unsigned short*)(hread + (size_t)rAc * 256 + (lk << 1));
        const unsigned short* hrow1 =
            (const unsigned short*)(hread + (size_t)rBc * 256 + (lk << 1));
#pragma unroll 8
        for (int kt = 0; kt < 32; ++kt) {
          s8 fa = LD8(hrow0 + (kt << 5));   // +kt*8 u64 = +kt*32 bf16
          s8 fb = LD8(hrow1 + (kt << 5));
          s8 bf = LD8(whh_sw + ((kt * 64 + lane) << 3));
          acc0 = MFMA(fa, bf, acc0);
          acc1 = MFMA(fb, bf, acc1);
        }
      }

      // wave-private transpose: D row(slot)=4*lk+j (+16 for acc1), col=ln
#pragma unroll
      for (int j = 0; j < 4; ++j) {
        red[w][(lk << 2) + j][ln] = acc0[j];
        red[w][16 + (lk << 2) + j][ln] = acc1[j];
      }
      // same-wave DS ordering: reads below wait on lgkmcnt for the writes
      const bool carry = valid && (L > (u32)(s + 1));
      u32 hbits = 0;
      u32 cbits0 = 0, cbits1 = 0;
#pragma unroll
      for (int e = 0; e < 2; ++e) {   // this lane: slot=slane, cols 2*ehalf+e
        const int eq = (ehalf << 1) + e;
        float gi = red[w][slane][eq]      + abias[act][eq];
        float gf = red[w][slane][4 + eq]  + abias[act][4 + eq];
        float gg = red[w][slane][8 + eq]  + abias[act][8 + eq];
        float go = red[w][slane][12 + eq] + abias[act][12 + eq];
        const float cprev = (e == 0) ? __uint_as_float((u32)cq)
                                     : __uint_as_float((u32)(cq >> 32));
        const float si = sigf(gi), sf = sigf(gf), so = sigf(go);
        const float cn = sf * cprev + si * tanhf_fast(gg);
        const float hn = so * tanhf_fast(cn);
        if (e == 0) cbits0 = __float_as_uint(cn); else cbits1 = __float_as_uint(cn);
        hbits |= ((u32)f2b(hn)) << (16 * e);
      }
      if (carry)   // fp32 c carry, agent atomic (write-through)
        AS(c_all + ((size_t)blk << 14) + ((size_t)slot << 1) + ehalf,
           ((u64)cbits1 << 32) | (u64)cbits0);
      // pack 4 cols: lane<32 has cols 0-1 (low), lane+32 has 2-3 (high)
      const u32 other = (u32)__shfl_xor((int)hbits, 32, 64);
      if (lane < 32 && valid) {
        const u64 hu = ((u64)other << 32) | (u64)hbits;
        AS(&hs2[((size_t)blk << 14) + orow], hu);      // history (atomic)
        if (carry) AS(hwrite + (size_t)slot * 256 + blk, hu);  // carry h
      }
    }

    // per-wave drain of stores, block sync, global barrier (NO fence: R17)
    asm volatile("s_waitcnt vmcnt(0)" ::: "memory");
    __syncthreads();
    if (s + 1 < maxlen) {
      if (tid == 0) {
        __hip_atomic_fetch_add(gcnt + (blk >> 4) * 32, 1u,
                               __ATOMIC_RELAXED, __HIP_MEMORY_SCOPE_AGENT);
        const u32 tgt = (u32)(s + 1) * 16u;
        for (u32 spin = 0; spin < (1u << 20); ++spin) {
          u32 mn = 0xFFFFFFFFu;
#pragma unroll
          for (int g = 0; g < 16; ++g) {
            u32 v = AL32(gcnt + g * 32);
            mn = (v < mn) ? v : mn;
          }
          if (mn >= tgt) break;
          __builtin_amdgcn_s_sleep(1);
        }
      }
      __syncthreads();
    }
  }
}

// ---------------------------------------------------------------------------
// out = hs @ W_out^T (+bias), fused logsumexp on the logmix third.
__global__ __launch_bounds__(256, 2) void out_gemm_k(
    const u64* __restrict__ hs2, const unsigned short* __restrict__ wout,
    const float* __restrict__ b_out, float* __restrict__ out) {
  const int mblk = blockIdx.x, nblk = blockIdx.y;
  const int tid = threadIdx.x, lane = tid & 63, w = tid >> 6;
  const int ln = lane & 15, lk = lane >> 4;
  __shared__ alignas(16) unsigned char smraw[21760];
  unsigned short* bsm = (unsigned short*)smraw;  // [80][136] bf16 B-chunk
  float* ep = (float*)smraw;                     // [64][84] f32 epilogue tile

  const int r0 = mblk * 64 + w * 16;
  f4 acc[5];
#pragma unroll
  for (int s = 0; s < 5; ++s) acc[s] = (f4){0.f, 0.f, 0.f, 0.f};

  for (int kc = 0; kc < 8; ++kc) {  // K chunks of 128
#pragma unroll
    for (int ii = 0; ii < 5; ++ii) {           // 1280 us8 chunks exact
      int i = tid + ii * 256;
      int n = i >> 4, k16 = i & 15;
      us8v v = *reinterpret_cast<const us8v*>(
          wout + (size_t)(nblk * 80 + n) * 1024 + kc * 128 + (k16 << 3));
      *reinterpret_cast<us8v*>(bsm + n * 136 + (k16 << 3)) = v;
    }
    __syncthreads();
#pragma unroll
    for (int ks = 0; ks < 4; ++ks) {
      const int k0 = kc * 128 + ks * 32 + (lk << 3);
      union { u64 q[2]; s8 v; } ua;            // A-frag: 2 x 8B from hs2
      ua.q[0] = hs2[(size_t)(k0 >> 2) * 16384 + r0 + ln];
      ua.q[1] = hs2[((size_t)(k0 >> 2) + 1) * 16384 + r0 + ln];
#pragma unroll
      for (int s = 0; s < 5; ++s) {
        s8 b = LD8(bsm + (s * 16 + ln) * 136 + ks * 32 + (lk << 3));
        acc[s] = MFMA(ua.v, b, acc[s]);
      }
    }
    __syncthreads();
  }

  const int T = nblk >> 3;  // 0 logmix, 1 mu, 2 logstd
  if (T) {
    float* base = out + (size_t)10465280 * T;
    const int lc0 = (nblk - (T << 3)) * 80;
#pragma unroll
    for (int s = 0; s < 5; ++s) {
      const int lc = lc0 + s * 16 + ln;
      const float bias = b_out[T * 640 + lc];
#pragma unroll
      for (int j = 0; j < 4; ++j) {
        const int row = r0 + (lk << 2) + j;
        if (row < 16352) base[(size_t)row * 640 + lc] = acc[s][j] + bias;
      }
    }
  } else {  // logmix: bounce through LDS, per-(row, z-group) logsumexp over 5
#pragma unroll
    for (int s = 0; s < 5; ++s) {
      const float bias = b_out[nblk * 80 + s * 16 + ln];
#pragma unroll
      for (int j = 0; j < 4; ++j)
        ep[(w * 16 + (lk << 2) + j) * 84 + s * 16 + ln] = acc[s][j] + bias;
    }
    __syncthreads();
    for (int task = tid; task < 1024; task += 256) {
      const int rr = task >> 4, grp = task & 15;
      const int row = mblk * 64 + rr;
      const float* e = ep + rr * 84 + grp * 5;
      float v0 = e[0], v1 = e[1], v2 = e[2], v3 = e[3], v4 = e[4];
      float mx = fmaxf(fmaxf(fmaxf(v0, v1), fmaxf(v2, v3)), v4);
      float ssum = expf(v0 - mx) + expf(v1 - mx) + expf(v2 - mx) +
                   expf(v3 - mx) + expf(v4 - mx);
      float lse = mx + logf(ssum);
      if (row < 16352) {
        float* o = out + (size_t)row * 640 + nblk * 80 + grp * 5;
        o[0] = v0 - lse; o[1] = v1 - lse; o[2] = v2 - lse;
        o[3] = v3 - lse; o[4] = v4 - lse;
      }
    }
  }
}

// ---------------------------------------------------------------------------
__global__ __launch_bounds__(256) void donep_k(
    const u64* __restrict__ hs2, const unsigned short* __restrict__ wout,
    const float* __restrict__ b_out, float* __restrict__ out) {
  const int lane = threadIdx.x & 63;
  const int wv = (blockIdx.x * 256 + threadIdx.x) >> 6;  // 2048 waves
  const unsigned short* wrow = wout + (size_t)1920 * 1024 + lane * 16;
  float wl[16];
#pragma unroll
  for (int i = 0; i < 16; ++i) wl[i] = b2f(wrow[i]);
  const float bias = b_out[1920];
  for (int r = wv; r < 16352; r += 2048) {
    float d = 0.f;
#pragma unroll
    for (int j = 0; j < 4; ++j) {   // k = lane*16 + 4j + (0..3)
      union { u64 q; unsigned short h[4]; } u;
      u.q = hs2[(size_t)(lane * 4 + j) * 16384 + r];
#pragma unroll
      for (int i = 0; i < 4; ++i) d += b2f(u.h[i]) * wl[j * 4 + i];
    }
#pragma unroll
    for (int off = 32; off; off >>= 1) d += __shfl_down(d, off, 64);
    if (lane == 0) out[31395840 + r] = d + bias;
  }
}

// ---------------------------------------------------------------------------
extern "C" void kernel_launch(void* const* d_in, const int* in_sizes, int n_in,
                              void* d_out, int out_size, void* d_ws, size_t ws_size,
                              hipStream_t stream) {
  const float* z       = (const float*)d_in[0];
  const int*   actions = (const int*)d_in[1];
  const int*   dones   = (const int*)d_in[2];
  const float* embed   = (const float*)d_in[3];
  const float* Wih     = (const float*)d_in[4];
  const float* Whh     = (const float*)d_in[5];
  const float* bih     = (const float*)d_in[6];
  const float* bhh     = (const float*)d_in[7];
  const float* Wout    = (const float*)d_in[8];
  const float* bout    = (const float*)d_in[9];
  float* out = (float*)d_out;

  if (ws_size < WS_END) return;  // fail visibly rather than corrupt memory

  char* ws = (char*)d_ws;
  u32* gcnt              = (u32*)(ws + WS_GCNT);
  u32* nact              = (u32*)(ws + WS_NACT);
  u32* hdr               = (u32*)(ws + WS_HDR);
  u32* metaA             = (u32*)(ws + WS_META);
  u32* loff              = (u32*)(ws + WS_LOFF);
  u32* tmp               = (u32*)(ws + WS_TMP);
  unsigned short* zt     = (unsigned short*)(ws + WS_ZT);
  unsigned short* wout16 = (unsigned short*)(ws + WS_WOUT);
  u64* hs2               = (u64*)(ws + WS_HS2);
  // d_out doubles as scratch during the recurrence (overwritten afterwards)
  u64* hsl   = (u64*)d_out;                          // ladder <= 33.4MB
  u64* call  = (u64*)((char*)d_out + DO_CALL);       // 32MB c-state (packed)

  hipMemsetAsync(d_ws, 0, 2048, stream);  // barrier counters only

  seg_build_k<<<1, 256, 0, stream>>>(dones, tmp, metaA, nact, hdr, loff);
  cvt_z_k<<<2048, 256, 0, stream>>>(z, zt);    // overwrites tmp after build
  zero_hs_tail_k<<<32, 256, 0, stream>>>(hs2);
  lstm_seg_k<<<256, 1024, 0, stream>>>(Whh, Wih, embed, bih, bhh, actions,
                                       zt, metaA, nact, hdr, loff, hsl, call,
                                       hs2, gcnt);
  cvt_wout_k<<<1921, 256, 0, stream>>>(Wout, wout16);
  out_gemm_k<<<dim3(256, 24), 256, 0, stream>>>(hs2, wout16, bout, out);
  donep_k<<<512, 256, 0, stream>>>(hs2, wout16, bout, out);
}

// Round 18
// 1046.124 us; speedup vs baseline: 3.4492x; 1.0090x over previous
//
#include <hip/hip_runtime.h>
#include <hip/hip_bf16.h>

// ---------------------------------------------------------------------------
// RNNModel (MDN-RNN). Segment algorithm (R9-R17): dones (p=0.5) reset h,c ->
// recurrence splits into segments (max ~15 offsets); sorted desc by len so
// active-at-offset-s = prefix [0,N_s). Ladder h-exchange: region_s at loff[s],
// each (slot,s) address written once (8B agent atomic -> LLC), read once at
// the next step with PLAIN coalesced 16B loads clamped inside region s.
// R18: de-atomic-ize everything that doesn't need agent scope. R17 counters:
//   WRITE_SIZE 219MB vs ~82MB payload, FETCH 110MB vs ~35MB inputs -- agent
//   atomics are write-through/no-allocate => every 8B atomic is an HBM
//   transaction (8x partial-line amp on strided stores). Per-tile fixed cost
//   that TLP (R16: 2x waves, -4%) and fence removal (R17: -3%) never touched.
//   - c_all: BLOCK-PRIVATE (same block writes s, reads s+1, same L2) ->
//     plain load/store; c-state now lives in own-XCD L2, off the HBM path.
//   - hs2: read only after dispatch boundary; R4-R11 used plain stores and
//     cross-XCD out_gemm reads were correct (end-of-dispatch AQL release
//     flushes L2) -> plain stores again.
//   - ladder carry: the only true intra-kernel cross-block data -> keeps
//     agent atomics + vmcnt drain + group barrier.
// Kept: 16 waves/block, unroll 8, wave-autonomous tiles, no per-step fence,
//   clamped gathers, seg_build scan/sort, out_gemm/donep.
// ---------------------------------------------------------------------------

typedef float f4 __attribute__((ext_vector_type(4)));
typedef short s8 __attribute__((ext_vector_type(8)));
typedef unsigned short us8v __attribute__((ext_vector_type(8)));
typedef unsigned short us4v __attribute__((ext_vector_type(4)));
typedef unsigned long long u64;
typedef unsigned u32;

#define DEV __device__ __forceinline__

DEV unsigned short f2b(float f) {          // fp32 -> bf16 RNE
  unsigned u = __float_as_uint(f);
  return (unsigned short)((u + 0x7FFFu + ((u >> 16) & 1u)) >> 16);
}
DEV float b2f(unsigned short s) { return __uint_as_float(((unsigned)s) << 16); }

DEV f4 MFMA(s8 a, s8 b, f4 c) {
  return __builtin_amdgcn_mfma_f32_16x16x32_bf16(a, b, c, 0, 0, 0);
}
DEV s8 LD8(const unsigned short* p) { return *reinterpret_cast<const s8*>(p); }

DEV u32 AL32(const u32* p) {
  return __hip_atomic_load(p, __ATOMIC_RELAXED, __HIP_MEMORY_SCOPE_AGENT);
}
DEV void AS(u64* p, u64 v) {
  __hip_atomic_store(p, v, __ATOMIC_RELAXED, __HIP_MEMORY_SCOPE_AGENT);
}

DEV float sigf(float x) {   // 1/(1+e^-x) via v_exp + v_rcp (~1e-6 rel)
  float e = __builtin_amdgcn_exp2f(x * -1.44269504f);
  return __builtin_amdgcn_rcpf(1.f + e);
}
DEV float tanhf_fast(float x) {  // 1 - 2/(e^{2x}+1); saturates correctly
  float e = __builtin_amdgcn_exp2f(x * 2.88539008f);
  return 1.f - 2.f * __builtin_amdgcn_rcpf(e + 1.f);
}

// ---- d_ws layout (bytes), total = proven 41.8MB ----
static constexpr size_t WS_GCNT = 0;        // 16 group counters, 128B apart
static constexpr size_t WS_NACT = 2048;     // N_act[512] u32
static constexpr size_t WS_HDR  = 4096;     // hdr[0]=total, hdr[1]=maxlen
static constexpr size_t WS_META = 4352;     // meta[16384] u32 (ends 69888)
static constexpr size_t WS_LOFF = 69888;    // loff[512] u32 (ends 71936)
static constexpr size_t WS_TMP  = 131072;   // seg_build scratch (pre-zt)
static constexpr size_t WS_ZT   = 131072;   // zt [16384][128] bf16 (4MB)
static constexpr size_t WS_WOUT = 4325376;  // wout16 (3.75MB)
static constexpr size_t WS_HS2  = 8261632;  // hs2 [256][16384] u64 (32MB)
static constexpr size_t WS_END  = 41816064;
// ---- d_out scratch (dead until out GEMMs overwrite) ----
// hsl ladder: <= 16320 slots x 2KB = 33.4MB at d_out+0
// c_all: [256 blk][8192 slot][2 u64(=4 f32)] = 32MB at d_out+34MiB
static constexpr size_t DO_CALL = 35651584;

// ---------------------------------------------------------------------------
__global__ void cvt_wout_k(const float* __restrict__ W, unsigned short* __restrict__ o) {
  int i = blockIdx.x * 256 + threadIdx.x;         // 491776 float4 units exact
  if (i < 491776) {
    const float4 v = reinterpret_cast<const float4*>(W)[i];
    us4v u; u[0] = f2b(v.x); u[1] = f2b(v.y); u[2] = f2b(v.z); u[3] = f2b(v.w);
    reinterpret_cast<us4v*>(o)[i] = u;
  }
}

__global__ void cvt_z_k(const float* __restrict__ z, unsigned short* __restrict__ zt) {
  // z = 32*512*128 f32 = 524288 float4 units exact (linear, layout preserved)
  int i = blockIdx.x * 256 + threadIdx.x;
  if (i < 524288) {
    const float4 v = reinterpret_cast<const float4*>(z)[i];
    us4v u; u[0] = f2b(v.x); u[1] = f2b(v.y); u[2] = f2b(v.z); u[3] = f2b(v.w);
    reinterpret_cast<us4v*>(zt)[i] = u;
  }
}

__global__ void zero_hs_tail_k(u64* __restrict__ hs2) {
  // rows 16352..16383 of all 256 regions
  int i = blockIdx.x * 256 + threadIdx.x;
  if (i < 8192) {
    int region = i >> 5, r = 16352 + (i & 31);
    hs2[(size_t)region * 16384 + r] = 0ull;
  }
}

// ---------------------------------------------------------------------------
// Segment scan + counting sort (desc by len) + ladder offsets. 1 block.
__global__ __launch_bounds__(256) void seg_build_k(
    const int* __restrict__ dones, u32* __restrict__ tmp,
    u32* __restrict__ meta, u32* __restrict__ nact, u32* __restrict__ hdr,
    u32* __restrict__ loff) {
  __shared__ u32 hist[512];
  __shared__ u32 cur[512];
  __shared__ u32 scnt[32];
  const int tid = threadIdx.x;
  for (int i = tid; i < 512; i += 256) hist[i] = 0;
  __syncthreads();
  if (tid < 32) {   // per-batch scan: step t fresh iff t==0 or done[t-1]
    int b = tid, cnt = 0, t0 = 0;
    for (int t = 1; t <= 511; ++t) {
      bool brk = (t == 511) || (dones[b * 512 + t - 1] != 0);
      if (brk) {
        int len = t - t0;
        tmp[b * 511 + cnt] = ((u32)t0 << 16) | (u32)len;
        atomicAdd(&hist[len], 1u);
        ++cnt; t0 = t;
      }
    }
    scnt[b] = (u32)cnt;
  }
  __syncthreads();
  if (tid == 0) {   // suffix sums: nact[s] = #len>s; bucket bases (desc)
    u32 acc = 0; int ml = 0;
    for (int L = 511; L >= 0; --L) {
      cur[L] = acc; nact[L] = acc;
      if (hist[L] && !ml) ml = L;
      acc += hist[L];
    }
    hdr[0] = acc; hdr[1] = (u32)ml;
    u32 off = 0; loff[0] = 0;          // ladder: region s at loff[s] slots
    for (int s2 = 1; s2 <= ml; ++s2) { loff[s2] = off; off += nact[s2]; }
  }
  __syncthreads();
  if (tid < 32) {   // scatter (within-bucket order arbitrary: prefix prop ok)
    int b = tid; u32 c = scnt[b];
    for (u32 i = 0; i < c; ++i) {
      u32 e = tmp[b * 511 + i];
      u32 len = e & 0xFFFFu, t0 = e >> 16;
      u32 slot = atomicAdd(&cur[len], 1u);
      meta[slot] = ((u32)b << 20) | (t0 << 10) | len;
    }
  }
}

// ---------------------------------------------------------------------------
// Segment-batched LSTM, wave-autonomous tiles + ladder exchange.
// grid=256, block=1024 (16 waves). Block blk owns h cols [4blk,4blk+4).
__global__ __launch_bounds__(1024, 1) void lstm_seg_k(
    const float* __restrict__ Whh, const float* __restrict__ Wih,
    const float* __restrict__ embed, const float* __restrict__ bih,
    const float* __restrict__ bhh, const int* __restrict__ actions,
    const unsigned short* __restrict__ zt, const u32* __restrict__ meta,
    const u32* __restrict__ nact, const u32* __restrict__ hdr,
    const u32* __restrict__ loff, u64* __restrict__ hsl,
    u64* __restrict__ c_all, u64* __restrict__ hs2,
    u32* __restrict__ gcnt) {
  const int blk = blockIdx.x;
  const int tid = threadIdx.x;
  const int lane = tid & 63;
  const int w = tid >> 6;                 // wave 0..15
  const int ln = lane & 15, lk = lane >> 4;
  const int slane = lane & 31;            // slot sub-index in tile
  const int ehalf = lane >> 5;            // 0: cols 0-1, 1: cols 2-3

  __shared__ alignas(16) unsigned short whh_sw[32 * 64 * 8];   // 32 KB
  __shared__ alignas(16) unsigned short wz_sw[4 * 64 * 8];     // 4 KB
  __shared__ float abias[18][16];
  __shared__ float red[16][32][17];       // wave-private gate transpose ~35KB

  for (int i = tid; i < 32 * 64 * 8; i += 1024) {
    int j = i & 7, L = (i >> 3) & 63, kt = i >> 9;
    int n = L & 15;
    int grow = (n >> 2) * 1024 + blk * 4 + (n & 3);
    int k = kt * 32 + ((L >> 4) << 3) + j;
    whh_sw[i] = f2b(Whh[grow * 1024 + k]);
  }
  for (int i = tid; i < 4 * 64 * 8; i += 1024) {
    int j = i & 7, L = (i >> 3) & 63, kt = i >> 9;
    int n = L & 15;
    int grow = (n >> 2) * 1024 + blk * 4 + (n & 3);
    int k = kt * 32 + ((L >> 4) << 3) + j;
    wz_sw[i] = f2b(Wih[grow * 144 + k]);
  }
  for (int i = tid; i < 18 * 16; i += 1024) {
    int a = i >> 4, n = i & 15;
    int grow = (n >> 2) * 1024 + blk * 4 + (n & 3);
    float s = bih[grow] + bhh[grow];
    for (int j = 0; j < 16; ++j) s += embed[a * 16 + j] * Wih[grow * 144 + 128 + j];
    abias[a][n] = s;
  }
  __syncthreads();

  const int maxlen = (int)hdr[1];

  for (int s = 0; s < maxlen; ++s) {
    const u32 N = nact[s];                   // active slots (prefix)
    const int ntiles = (int)((N + 31) >> 5);
    const u64* hread = hsl + (size_t)loff[s] * 256;       // region s (s>=1)
    u64* hwrite = hsl + (size_t)loff[s + 1] * 256;        // region s+1

    for (int tile = w; tile < ntiles; tile += 16) {
      const u32 sb = (u32)tile << 5;
      const u32 slot = sb + (u32)slane;
      const bool valid = slot < N;
      // meta: each lane for its slot (lanes 32-63 duplicate 0-31)
      const u32 m = valid ? meta[slot] : 0u;
      const u32 b = m >> 20, t0 = (m >> 10) & 1023u, L = m & 1023u;
      const int zrow = (int)(b * 512u + t0 + (u32)s);
      const int orow = (int)(b * 511u + t0 + (u32)s);
      const u32 act = valid ? (u32)actions[zrow] : 0u;
      // c-state: BLOCK-PRIVATE (same L2) -> plain load (R18). Issued early.
      u64 cq = 0;
      if (s && valid)
        cq = c_all[((size_t)blk << 14) + ((size_t)slot << 1) + ehalf];
      // broadcast z rows for the two A-subtiles
      const int zr0 = __shfl(zrow, ln, 64);
      const int zr1 = __shfl(zrow, ln + 16, 64);

      f4 acc0 = {0.f, 0.f, 0.f, 0.f};
      f4 acc1 = {0.f, 0.f, 0.f, 0.f};
#pragma unroll
      for (int kz = 0; kz < 4; ++kz) {     // z contribution (K=128)
        s8 a0 = LD8(zt + (size_t)zr0 * 128 + kz * 32 + (lk << 3));
        s8 a1 = LD8(zt + (size_t)zr1 * 128 + kz * 32 + (lk << 3));
        s8 bf = LD8(wz_sw + ((kz * 64 + lane) << 3));
        acc0 = MFMA(a0, bf, acc0);
        acc1 = MFMA(a1, bf, acc1);
      }
      if (s) {  // h gather: PLAIN coalesced 16B loads (ladder; clamped)
        const u32 rA = sb + (u32)ln;
        const u32 rB = rA + 16u;
        const u32 rAc = (rA < N) ? rA : (N - 1u);   // stay inside region s
        const u32 rBc = (rB < N) ? rB : (N - 1u);
        const unsigned short* hrow0 =
            (const unsigned short*)(hread + (size_t)rAc * 256 + (lk << 1));
        const unsigned short* hrow1 =
            (const unsigned short*)(hread + (size_t)rBc * 256 + (lk << 1));
#pragma unroll 8
        for (int kt = 0; kt < 32; ++kt) {
          s8 fa = LD8(hrow0 + (kt << 5));   // +kt*8 u64 = +kt*32 bf16
          s8 fb = LD8(hrow1 + (kt << 5));
          s8 bf = LD8(whh_sw + ((kt * 64 + lane) << 3));
          acc0 = MFMA(fa, bf, acc0);
          acc1 = MFMA(fb, bf, acc1);
        }
      }

      // wave-private transpose: D row(slot)=4*lk+j (+16 for acc1), col=ln
#pragma unroll
      for (int j = 0; j < 4; ++j) {
        red[w][(lk << 2) + j][ln] = acc0[j];
        red[w][16 + (lk << 2) + j][ln] = acc1[j];
      }
      // same-wave DS ordering: reads below wait on lgkmcnt for the writes
      const bool carry = valid && (L > (u32)(s + 1));
      u32 hbits = 0;
      u32 cbits0 = 0, cbits1 = 0;
#pragma unroll
      for (int e = 0; e < 2; ++e) {   // this lane: slot=slane, cols 2*ehalf+e
        const int eq = (ehalf << 1) + e;
        float gi = red[w][slane][eq]      + abias[act][eq];
        float gf = red[w][slane][4 + eq]  + abias[act][4 + eq];
        float gg = red[w][slane][8 + eq]  + abias[act][8 + eq];
        float go = red[w][slane][12 + eq] + abias[act][12 + eq];
        const float cprev = (e == 0) ? __uint_as_float((u32)cq)
                                     : __uint_as_float((u32)(cq >> 32));
        const float si = sigf(gi), sf = sigf(gf), so = sigf(go);
        const float cn = sf * cprev + si * tanhf_fast(gg);
        const float hn = so * tanhf_fast(cn);
        if (e == 0) cbits0 = __float_as_uint(cn); else cbits1 = __float_as_uint(cn);
        hbits |= ((u32)f2b(hn)) << (16 * e);
      }
      if (carry)   // fp32 c carry: plain store, block-private L2 (R18)
        c_all[((size_t)blk << 14) + ((size_t)slot << 1) + ehalf] =
            ((u64)cbits1 << 32) | (u64)cbits0;
      // pack 4 cols: lane<32 has cols 0-1 (low), lane+32 has 2-3 (high)
      const u32 other = (u32)__shfl_xor((int)hbits, 32, 64);
      if (lane < 32 && valid) {
        const u64 hu = ((u64)other << 32) | (u64)hbits;
        hs2[((size_t)blk << 14) + orow] = hu;   // history: plain (R18);
                                                // end-of-dispatch release
                                                // publishes to out_gemm
        if (carry) AS(hwrite + (size_t)slot * 256 + blk, hu);  // carry h
      }
    }

    // per-wave drain of stores, block sync, global barrier
    asm volatile("s_waitcnt vmcnt(0)" ::: "memory");
    __syncthreads();
    if (s + 1 < maxlen) {
      if (tid == 0) {
        __hip_atomic_fetch_add(gcnt + (blk >> 4) * 32, 1u,
                               __ATOMIC_RELAXED, __HIP_MEMORY_SCOPE_AGENT);
        const u32 tgt = (u32)(s + 1) * 16u;
        for (u32 spin = 0; spin < (1u << 20); ++spin) {
          u32 mn = 0xFFFFFFFFu;
#pragma unroll
          for (int g = 0; g < 16; ++g) {
            u32 v = AL32(gcnt + g * 32);
            mn = (v < mn) ? v : mn;
          }
          if (mn >= tgt) break;
          __builtin_amdgcn_s_sleep(1);
        }
      }
      __syncthreads();
    }
  }
}

// ---------------------------------------------------------------------------
// out = hs @ W_out^T (+bias), fused logsumexp on the logmix third.
__global__ __launch_bounds__(256, 2) void out_gemm_k(
    const u64* __restrict__ hs2, const unsigned short* __restrict__ wout,
    const float* __restrict__ b_out, float* __restrict__ out) {
  const int mblk = blockIdx.x, nblk = blockIdx.y;
  const int tid = threadIdx.x, lane = tid & 63, w = tid >> 6;
  const int ln = lane & 15, lk = lane >> 4;
  __shared__ alignas(16) unsigned char smraw[21760];
  unsigned short* bsm = (unsigned short*)smraw;  // [80][136] bf16 B-chunk
  float* ep = (float*)smraw;                     // [64][84] f32 epilogue tile

  const int r0 = mblk * 64 + w * 16;
  f4 acc[5];
#pragma unroll
  for (int s = 0; s < 5; ++s) acc[s] = (f4){0.f, 0.f, 0.f, 0.f};

  for (int kc = 0; kc < 8; ++kc) {  // K chunks of 128
#pragma unroll
    for (int ii = 0; ii < 5; ++ii) {           // 1280 us8 chunks exact
      int i = tid + ii * 256;
      int n = i >> 4, k16 = i & 15;
      us8v v = *reinterpret_cast<const us8v*>(
          wout + (size_t)(nblk * 80 + n) * 1024 + kc * 128 + (k16 << 3));
      *reinterpret_cast<us8v*>(bsm + n * 136 + (k16 << 3)) = v;
    }
    __syncthreads();
#pragma unroll
    for (int ks = 0; ks < 4; ++ks) {
      const int k0 = kc * 128 + ks * 32 + (lk << 3);
      union { u64 q[2]; s8 v; } ua;            // A-frag: 2 x 8B from hs2
      ua.q[0] = hs2[(size_t)(k0 >> 2) * 16384 + r0 + ln];
      ua.q[1] = hs2[((size_t)(k0 >> 2) + 1) * 16384 + r0 + ln];
#pragma unroll
      for (int s = 0; s < 5; ++s) {
        s8 b = LD8(bsm + (s * 16 + ln) * 136 + ks * 32 + (lk << 3));
        acc[s] = MFMA(ua.v, b, acc[s]);
      }
    }
    __syncthreads();
  }

  const int T = nblk >> 3;  // 0 logmix, 1 mu, 2 logstd
  if (T) {
    float* base = out + (size_t)10465280 * T;
    const int lc0 = (nblk - (T << 3)) * 80;
#pragma unroll
    for (int s = 0; s < 5; ++s) {
      const int lc = lc0 + s * 16 + ln;
      const float bias = b_out[T * 640 + lc];
#pragma unroll
      for (int j = 0; j < 4; ++j) {
        const int row = r0 + (lk << 2) + j;
        if (row < 16352) base[(size_t)row * 640 + lc] = acc[s][j] + bias;
      }
    }
  } else {  // logmix: bounce through LDS, per-(row, z-group) logsumexp over 5
#pragma unroll
    for (int s = 0; s < 5; ++s) {
      const float bias = b_out[nblk * 80 + s * 16 + ln];
#pragma unroll
      for (int j = 0; j < 4; ++j)
        ep[(w * 16 + (lk << 2) + j) * 84 + s * 16 + ln] = acc[s][j] + bias;
    }
    __syncthreads();
    for (int task = tid; task < 1024; task += 256) {
      const int rr = task >> 4, grp = task & 15;
      const int row = mblk * 64 + rr;
      const float* e = ep + rr * 84 + grp * 5;
      float v0 = e[0], v1 = e[1], v2 = e[2], v3 = e[3], v4 = e[4];
      float mx = fmaxf(fmaxf(fmaxf(v0, v1), fmaxf(v2, v3)), v4);
      float ssum = expf(v0 - mx) + expf(v1 - mx) + expf(v2 - mx) +
                   expf(v3 - mx) + expf(v4 - mx);
      float lse = mx + logf(ssum);
      if (row < 16352) {
        float* o = out + (size_t)row * 640 + nblk * 80 + grp * 5;
        o[0] = v0 - lse; o[1] = v1 - lse; o[2] = v2 - lse;
        o[3] = v3 - lse; o[4] = v4 - lse;
      }
    }
  }
}

// ---------------------------------------------------------------------------
__global__ __launch_bounds__(256) void donep_k(
    const u64* __restrict__ hs2, const unsigned short* __restrict__ wout,
    const float* __restrict__ b_out, float* __restrict__ out) {
  const int lane = threadIdx.x & 63;
  const int wv = (blockIdx.x * 256 + threadIdx.x) >> 6;  // 2048 waves
  const unsigned short* wrow = wout + (size_t)1920 * 1024 + lane * 16;
  float wl[16];
#pragma unroll
  for (int i = 0; i < 16; ++i) wl[i] = b2f(wrow[i]);
  const float bias = b_out[1920];
  for (int r = wv; r < 16352; r += 2048) {
    float d = 0.f;
#pragma unroll
    for (int j = 0; j < 4; ++j) {   // k = lane*16 + 4j + (0..3)
      union { u64 q; unsigned short h[4]; } u;
      u.q = hs2[(size_t)(lane * 4 + j) * 16384 + r];
#pragma unroll
      for (int i = 0; i < 4; ++i) d += b2f(u.h[i]) * wl[j * 4 + i];
    }
#pragma unroll
    for (int off = 32; off; off >>= 1) d += __shfl_down(d, off, 64);
    if (lane == 0) out[31395840 + r] = d + bias;
  }
}

// ---------------------------------------------------------------------------
extern "C" void kernel_launch(void* const* d_in, const int* in_sizes, int n_in,
                              void* d_out, int out_size, void* d_ws, size_t ws_size,
                              hipStream_t stream) {
  const float* z       = (const float*)d_in[0];
  const int*   actions = (const int*)d_in[1];
  const int*   dones   = (const int*)d_in[2];
  const float* embed   = (const float*)d_in[3];
  const float* Wih     = (const float*)d_in[4];
  const float* Whh     = (const float*)d_in[5];
  const float* bih     = (const float*)d_in[6];
  const float* bhh     = (const float*)d_in[7];
  const float* Wout    = (const float*)d_in[8];
  const float* bout    = (const float*)d_in[9];
  float* out = (float*)d_out;

  if (ws_size < WS_END) return;  // fail visibly rather than corrupt memory

  char* ws = (char*)d_ws;
  u32* gcnt              = (u32*)(ws + WS_GCNT);
  u32* nact              = (u32*)(ws + WS_NACT);
  u32* hdr               = (u32*)(ws + WS_HDR);
  u32* metaA             = (u32*)(ws + WS_META);
  u32* loff              = (u32*)(ws + WS_LOFF);
  u32* tmp               = (u32*)(ws + WS_TMP);
  unsigned short* zt     = (unsigned short*)(ws + WS_ZT);
  unsigned short* wout16 = (unsigned short*)(ws + WS_WOUT);
  u64* hs2               = (u64*)(ws + WS_HS2);
  // d_out doubles as scratch during the recurrence (overwritten afterwards)
  u64* hsl   = (u64*)d_out;                          // ladder <= 33.4MB
  u64* call  = (u64*)((char*)d_out + DO_CALL);       // 32MB c-state (packed)

  hipMemsetAsync(d_ws, 0, 2048, stream);  // barrier counters only

  seg_build_k<<<1, 256, 0, stream>>>(dones, tmp, metaA, nact, hdr, loff);
  cvt_z_k<<<2048, 256, 0, stream>>>(z, zt);    // overwrites tmp after build
  zero_hs_tail_k<<<32, 256, 0, stream>>>(hs2);
  lstm_seg_k<<<256, 1024, 0, stream>>>(Whh, Wih, embed, bih, bhh, actions,
                                       zt, metaA, nact, hdr, loff, hsl, call,
                                       hs2, gcnt);
  cvt_wout_k<<<1921, 256, 0, stream>>>(Wout, wout16);
  out_gemm_k<<<dim3(256, 24), 256, 0, stream>>>(hs2, wout16, bout, out);
  donep_k<<<512, 256, 0, stream>>>(hs2, wout16, bout, out);
}

// Round 19
// 1036.301 us; speedup vs baseline: 3.4819x; 1.0095x over previous
//
#include <hip/hip_runtime.h>
#include <hip/hip_bf16.h>

// ---------------------------------------------------------------------------
// RNNModel (MDN-RNN). Segment algorithm (R9-R18): dones (p=0.5) reset h,c ->
// recurrence splits into segments; sorted desc by len so active-at-s =
// prefix [0,N_s). Ladder h-exchange: region_s at loff[s], each (slot,s)
// address written once (8B agent atomic), read once next step with plain
// coalesced 16B loads clamped inside region s. c/hs2 plain (R18).
// R19: amortize per-tile fixed cost -- M=64 slot tiles (512->256 tiles):
//   lane owns a whole slot (4 cols): no shfl packing, c = one 16B load/store,
//   per-kt B-frag amortized over 4 A-subtiles (4 MFMA/LDS-read). R16-R18
//   showed TLP/fence/atomics each worth only ~3-4% -> cost is distributed
//   per-tile overhead; halving tile count attacks it directly.
//   donep FUSED into out_gemm (nblk==23: 6th B-subtile holds W_out row 1920,
//   zero-padded rows 81-95; epilogue ln==0 writes done_p) -- deletes a
//   kernel that re-read 32MB of hs2.
// Kept: 16 waves/block, wave-autonomous tiles, no per-step fence, clamped
//   gathers, ladder agent atomics + vmcnt drain + group barrier, seg_build.
// ---------------------------------------------------------------------------

typedef float f4 __attribute__((ext_vector_type(4)));
typedef short s8 __attribute__((ext_vector_type(8)));
typedef unsigned short us8v __attribute__((ext_vector_type(8)));
typedef unsigned short us4v __attribute__((ext_vector_type(4)));
typedef unsigned long long u64;
typedef unsigned u32;

#define DEV __device__ __forceinline__

DEV unsigned short f2b(float f) {          // fp32 -> bf16 RNE
  unsigned u = __float_as_uint(f);
  return (unsigned short)((u + 0x7FFFu + ((u >> 16) & 1u)) >> 16);
}
DEV float b2f(unsigned short s) { return __uint_as_float(((unsigned)s) << 16); }

DEV f4 MFMA(s8 a, s8 b, f4 c) {
  return __builtin_amdgcn_mfma_f32_16x16x32_bf16(a, b, c, 0, 0, 0);
}
DEV s8 LD8(const unsigned short* p) { return *reinterpret_cast<const s8*>(p); }

DEV u32 AL32(const u32* p) {
  return __hip_atomic_load(p, __ATOMIC_RELAXED, __HIP_MEMORY_SCOPE_AGENT);
}
DEV void AS(u64* p, u64 v) {
  __hip_atomic_store(p, v, __ATOMIC_RELAXED, __HIP_MEMORY_SCOPE_AGENT);
}

DEV float sigf(float x) {   // 1/(1+e^-x) via v_exp + v_rcp (~1e-6 rel)
  float e = __builtin_amdgcn_exp2f(x * -1.44269504f);
  return __builtin_amdgcn_rcpf(1.f + e);
}
DEV float tanhf_fast(float x) {  // 1 - 2/(e^{2x}+1); saturates correctly
  float e = __builtin_amdgcn_exp2f(x * 2.88539008f);
  return 1.f - 2.f * __builtin_amdgcn_rcpf(e + 1.f);
}

// ---- d_ws layout (bytes) ----
static constexpr size_t WS_GCNT = 0;        // 16 group counters, 128B apart
static constexpr size_t WS_NACT = 2048;     // N_act[512] u32
static constexpr size_t WS_HDR  = 4096;     // hdr[0]=total, hdr[1]=maxlen
static constexpr size_t WS_META = 4352;     // meta[16384] u32
static constexpr size_t WS_LOFF = 69888;    // loff[512] u32
static constexpr size_t WS_TMP  = 131072;   // seg_build scratch (pre-zt)
static constexpr size_t WS_ZT   = 131072;   // zt [16384][128] bf16 (4MB)
static constexpr size_t WS_WOUT = 4325376;  // wout16 (3.75MB)
static constexpr size_t WS_HS2  = 8261632;  // hs2 [256][16384] u64 (32MB)
static constexpr size_t WS_END  = 41816064;
// ---- d_out scratch ----
// hsl ladder <= 33.4MB at d_out+0; c_all [256][8192][16B] at d_out+34MiB
static constexpr size_t DO_CALL = 35651584;

// ---------------------------------------------------------------------------
__global__ void cvt_wout_k(const float* __restrict__ W, unsigned short* __restrict__ o) {
  int i = blockIdx.x * 256 + threadIdx.x;         // 491776 float4 units exact
  if (i < 491776) {
    const float4 v = reinterpret_cast<const float4*>(W)[i];
    us4v u; u[0] = f2b(v.x); u[1] = f2b(v.y); u[2] = f2b(v.z); u[3] = f2b(v.w);
    reinterpret_cast<us4v*>(o)[i] = u;
  }
}

__global__ void cvt_z_k(const float* __restrict__ z, unsigned short* __restrict__ zt) {
  // z = 32*512*128 f32 = 524288 float4 units exact
  int i = blockIdx.x * 256 + threadIdx.x;
  if (i < 524288) {
    const float4 v = reinterpret_cast<const float4*>(z)[i];
    us4v u; u[0] = f2b(v.x); u[1] = f2b(v.y); u[2] = f2b(v.z); u[3] = f2b(v.w);
    reinterpret_cast<us4v*>(zt)[i] = u;
  }
}

__global__ void zero_hs_tail_k(u64* __restrict__ hs2) {
  int i = blockIdx.x * 256 + threadIdx.x;
  if (i < 8192) {
    int region = i >> 5, r = 16352 + (i & 31);
    hs2[(size_t)region * 16384 + r] = 0ull;
  }
}

// ---------------------------------------------------------------------------
// Segment scan + counting sort (desc by len) + ladder offsets. 1 block.
__global__ __launch_bounds__(256) void seg_build_k(
    const int* __restrict__ dones, u32* __restrict__ tmp,
    u32* __restrict__ meta, u32* __restrict__ nact, u32* __restrict__ hdr,
    u32* __restrict__ loff) {
  __shared__ u32 hist[512];
  __shared__ u32 cur[512];
  __shared__ u32 scnt[32];
  const int tid = threadIdx.x;
  for (int i = tid; i < 512; i += 256) hist[i] = 0;
  __syncthreads();
  if (tid < 32) {
    int b = tid, cnt = 0, t0 = 0;
    for (int t = 1; t <= 511; ++t) {
      bool brk = (t == 511) || (dones[b * 512 + t - 1] != 0);
      if (brk) {
        int len = t - t0;
        tmp[b * 511 + cnt] = ((u32)t0 << 16) | (u32)len;
        atomicAdd(&hist[len], 1u);
        ++cnt; t0 = t;
      }
    }
    scnt[b] = (u32)cnt;
  }
  __syncthreads();
  if (tid == 0) {
    u32 acc = 0; int ml = 0;
    for (int L = 511; L >= 0; --L) {
      cur[L] = acc; nact[L] = acc;
      if (hist[L] && !ml) ml = L;
      acc += hist[L];
    }
    hdr[0] = acc; hdr[1] = (u32)ml;
    u32 off = 0; loff[0] = 0;
    for (int s2 = 1; s2 <= ml; ++s2) { loff[s2] = off; off += nact[s2]; }
  }
  __syncthreads();
  if (tid < 32) {
    int b = tid; u32 c = scnt[b];
    for (u32 i = 0; i < c; ++i) {
      u32 e = tmp[b * 511 + i];
      u32 len = e & 0xFFFFu, t0 = e >> 16;
      u32 slot = atomicAdd(&cur[len], 1u);
      meta[slot] = ((u32)b << 20) | (t0 << 10) | len;
    }
  }
}

// ---------------------------------------------------------------------------
// Segment-batched LSTM, 64-slot wave-autonomous tiles + ladder exchange.
// grid=256, block=1024 (16 waves). Block blk owns h cols [4blk,4blk+4).
// Wave w -> tiles w, w+16, ... Lane owns one slot (4 cols) end-to-end.
__global__ __launch_bounds__(1024, 1) void lstm_seg_k(
    const float* __restrict__ Whh, const float* __restrict__ Wih,
    const float* __restrict__ embed, const float* __restrict__ bih,
    const float* __restrict__ bhh, const int* __restrict__ actions,
    const unsigned short* __restrict__ zt, const u32* __restrict__ meta,
    const u32* __restrict__ nact, const u32* __restrict__ hdr,
    const u32* __restrict__ loff, u64* __restrict__ hsl,
    u64* __restrict__ c_all, u64* __restrict__ hs2,
    u32* __restrict__ gcnt) {
  const int blk = blockIdx.x;
  const int tid = threadIdx.x;
  const int lane = tid & 63;
  const int w = tid >> 6;                 // wave 0..15
  const int ln = lane & 15, lk = lane >> 4;

  __shared__ alignas(16) unsigned short whh_sw[32 * 64 * 8];   // 32 KB
  __shared__ alignas(16) unsigned short wz_sw[4 * 64 * 8];     // 4 KB
  __shared__ float abias[18][16];
  __shared__ float red[16][64][17];       // wave-private gate transpose 68KB

  for (int i = tid; i < 32 * 64 * 8; i += 1024) {
    int j = i & 7, L = (i >> 3) & 63, kt = i >> 9;
    int n = L & 15;
    int grow = (n >> 2) * 1024 + blk * 4 + (n & 3);
    int k = kt * 32 + ((L >> 4) << 3) + j;
    whh_sw[i] = f2b(Whh[grow * 1024 + k]);
  }
  for (int i = tid; i < 4 * 64 * 8; i += 1024) {
    int j = i & 7, L = (i >> 3) & 63, kt = i >> 9;
    int n = L & 15;
    int grow = (n >> 2) * 1024 + blk * 4 + (n & 3);
    int k = kt * 32 + ((L >> 4) << 3) + j;
    wz_sw[i] = f2b(Wih[grow * 144 + k]);
  }
  for (int i = tid; i < 18 * 16; i += 1024) {
    int a = i >> 4, n = i & 15;
    int grow = (n >> 2) * 1024 + blk * 4 + (n & 3);
    float s = bih[grow] + bhh[grow];
    for (int j = 0; j < 16; ++j) s += embed[a * 16 + j] * Wih[grow * 144 + 128 + j];
    abias[a][n] = s;
  }
  __syncthreads();

  const int maxlen = (int)hdr[1];

  for (int s = 0; s < maxlen; ++s) {
    const u32 N = nact[s];                   // active slots (prefix)
    const int ntiles = (int)((N + 63) >> 6);
    const u64* hread = hsl + (size_t)loff[s] * 256;       // region s (s>=1)
    u64* hwrite = hsl + (size_t)loff[s + 1] * 256;        // region s+1

    for (int tile = w; tile < ntiles; tile += 16) {
      const u32 sb = (u32)tile << 6;
      const u32 slot = sb + (u32)lane;         // lane owns this slot
      const bool valid = slot < N;
      const u32 m = valid ? meta[slot] : 0u;
      const u32 b = m >> 20, t0 = (m >> 10) & 1023u, L = m & 1023u;
      const int zrow = (int)(b * 512u + t0 + (u32)s);
      const int orow = (int)(b * 511u + t0 + (u32)s);
      const u32 act = valid ? (u32)actions[zrow] : 0u;
      // c-state: one 16B plain load per lane (block-private L2)
      union { u64 q[2]; } cc; cc.q[0] = 0; cc.q[1] = 0;
      if (s && valid) {
        const u64* cp = c_all + ((size_t)blk << 14) + ((size_t)slot << 1);
        cc.q[0] = cp[0]; cc.q[1] = cp[1];
      }
      // z-row broadcast for the 4 A-subtiles (rows sb+ln+16q)
      int zr[4];
#pragma unroll
      for (int q = 0; q < 4; ++q) zr[q] = __shfl(zrow, ln + 16 * q, 64);

      f4 acc0 = {0.f,0.f,0.f,0.f}, acc1 = {0.f,0.f,0.f,0.f};
      f4 acc2 = {0.f,0.f,0.f,0.f}, acc3 = {0.f,0.f,0.f,0.f};
#pragma unroll
      for (int kz = 0; kz < 4; ++kz) {     // z contribution (K=128)
        s8 bf = LD8(wz_sw + ((kz * 64 + lane) << 3));
        s8 a0 = LD8(zt + (size_t)zr[0] * 128 + kz * 32 + (lk << 3));
        s8 a1 = LD8(zt + (size_t)zr[1] * 128 + kz * 32 + (lk << 3));
        s8 a2 = LD8(zt + (size_t)zr[2] * 128 + kz * 32 + (lk << 3));
        s8 a3 = LD8(zt + (size_t)zr[3] * 128 + kz * 32 + (lk << 3));
        acc0 = MFMA(a0, bf, acc0);  acc1 = MFMA(a1, bf, acc1);
        acc2 = MFMA(a2, bf, acc2);  acc3 = MFMA(a3, bf, acc3);
      }
      if (s) {  // h gather: plain coalesced 16B loads, clamped inside region
        const u32 r0c = (sb + (u32)ln      < N) ? sb + (u32)ln      : N - 1u;
        const u32 r1c = (sb + (u32)ln + 16 < N) ? sb + (u32)ln + 16 : N - 1u;
        const u32 r2c = (sb + (u32)ln + 32 < N) ? sb + (u32)ln + 32 : N - 1u;
        const u32 r3c = (sb + (u32)ln + 48 < N) ? sb + (u32)ln + 48 : N - 1u;
        const unsigned short* h0 =
            (const unsigned short*)(hread + (size_t)r0c * 256) + (lk << 3);
        const unsigned short* h1 =
            (const unsigned short*)(hread + (size_t)r1c * 256) + (lk << 3);
        const unsigned short* h2 =
            (const unsigned short*)(hread + (size_t)r2c * 256) + (lk << 3);
        const unsigned short* h3 =
            (const unsigned short*)(hread + (size_t)r3c * 256) + (lk << 3);
#pragma unroll 8
        for (int kt = 0; kt < 32; ++kt) {   // +kt*32 bf16 per K-step
          s8 bf = LD8(whh_sw + ((kt * 64 + lane) << 3));
          s8 f0 = LD8(h0 + (kt << 5));
          s8 f1 = LD8(h1 + (kt << 5));
          s8 f2 = LD8(h2 + (kt << 5));
          s8 f3 = LD8(h3 + (kt << 5));
          acc0 = MFMA(f0, bf, acc0);  acc1 = MFMA(f1, bf, acc1);
          acc2 = MFMA(f2, bf, acc2);  acc3 = MFMA(f3, bf, acc3);
        }
      }

      // transpose: D row(slot-in-tile) = 16q + 4*lk + j, col = ln
#pragma unroll
      for (int j = 0; j < 4; ++j) {
        red[w][(lk << 2) + j][ln]      = acc0[j];
        red[w][16 + (lk << 2) + j][ln] = acc1[j];
        red[w][32 + (lk << 2) + j][ln] = acc2[j];
        red[w][48 + (lk << 2) + j][ln] = acc3[j];
      }
      // same-wave DS ordering: reads wait on lgkmcnt for the writes above
      const bool carry = valid && (L > (u32)(s + 1));
      u32 cb[4]; unsigned short hb[4];
#pragma unroll
      for (int e = 0; e < 4; ++e) {   // lane's slot, cols 0..3
        float gi = red[w][lane][e]      + abias[act][e];
        float gf = red[w][lane][4 + e]  + abias[act][4 + e];
        float gg = red[w][lane][8 + e]  + abias[act][8 + e];
        float go = red[w][lane][12 + e] + abias[act][12 + e];
        const u32 cpb = (e == 0) ? (u32)cc.q[0] : (e == 1) ? (u32)(cc.q[0] >> 32)
                       : (e == 2) ? (u32)cc.q[1] : (u32)(cc.q[1] >> 32);
        const float cprev = __uint_as_float(cpb);
        const float si = sigf(gi), sf = sigf(gf), so = sigf(go);
        const float cn = sf * cprev + si * tanhf_fast(gg);
        const float hn = so * tanhf_fast(cn);
        cb[e] = __float_as_uint(cn);
        hb[e] = f2b(hn);
      }
      if (carry) {   // c carry: one 16B plain store
        u64* cp = c_all + ((size_t)blk << 14) + ((size_t)slot << 1);
        cp[0] = ((u64)cb[1] << 32) | (u64)cb[0];
        cp[1] = ((u64)cb[3] << 32) | (u64)cb[2];
      }
      const u64 hu = (u64)hb[0] | ((u64)hb[1] << 16) |
                     ((u64)hb[2] << 32) | ((u64)hb[3] << 48);
      if (valid) {
        hs2[((size_t)blk << 14) + orow] = hu;          // history (plain)
        if (carry) AS(hwrite + (size_t)slot * 256 + blk, hu);  // carry h
      }
    }

    // per-wave drain of stores, block sync, global barrier
    asm volatile("s_waitcnt vmcnt(0)" ::: "memory");
    __syncthreads();
    if (s + 1 < maxlen) {
      if (tid == 0) {
        __hip_atomic_fetch_add(gcnt + (blk >> 4) * 32, 1u,
                               __ATOMIC_RELAXED, __HIP_MEMORY_SCOPE_AGENT);
        const u32 tgt = (u32)(s + 1) * 16u;
        for (u32 spin = 0; spin < (1u << 20); ++spin) {
          u32 mn = 0xFFFFFFFFu;
#pragma unroll
          for (int g = 0; g < 16; ++g) {
            u32 v = AL32(gcnt + g * 32);
            mn = (v < mn) ? v : mn;
          }
          if (mn >= tgt) break;
          __builtin_amdgcn_s_sleep(1);
        }
      }
      __syncthreads();
    }
  }
}

// ---------------------------------------------------------------------------
// out = hs @ W_out^T (+bias), fused logsumexp on logmix; nblk==23 also
// computes done_p (W_out row 1920) via a 6th zero-padded B-subtile.
__global__ __launch_bounds__(256, 2) void out_gemm_k(
    const u64* __restrict__ hs2, const unsigned short* __restrict__ wout,
    const float* __restrict__ b_out, float* __restrict__ out) {
  const int mblk = blockIdx.x, nblk = blockIdx.y;
  const int tid = threadIdx.x, lane = tid & 63, w = tid >> 6;
  const int ln = lane & 15, lk = lane >> 4;
  __shared__ alignas(16) unsigned char smraw[26112];
  unsigned short* bsm = (unsigned short*)smraw;  // [96][136] bf16 B-chunk
  float* ep = (float*)smraw;                     // [64][84] f32 epilogue tile
  const bool last = (nblk == 23);

  if (last) {  // zero pad rows 81..95 once (cols 1921+ of the 6th subtile)
    for (int i = tid; i < 15 * 136; i += 256) bsm[81 * 136 + i] = 0;
  }
  __syncthreads();

  const int r0 = mblk * 64 + w * 16;
  f4 acc[5];
#pragma unroll
  for (int s = 0; s < 5; ++s) acc[s] = (f4){0.f, 0.f, 0.f, 0.f};
  f4 acc5 = {0.f, 0.f, 0.f, 0.f};

  for (int kc = 0; kc < 8; ++kc) {  // K chunks of 128
#pragma unroll
    for (int ii = 0; ii < 5; ++ii) {           // 1280 us8 chunks exact
      int i = tid + ii * 256;
      int n = i >> 4, k16 = i & 15;
      us8v v = *reinterpret_cast<const us8v*>(
          wout + (size_t)(nblk * 80 + n) * 1024 + kc * 128 + (k16 << 3));
      *reinterpret_cast<us8v*>(bsm + n * 136 + (k16 << 3)) = v;
    }
    if (last && tid < 16) {                    // row 80 = wout row 1920
      us8v v = *reinterpret_cast<const us8v*>(
          wout + (size_t)1920 * 1024 + kc * 128 + (tid << 3));
      *reinterpret_cast<us8v*>(bsm + 80 * 136 + (tid << 3)) = v;
    }
    __syncthreads();
#pragma unroll
    for (int ks = 0; ks < 4; ++ks) {
      const int k0 = kc * 128 + ks * 32 + (lk << 3);
      union { u64 q[2]; s8 v; } ua;            // A-frag: 2 x 8B from hs2
      ua.q[0] = hs2[(size_t)(k0 >> 2) * 16384 + r0 + ln];
      ua.q[1] = hs2[((size_t)(k0 >> 2) + 1) * 16384 + r0 + ln];
#pragma unroll
      for (int s = 0; s < 5; ++s) {
        s8 b = LD8(bsm + (s * 16 + ln) * 136 + ks * 32 + (lk << 3));
        acc[s] = MFMA(ua.v, b, acc[s]);
      }
      if (last) {
        s8 b6 = LD8(bsm + ((80 + ln) * 136) + ks * 32 + (lk << 3));
        acc5 = MFMA(ua.v, b6, acc5);
      }
    }
    __syncthreads();
  }

  const int T = nblk >> 3;  // 0 logmix, 1 mu, 2 logstd
  if (T) {
    float* base = out + (size_t)10465280 * T;
    const int lc0 = (nblk - (T << 3)) * 80;
#pragma unroll
    for (int s = 0; s < 5; ++s) {
      const int lc = lc0 + s * 16 + ln;
      const float bias = b_out[T * 640 + lc];
#pragma unroll
      for (int j = 0; j < 4; ++j) {
        const int row = r0 + (lk << 2) + j;
        if (row < 16352) base[(size_t)row * 640 + lc] = acc[s][j] + bias;
      }
    }
    if (last && ln == 0) {     // done_p: col 0 of the 6th subtile
      const float bias = b_out[1920];
#pragma unroll
      for (int j = 0; j < 4; ++j) {
        const int row = r0 + (lk << 2) + j;
        if (row < 16352) out[31395840 + row] = acc5[j] + bias;
      }
    }
  } else {  // logmix: bounce through LDS, per-(row, z-group) logsumexp over 5
#pragma unroll
    for (int s = 0; s < 5; ++s) {
      const float bias = b_out[nblk * 80 + s * 16 + ln];
#pragma unroll
      for (int j = 0; j < 4; ++j)
        ep[(w * 16 + (lk << 2) + j) * 84 + s * 16 + ln] = acc[s][j] + bias;
    }
    __syncthreads();
    for (int task = tid; task < 1024; task += 256) {
      const int rr = task >> 4, grp = task & 15;
      const int row = mblk * 64 + rr;
      const float* e = ep + rr * 84 + grp * 5;
      float v0 = e[0], v1 = e[1], v2 = e[2], v3 = e[3], v4 = e[4];
      float mx = fmaxf(fmaxf(fmaxf(v0, v1), fmaxf(v2, v3)), v4);
      float ssum = expf(v0 - mx) + expf(v1 - mx) + expf(v2 - mx) +
                   expf(v3 - mx) + expf(v4 - mx);
      float lse = mx + logf(ssum);
      if (row < 16352) {
        float* o = out + (size_t)row * 640 + nblk * 80 + grp * 5;
        o[0] = v0 - lse; o[1] = v1 - lse; o[2] = v2 - lse;
        o[3] = v3 - lse; o[4] = v4 - lse;
      }
    }
  }
}

// ---------------------------------------------------------------------------
extern "C" void kernel_launch(void* const* d_in, const int* in_sizes, int n_in,
                              void* d_out, int out_size, void* d_ws, size_t ws_size,
                              hipStream_t stream) {
  const float* z       = (const float*)d_in[0];
  const int*   actions = (const int*)d_in[1];
  const int*   dones   = (const int*)d_in[2];
  const float* embed   = (const float*)d_in[3];
  const float* Wih     = (const float*)d_in[4];
  const float* Whh     = (const float*)d_in[5];
  const float* bih     = (const float*)d_in[6];
  const float* bhh     = (const float*)d_in[7];
  const float* Wout    = (const float*)d_in[8];
  const float* bout    = (const float*)d_in[9];
  float* out = (float*)d_out;

  if (ws_size < WS_END) return;  // fail visibly rather than corrupt memory

  char* ws = (char*)d_ws;
  u32* gcnt              = (u32*)(ws + WS_GCNT);
  u32* nact              = (u32*)(ws + WS_NACT);
  u32* hdr               = (u32*)(ws + WS_HDR);
  u32* metaA             = (u32*)(ws + WS_META);
  u32* loff              = (u32*)(ws + WS_LOFF);
  u32* tmp               = (u32*)(ws + WS_TMP);
  unsigned short* zt     = (unsigned short*)(ws + WS_ZT);
  unsigned short* wout16 = (unsigned short*)(ws + WS_WOUT);
  u64* hs2               = (u64*)(ws + WS_HS2);
  // d_out doubles as scratch during the recurrence (overwritten afterwards)
  u64* hsl   = (u64*)d_out;                          // ladder <= 33.4MB
  u64* call  = (u64*)((char*)d_out + DO_CALL);       // 32MB c-state (packed)

  hipMemsetAsync(d_ws, 0, 2048, stream);  // barrier counters only

  seg_build_k<<<1, 256, 0, stream>>>(dones, tmp, metaA, nact, hdr, loff);
  cvt_z_k<<<2048, 256, 0, stream>>>(z, zt);    // overwrites tmp after build
  zero_hs_tail_k<<<32, 256, 0, stream>>>(hs2);
  lstm_seg_k<<<256, 1024, 0, stream>>>(Whh, Wih, embed, bih, bhh, actions,
                                       zt, metaA, nact, hdr, loff, hsl, call,
                                       hs2, gcnt);
  cvt_wout_k<<<1921, 256, 0, stream>>>(Wout, wout16);
  out_gemm_k<<<dim3(256, 24), 256, 0, stream>>>(hs2, wout16, bout, out);
}

// Round 20
// 863.588 us; speedup vs baseline: 4.1783x; 1.2000x over previous
//
#include <hip/hip_runtime.h>
#include <hip/hip_bf16.h>

// ---------------------------------------------------------------------------
// RNNModel (MDN-RNN). Segment algorithm (R9-R19). R20: 8-COL GROUPS.
// 256 blocks = 128 col-groups x 2 slot-halves. Group g owns h cols
// [8g,8g+8) = 32 gate rows; the pair splits slot tiles by parity.
// Each 16B gather load feeds 2 N-subtiles (8 MFMA/kt) -> per-block gather
// volume AND L2 request count halve (R16-R19 showed TLP/fence/atomics/
// per-tile overhead each <=4%: the wall is L2 request throughput,
// ~19M req/XCD ~= 500us). MFMA total unchanged.
//   hs2 -> [128 regions][16384 rows][2 u64]; out_gemm A-frag = one 16B load.
//   c_all -> 32B/slot, block-private (slot parity stable across steps).
//   Ladder row: each group's half-block writes its 2 u64 per slot (atomic).
// Kept: ladder + clamp + plain gathers, no fence, vmcnt drain + group
// barrier, seg_build, fused done_p in out_gemm.
// ---------------------------------------------------------------------------

typedef float f4 __attribute__((ext_vector_type(4)));
typedef short s8 __attribute__((ext_vector_type(8)));
typedef unsigned short us8v __attribute__((ext_vector_type(8)));
typedef unsigned short us4v __attribute__((ext_vector_type(4)));
typedef unsigned long long u64;
typedef unsigned u32;

#define DEV __device__ __forceinline__

DEV unsigned short f2b(float f) {          // fp32 -> bf16 RNE
  unsigned u = __float_as_uint(f);
  return (unsigned short)((u + 0x7FFFu + ((u >> 16) & 1u)) >> 16);
}
DEV float b2f(unsigned short s) { return __uint_as_float(((unsigned)s) << 16); }

DEV f4 MFMA(s8 a, s8 b, f4 c) {
  return __builtin_amdgcn_mfma_f32_16x16x32_bf16(a, b, c, 0, 0, 0);
}
DEV s8 LD8(const unsigned short* p) { return *reinterpret_cast<const s8*>(p); }

DEV u32 AL32(const u32* p) {
  return __hip_atomic_load(p, __ATOMIC_RELAXED, __HIP_MEMORY_SCOPE_AGENT);
}
DEV void AS(u64* p, u64 v) {
  __hip_atomic_store(p, v, __ATOMIC_RELAXED, __HIP_MEMORY_SCOPE_AGENT);
}

DEV float sigf(float x) {
  float e = __builtin_amdgcn_exp2f(x * -1.44269504f);
  return __builtin_amdgcn_rcpf(1.f + e);
}
DEV float tanhf_fast(float x) {
  float e = __builtin_amdgcn_exp2f(x * 2.88539008f);
  return 1.f - 2.f * __builtin_amdgcn_rcpf(e + 1.f);
}

// ---- d_ws layout (bytes) ----
static constexpr size_t WS_GCNT = 0;        // 16 group counters, 128B apart
static constexpr size_t WS_NACT = 2048;
static constexpr size_t WS_HDR  = 4096;
static constexpr size_t WS_META = 4352;     // meta[16384] u32
static constexpr size_t WS_LOFF = 69888;    // loff[512] u32
static constexpr size_t WS_TMP  = 131072;
static constexpr size_t WS_ZT   = 131072;   // zt [16384][128] bf16 (4MB)
static constexpr size_t WS_WOUT = 4325376;  // wout16 (3.75MB)
static constexpr size_t WS_HS2  = 8261632;  // hs2 [128][16384][2 u64] (32MB)
static constexpr size_t WS_END  = 41816064;
// ---- d_out scratch ----
// hsl ladder <= 33.4MB at +0; c_all [256 blk][8192 slot][4 u64] = 64MB
static constexpr size_t DO_CALL = 35651584;

// ---------------------------------------------------------------------------
__global__ void cvt_wout_k(const float* __restrict__ W, unsigned short* __restrict__ o) {
  int i = blockIdx.x * 256 + threadIdx.x;         // 491776 float4 units exact
  if (i < 491776) {
    const float4 v = reinterpret_cast<const float4*>(W)[i];
    us4v u; u[0] = f2b(v.x); u[1] = f2b(v.y); u[2] = f2b(v.z); u[3] = f2b(v.w);
    reinterpret_cast<us4v*>(o)[i] = u;
  }
}

__global__ void cvt_z_k(const float* __restrict__ z, unsigned short* __restrict__ zt) {
  int i = blockIdx.x * 256 + threadIdx.x;         // 524288 float4 units exact
  if (i < 524288) {
    const float4 v = reinterpret_cast<const float4*>(z)[i];
    us4v u; u[0] = f2b(v.x); u[1] = f2b(v.y); u[2] = f2b(v.z); u[3] = f2b(v.w);
    reinterpret_cast<us4v*>(zt)[i] = u;
  }
}

__global__ void zero_hs_tail_k(u64* __restrict__ hs2) {
  // rows 16352..16383 of all 128 regions x 2 u64 = 8192 u64
  int i = blockIdx.x * 256 + threadIdx.x;
  if (i < 8192) {
    int region = i >> 6, rr = (i & 63) >> 1, hf = i & 1;
    hs2[((size_t)region * 16384 + 16352 + rr) * 2 + hf] = 0ull;
  }
}

// ---------------------------------------------------------------------------
// Segment scan + counting sort (desc by len) + ladder offsets. 1 block.
__global__ __launch_bounds__(256) void seg_build_k(
    const int* __restrict__ dones, u32* __restrict__ tmp,
    u32* __restrict__ meta, u32* __restrict__ nact, u32* __restrict__ hdr,
    u32* __restrict__ loff) {
  __shared__ u32 hist[512];
  __shared__ u32 cur[512];
  __shared__ u32 scnt[32];
  const int tid = threadIdx.x;
  for (int i = tid; i < 512; i += 256) hist[i] = 0;
  __syncthreads();
  if (tid < 32) {
    int b = tid, cnt = 0, t0 = 0;
    for (int t = 1; t <= 511; ++t) {
      bool brk = (t == 511) || (dones[b * 512 + t - 1] != 0);
      if (brk) {
        int len = t - t0;
        tmp[b * 511 + cnt] = ((u32)t0 << 16) | (u32)len;
        atomicAdd(&hist[len], 1u);
        ++cnt; t0 = t;
      }
    }
    scnt[b] = (u32)cnt;
  }
  __syncthreads();
  if (tid == 0) {
    u32 acc = 0; int ml = 0;
    for (int L = 511; L >= 0; --L) {
      cur[L] = acc; nact[L] = acc;
      if (hist[L] && !ml) ml = L;
      acc += hist[L];
    }
    hdr[0] = acc; hdr[1] = (u32)ml;
    u32 off = 0; loff[0] = 0;
    for (int s2 = 1; s2 <= ml; ++s2) { loff[s2] = off; off += nact[s2]; }
  }
  __syncthreads();
  if (tid < 32) {
    int b = tid; u32 c = scnt[b];
    for (u32 i = 0; i < c; ++i) {
      u32 e = tmp[b * 511 + i];
      u32 len = e & 0xFFFFu, t0 = e >> 16;
      u32 slot = atomicAdd(&cur[len], 1u);
      meta[slot] = ((u32)b << 20) | (t0 << 10) | len;
    }
  }
}

// ---------------------------------------------------------------------------
// Segment-batched LSTM. grid=256 = 128 col-groups x 2 halves; block=512
// (8 waves). Group g owns 8 h-cols = 32 gate rows; half processes tiles with
// (tile&1)==half. Lane owns one slot (8 cols). Wave-autonomous 64-slot tiles.
__global__ __launch_bounds__(512, 1) void lstm_seg_k(
    const float* __restrict__ Whh, const float* __restrict__ Wih,
    const float* __restrict__ embed, const float* __restrict__ bih,
    const float* __restrict__ bhh, const int* __restrict__ actions,
    const unsigned short* __restrict__ zt, const u32* __restrict__ meta,
    const u32* __restrict__ nact, const u32* __restrict__ hdr,
    const u32* __restrict__ loff, u64* __restrict__ hsl,
    u64* __restrict__ c_all, u64* __restrict__ hs2,
    u32* __restrict__ gcnt) {
  const int blk = blockIdx.x;
  const int g = blk >> 1;                 // col-group 0..127
  const int half = blk & 1;               // slot-tile parity
  const int tid = threadIdx.x;
  const int lane = tid & 63;
  const int w = tid >> 6;                 // wave 0..7
  const int ln = lane & 15, lk = lane >> 4;

  __shared__ alignas(16) unsigned short whh_sw[32 * 2 * 64 * 8];  // 64 KB
  __shared__ alignas(16) unsigned short wz_sw[4 * 2 * 64 * 8];    // 8 KB
  __shared__ float abias[18][32];
  __shared__ float red[8][64][33];        // wave-private transpose 67.6KB

  for (int i = tid; i < 32768; i += 512) {
    int j = i & 7, L = (i >> 3) & 63, nt = (i >> 9) & 1, kt = i >> 10;
    int n = nt * 16 + (L & 15);           // packed gate idx 0..31
    int grow = (n >> 3) * 1024 + g * 8 + (n & 7);
    int k = kt * 32 + ((L >> 4) << 3) + j;
    whh_sw[i] = f2b(Whh[grow * 1024 + k]);
  }
  for (int i = tid; i < 4096; i += 512) {
    int j = i & 7, L = (i >> 3) & 63, nt = (i >> 9) & 1, kz = i >> 10;
    int n = nt * 16 + (L & 15);
    int grow = (n >> 3) * 1024 + g * 8 + (n & 7);
    int k = kz * 32 + ((L >> 4) << 3) + j;
    wz_sw[i] = f2b(Wih[grow * 144 + k]);
  }
  for (int i = tid; i < 18 * 32; i += 512) {
    int a = i >> 5, n = i & 31;
    int grow = (n >> 3) * 1024 + g * 8 + (n & 7);
    float s = bih[grow] + bhh[grow];
    for (int j = 0; j < 16; ++j) s += embed[a * 16 + j] * Wih[grow * 144 + 128 + j];
    abias[a][n] = s;
  }
  __syncthreads();

  const int maxlen = (int)hdr[1];

  for (int s = 0; s < maxlen; ++s) {
    const u32 N = nact[s];
    const int ntiles = (int)((N + 63) >> 6);
    const u64* hread = hsl + (size_t)loff[s] * 256;
    u64* hwrite = hsl + (size_t)loff[s + 1] * 256;

    for (int tile = half + 2 * w; tile < ntiles; tile += 16) {
      const u32 sb = (u32)tile << 6;
      const u32 slot = sb + (u32)lane;
      const bool valid = slot < N;
      const u32 m = valid ? meta[slot] : 0u;
      const u32 b = m >> 20, t0 = (m >> 10) & 1023u, L = m & 1023u;
      const int zrow = (int)(b * 512u + t0 + (u32)s);
      const int orow = (int)(b * 511u + t0 + (u32)s);
      const u32 act = valid ? (u32)actions[zrow] : 0u;
      // c-state: 32B per slot, block-private (slot parity stable)
      u64 cq[4] = {0, 0, 0, 0};
      if (s && valid) {
        const u64* cp = c_all + ((size_t)blk << 15) + ((size_t)slot << 2);
        cq[0] = cp[0]; cq[1] = cp[1]; cq[2] = cp[2]; cq[3] = cp[3];
      }
      int zr[4];
#pragma unroll
      for (int q = 0; q < 4; ++q) zr[q] = __shfl(zrow, ln + 16 * q, 64);

      f4 a00 = {0,0,0,0}, a01 = {0,0,0,0}, a10 = {0,0,0,0}, a11 = {0,0,0,0};
      f4 a20 = {0,0,0,0}, a21 = {0,0,0,0}, a30 = {0,0,0,0}, a31 = {0,0,0,0};
#pragma unroll
      for (int kz = 0; kz < 4; ++kz) {     // z contribution (K=128)
        s8 b0 = LD8(wz_sw + (((kz * 2 + 0) * 64 + lane) << 3));
        s8 b1 = LD8(wz_sw + (((kz * 2 + 1) * 64 + lane) << 3));
        s8 f0 = LD8(zt + (size_t)zr[0] * 128 + kz * 32 + (lk << 3));
        s8 f1 = LD8(zt + (size_t)zr[1] * 128 + kz * 32 + (lk << 3));
        s8 f2 = LD8(zt + (size_t)zr[2] * 128 + kz * 32 + (lk << 3));
        s8 f3 = LD8(zt + (size_t)zr[3] * 128 + kz * 32 + (lk << 3));
        a00 = MFMA(f0, b0, a00);  a01 = MFMA(f0, b1, a01);
        a10 = MFMA(f1, b0, a10);  a11 = MFMA(f1, b1, a11);
        a20 = MFMA(f2, b0, a20);  a21 = MFMA(f2, b1, a21);
        a30 = MFMA(f3, b0, a30);  a31 = MFMA(f3, b1, a31);
      }
      if (s) {  // h gather: plain coalesced 16B loads, clamped inside region
        const u32 r0c = (sb + (u32)ln      < N) ? sb + (u32)ln      : N - 1u;
        const u32 r1c = (sb + (u32)ln + 16 < N) ? sb + (u32)ln + 16 : N - 1u;
        const u32 r2c = (sb + (u32)ln + 32 < N) ? sb + (u32)ln + 32 : N - 1u;
        const u32 r3c = (sb + (u32)ln + 48 < N) ? sb + (u32)ln + 48 : N - 1u;
        const unsigned short* h0 =
            (const unsigned short*)(hread + (size_t)r0c * 256) + (lk << 3);
        const unsigned short* h1 =
            (const unsigned short*)(hread + (size_t)r1c * 256) + (lk << 3);
        const unsigned short* h2 =
            (const unsigned short*)(hread + (size_t)r2c * 256) + (lk << 3);
        const unsigned short* h3 =
            (const unsigned short*)(hread + (size_t)r3c * 256) + (lk << 3);
#pragma unroll 8
        for (int kt = 0; kt < 32; ++kt) {
          s8 b0 = LD8(whh_sw + (((kt * 2 + 0) * 64 + lane) << 3));
          s8 b1 = LD8(whh_sw + (((kt * 2 + 1) * 64 + lane) << 3));
          s8 f0 = LD8(h0 + (kt << 5));
          s8 f1 = LD8(h1 + (kt << 5));
          s8 f2 = LD8(h2 + (kt << 5));
          s8 f3 = LD8(h3 + (kt << 5));
          a00 = MFMA(f0, b0, a00);  a01 = MFMA(f0, b1, a01);
          a10 = MFMA(f1, b0, a10);  a11 = MFMA(f1, b1, a11);
          a20 = MFMA(f2, b0, a20);  a21 = MFMA(f2, b1, a21);
          a30 = MFMA(f3, b0, a30);  a31 = MFMA(f3, b1, a31);
        }
      }

      // transpose: D row = 16q + 4lk + j, col = nt*16 + ln
#pragma unroll
      for (int j = 0; j < 4; ++j) {
        red[w][(lk << 2) + j][ln]           = a00[j];
        red[w][(lk << 2) + j][16 + ln]      = a01[j];
        red[w][16 + (lk << 2) + j][ln]      = a10[j];
        red[w][16 + (lk << 2) + j][16 + ln] = a11[j];
        red[w][32 + (lk << 2) + j][ln]      = a20[j];
        red[w][32 + (lk << 2) + j][16 + ln] = a21[j];
        red[w][48 + (lk << 2) + j][ln]      = a30[j];
        red[w][48 + (lk << 2) + j][16 + ln] = a31[j];
      }
      // same-wave DS ordering
      const bool carry = valid && (L > (u32)(s + 1));
      u32 cb[8]; unsigned short hb[8];
#pragma unroll
      for (int e = 0; e < 8; ++e) {   // lane's slot, cols 0..7
        float gi = red[w][lane][e]      + abias[act][e];
        float gf = red[w][lane][8 + e]  + abias[act][8 + e];
        float gg = red[w][lane][16 + e] + abias[act][16 + e];
        float go = red[w][lane][24 + e] + abias[act][24 + e];
        const u32 cpb = (e & 1) ? (u32)(cq[e >> 1] >> 32) : (u32)cq[e >> 1];
        const float cprev = __uint_as_float(cpb);
        const float si = sigf(gi), sf = sigf(gf), so = sigf(go);
        const float cn = sf * cprev + si * tanhf_fast(gg);
        const float hn = so * tanhf_fast(cn);
        cb[e] = __float_as_uint(cn);
        hb[e] = f2b(hn);
      }
      if (carry) {   // c carry: 32B plain store
        u64* cp = c_all + ((size_t)blk << 15) + ((size_t)slot << 2);
        cp[0] = ((u64)cb[1] << 32) | (u64)cb[0];
        cp[1] = ((u64)cb[3] << 32) | (u64)cb[2];
        cp[2] = ((u64)cb[5] << 32) | (u64)cb[4];
        cp[3] = ((u64)cb[7] << 32) | (u64)cb[6];
      }
      const u64 hu0 = (u64)hb[0] | ((u64)hb[1] << 16) |
                      ((u64)hb[2] << 32) | ((u64)hb[3] << 48);
      const u64 hu1 = (u64)hb[4] | ((u64)hb[5] << 16) |
                      ((u64)hb[6] << 32) | ((u64)hb[7] << 48);
      if (valid) {
        u64* hp = hs2 + ((size_t)g * 16384 + orow) * 2;
        hp[0] = hu0; hp[1] = hu1;                      // history (plain)
        if (carry) {                                   // carry h (atomic)
          AS(hwrite + (size_t)slot * 256 + 2 * g, hu0);
          AS(hwrite + (size_t)slot * 256 + 2 * g + 1, hu1);
        }
      }
    }

    // per-wave drain, block sync, global barrier
    asm volatile("s_waitcnt vmcnt(0)" ::: "memory");
    __syncthreads();
    if (s + 1 < maxlen) {
      if (tid == 0) {
        __hip_atomic_fetch_add(gcnt + (blk >> 4) * 32, 1u,
                               __ATOMIC_RELAXED, __HIP_MEMORY_SCOPE_AGENT);
        const u32 tgt = (u32)(s + 1) * 16u;
        for (u32 spin = 0; spin < (1u << 20); ++spin) {
          u32 mn = 0xFFFFFFFFu;
#pragma unroll
          for (int gg2 = 0; gg2 < 16; ++gg2) {
            u32 v = AL32(gcnt + gg2 * 32);
            mn = (v < mn) ? v : mn;
          }
          if (mn >= tgt) break;
          __builtin_amdgcn_s_sleep(1);
        }
      }
      __syncthreads();
    }
  }
}

// ---------------------------------------------------------------------------
// out = hs @ W_out^T (+bias), fused logsumexp on logmix; nblk==23 also
// computes done_p (W_out row 1920) via a 6th zero-padded B-subtile.
__global__ __launch_bounds__(256, 2) void out_gemm_k(
    const u64* __restrict__ hs2, const unsigned short* __restrict__ wout,
    const float* __restrict__ b_out, float* __restrict__ out) {
  const int mblk = blockIdx.x, nblk = blockIdx.y;
  const int tid = threadIdx.x, lane = tid & 63, w = tid >> 6;
  const int ln = lane & 15, lk = lane >> 4;
  __shared__ alignas(16) unsigned char smraw[26112];
  unsigned short* bsm = (unsigned short*)smraw;  // [96][136] bf16 B-chunk
  float* ep = (float*)smraw;                     // [64][84] f32 epilogue tile
  const bool last = (nblk == 23);

  if (last) {
    for (int i = tid; i < 15 * 136; i += 256) bsm[81 * 136 + i] = 0;
  }
  __syncthreads();

  const int r0 = mblk * 64 + w * 16;
  f4 acc[5];
#pragma unroll
  for (int s = 0; s < 5; ++s) acc[s] = (f4){0.f, 0.f, 0.f, 0.f};
  f4 acc5 = {0.f, 0.f, 0.f, 0.f};

  for (int kc = 0; kc < 8; ++kc) {  // K chunks of 128
#pragma unroll
    for (int ii = 0; ii < 5; ++ii) {
      int i = tid + ii * 256;
      int n = i >> 4, k16 = i & 15;
      us8v v = *reinterpret_cast<const us8v*>(
          wout + (size_t)(nblk * 80 + n) * 1024 + kc * 128 + (k16 << 3));
      *reinterpret_cast<us8v*>(bsm + n * 136 + (k16 << 3)) = v;
    }
    if (last && tid < 16) {
      us8v v = *reinterpret_cast<const us8v*>(
          wout + (size_t)1920 * 1024 + kc * 128 + (tid << 3));
      *reinterpret_cast<us8v*>(bsm + 80 * 136 + (tid << 3)) = v;
    }
    __syncthreads();
#pragma unroll
    for (int ks = 0; ks < 4; ++ks) {
      const int k0 = kc * 128 + ks * 32 + (lk << 3);
      // A-frag: one 16B load from hs2[group = k0>>3][row][2 u64]
      s8 a = *reinterpret_cast<const s8*>(
          hs2 + ((size_t)(k0 >> 3) * 16384 + r0 + ln) * 2);
#pragma unroll
      for (int s = 0; s < 5; ++s) {
        s8 b = LD8(bsm + (s * 16 + ln) * 136 + ks * 32 + (lk << 3));
        acc[s] = MFMA(a, b, acc[s]);
      }
      if (last) {
        s8 b6 = LD8(bsm + ((80 + ln) * 136) + ks * 32 + (lk << 3));
        acc5 = MFMA(a, b6, acc5);
      }
    }
    __syncthreads();
  }

  const int T = nblk >> 3;  // 0 logmix, 1 mu, 2 logstd
  if (T) {
    float* base = out + (size_t)10465280 * T;
    const int lc0 = (nblk - (T << 3)) * 80;
#pragma unroll
    for (int s = 0; s < 5; ++s) {
      const int lc = lc0 + s * 16 + ln;
      const float bias = b_out[T * 640 + lc];
#pragma unroll
      for (int j = 0; j < 4; ++j) {
        const int row = r0 + (lk << 2) + j;
        if (row < 16352) base[(size_t)row * 640 + lc] = acc[s][j] + bias;
      }
    }
    if (last && ln == 0) {
      const float bias = b_out[1920];
#pragma unroll
      for (int j = 0; j < 4; ++j) {
        const int row = r0 + (lk << 2) + j;
        if (row < 16352) out[31395840 + row] = acc5[j] + bias;
      }
    }
  } else {  // logmix: LDS bounce + per-(row, z-group) logsumexp over 5
#pragma unroll
    for (int s = 0; s < 5; ++s) {
      const float bias = b_out[nblk * 80 + s * 16 + ln];
#pragma unroll
      for (int j = 0; j < 4; ++j)
        ep[(w * 16 + (lk << 2) + j) * 84 + s * 16 + ln] = acc[s][j] + bias;
    }
    __syncthreads();
    for (int task = tid; task < 1024; task += 256) {
      const int rr = task >> 4, grp = task & 15;
      const int row = mblk * 64 + rr;
      const float* e = ep + rr * 84 + grp * 5;
      float v0 = e[0], v1 = e[1], v2 = e[2], v3 = e[3], v4 = e[4];
      float mx = fmaxf(fmaxf(fmaxf(v0, v1), fmaxf(v2, v3)), v4);
      float ssum = expf(v0 - mx) + expf(v1 - mx) + expf(v2 - mx) +
                   expf(v3 - mx) + expf(v4 - mx);
      float lse = mx + logf(ssum);
      if (row < 16352) {
        float* o = out + (size_t)row * 640 + nblk * 80 + grp * 5;
        o[0] = v0 - lse; o[1] = v1 - lse; o[2] = v2 - lse;
        o[3] = v3 - lse; o[4] = v4 - lse;
      }
    }
  }
}

// ---------------------------------------------------------------------------
extern "C" void kernel_launch(void* const* d_in, const int* in_sizes, int n_in,
                              void* d_out, int out_size, void* d_ws, size_t ws_size,
                              hipStream_t stream) {
  const float* z       = (const float*)d_in[0];
  const int*   actions = (const int*)d_in[1];
  const int*   dones   = (const int*)d_in[2];
  const float* embed   = (const float*)d_in[3];
  const float* Wih     = (const float*)d_in[4];
  const float* Whh     = (const float*)d_in[5];
  const float* bih     = (const float*)d_in[6];
  const float* bhh     = (const float*)d_in[7];
  const float* Wout    = (const float*)d_in[8];
  const float* bout    = (const float*)d_in[9];
  float* out = (float*)d_out;

  if (ws_size < WS_END) return;

  char* ws = (char*)d_ws;
  u32* gcnt              = (u32*)(ws + WS_GCNT);
  u32* nact              = (u32*)(ws + WS_NACT);
  u32* hdr               = (u32*)(ws + WS_HDR);
  u32* metaA             = (u32*)(ws + WS_META);
  u32* loff              = (u32*)(ws + WS_LOFF);
  u32* tmp               = (u32*)(ws + WS_TMP);
  unsigned short* zt     = (unsigned short*)(ws + WS_ZT);
  unsigned short* wout16 = (unsigned short*)(ws + WS_WOUT);
  u64* hs2               = (u64*)(ws + WS_HS2);
  u64* hsl   = (u64*)d_out;                          // ladder <= 33.4MB
  u64* call  = (u64*)((char*)d_out + DO_CALL);       // 64MB c-state

  hipMemsetAsync(d_ws, 0, 2048, stream);  // barrier counters only

  seg_build_k<<<1, 256, 0, stream>>>(dones, tmp, metaA, nact, hdr, loff);
  cvt_z_k<<<2048, 256, 0, stream>>>(z, zt);
  zero_hs_tail_k<<<32, 256, 0, stream>>>(hs2);
  lstm_seg_k<<<256, 512, 0, stream>>>(Whh, Wih, embed, bih, bhh, actions,
                                      zt, metaA, nact, hdr, loff, hsl, call,
                                      hs2, gcnt);
  cvt_wout_k<<<1921, 256, 0, stream>>>(Wout, wout16);
  out_gemm_k<<<dim3(256, 24), 256, 0, stream>>>(hs2, wout16, bout, out);
}